// Round 8
// baseline (526.266 us; speedup 1.0000x reference)
//
#include <hip/hip_runtime.h>

typedef unsigned short u16;
typedef short s16x8 __attribute__((ext_vector_type(8)));
typedef u16 u16x8 __attribute__((ext_vector_type(8)));
typedef float f32x4 __attribute__((ext_vector_type(4)));

// ---------- helpers ----------
__device__ inline float bf2f(u16 u) {
    union { unsigned int i; float f; } w; w.i = ((unsigned int)u) << 16; return w.f;
}
__device__ inline u16 f2bf(float f) {
    union { float f; unsigned int i; } w; w.f = f;
    unsigned int u = w.i;
    u += 0x7fffu + ((u >> 16) & 1u);
    return (u16)(u >> 16);
}

// ---------- tiled transpose + bf16: dst[n*dstride+k] = bf16(src[k*N+n]) ----------
__global__ __launch_bounds__(256)
void wtransT(const float* __restrict__ src, u16* __restrict__ dst,
             int K, int N, int dstride, int src_z, int dz_hi, int dz_lo)
{
    int z = blockIdx.z;
    src += (size_t)z * src_z;
    dst += (size_t)(z >> 1) * dz_hi + (size_t)(z & 1) * dz_lo;
    __shared__ float t[32][33];
    int kt = blockIdx.y * 32, nt0 = blockIdx.x * 32;
    int lx = threadIdx.x & 31, ly = threadIdx.x >> 5;   // 32 x 8
#pragma unroll
    for (int i = 0; i < 32; i += 8) {
        int k = kt + ly + i, n = nt0 + lx;
        t[ly + i][lx] = (k < K && n < N) ? src[(size_t)k * N + n] : 0.f;
    }
    __syncthreads();
#pragma unroll
    for (int i = 0; i < 32; i += 8) {
        int n = nt0 + ly + i, k = kt + lx;
        if (n < N && k < K) dst[(size_t)n * dstride + k] = f2bf(t[lx][ly + i]);
    }
}

// ---------- plain f32 -> bf16 convert ----------
__global__ void cvtk(const float* __restrict__ src, u16* __restrict__ dst, int n) {
    int i = blockIdx.x * 256 + threadIdx.x;
    if (i < n) dst[i] = f2bf(src[i]);
}

// ---------- pipelined GEMM: counted vmcnt, r5 m-fastest XCD swizzle ----------
// C[M,N] = A[M,K] @ WT[N,K]^T ; 4 waves 2x2, BK=64, 2 LDS buffers.
// EPI 2: xv = fout[row*768+col] + v*aux[col]; fout=xv; bout[row*768+col]=bf16(xv)
// EPI 3: bout[row*ostride+col]=bf16(v); cols>=3104 (per dir-half): dt=softplus(v+aux) -> dtAll
// Requires: K%64==0, K/64>=2.
template<int BM, int BN, int EPI>
__global__ __launch_bounds__(256, 2)
void gemmP(const u16* __restrict__ A, const u16* __restrict__ WT,
           int M, int N, int K,
           float* __restrict__ fout, u16* __restrict__ bout,
           const float* __restrict__ aux, float* __restrict__ dtAll,
           int ostride)
{
    constexpr int MI = BM / 32;              // m fragments per wave
    constexpr int NI = BN / 32;              // n fragments per wave
    constexpr int L  = (BM + BN) / 32;       // gload_lds per thread per stage
    constexpr int TBUF = (BM + BN) * 64;     // u16 per k-tile buffer
    __shared__ u16 lds8[2 * TBUF];

    // m204 bijective XCD chunking, wid m-fastest: consecutive wids on an XCD
    // share the same n-tile (B-panel L2-resident), stream A. [r5-proven]
    int mt, nt;
    {
        int nwg = gridDim.x * gridDim.y;
        int f = blockIdx.y * gridDim.x + blockIdx.x;
        int q = nwg >> 3, r = nwg & 7;
        int xcd = f & 7, lo = f >> 3;
        int wid = (xcd < r ? xcd * (q + 1) : r * (q + 1) + (xcd - r) * q) + lo;
        mt = wid % gridDim.y; nt = wid / gridDim.y;
    }

    const int tid  = threadIdx.x;
    const int lane = tid & 63;
    const int wave = tid >> 6;
    const int wm = wave >> 1, wn = wave & 1;
    const int r16 = lane & 15;
    const int lg  = lane >> 4;               // 0..3
    const int mb  = mt * BM;
    const int nb  = nt * BN;
    const int wbase = tid & 192;

    f32x4 acc[MI][NI];
#pragma unroll
    for (int mi = 0; mi < MI; mi++)
#pragma unroll
        for (int ni = 0; ni < NI; ni++)
            acc[mi][ni] = (f32x4){0.f, 0.f, 0.f, 0.f};

    // stage one K-tile; gload_lds writes linearly, source chunk pre-swizzled cb^=row&7
    auto stage = [&](int buf, int k0) {
        u16* bA = &lds8[buf * TBUF];
#pragma unroll
        for (int rr = 0; rr < L; rr++) {
            int e = rr * 256 + tid;
            int row = e >> 3;
            int cbs = (e & 7) ^ (row & 7);
            const u16* g = (rr < BM / 32)
                ? A  + (size_t)(mb + row) * K + k0 + cbs * 8
                : WT + (size_t)(nb + row - BM) * K + k0 + cbs * 8;
            __builtin_amdgcn_global_load_lds(
                (const __attribute__((address_space(1))) void*)g,
                (__attribute__((address_space(3))) void*)&bA[(rr * 256 + wbase) * 8],
                16, 0, 0);
        }
    };

    const int ntk = K >> 6;
    stage(0, 0);
    stage(1, 64);
    if constexpr (L == 8) asm volatile("s_waitcnt vmcnt(8)" ::: "memory");
    else                  asm volatile("s_waitcnt vmcnt(6)" ::: "memory");
    __builtin_amdgcn_sched_barrier(0);
    __builtin_amdgcn_s_barrier();

    for (int t = 0; t < ntk; t++) {
        const int buf = t & 1;
        const u16* bA = &lds8[buf * TBUF];
        const u16* bB = bA + BM * 64;
        s16x8 a[MI][2], b[NI][2];
#pragma unroll
        for (int mf = 0; mf < MI; mf++)
#pragma unroll
            for (int kk = 0; kk < 2; kk++) {
                int row = wm * (BM / 2) + mf * 16 + r16;
                int cb = (kk * 4 + lg) ^ (row & 7);
                a[mf][kk] = *(const s16x8*)&bA[row * 64 + cb * 8];
            }
#pragma unroll
        for (int nf = 0; nf < NI; nf++)
#pragma unroll
            for (int kk = 0; kk < 2; kk++) {
                int row = wn * (BN / 2) + nf * 16 + r16;
                int cb = (kk * 4 + lg) ^ (row & 7);
                b[nf][kk] = *(const s16x8*)&bB[row * 64 + cb * 8];
            }
        asm volatile("s_waitcnt lgkmcnt(0)" ::: "memory");
        __builtin_amdgcn_sched_barrier(0);
        __builtin_amdgcn_s_barrier();        // all waves done reading buf
        if (t + 2 < ntk) {
            stage(buf, (t + 2) << 6);        // overwrite just-read buffer
            if constexpr (L == 8) asm volatile("s_waitcnt vmcnt(8)" ::: "memory");
            else                  asm volatile("s_waitcnt vmcnt(6)" ::: "memory");
        } else {
            asm volatile("s_waitcnt vmcnt(0)" ::: "memory");
        }
        __builtin_amdgcn_sched_barrier(0);
        __builtin_amdgcn_s_barrier();        // buf^1 ready for next iter
        __builtin_amdgcn_s_setprio(1);
#pragma unroll
        for (int mf = 0; mf < MI; mf++)
#pragma unroll
            for (int nf = 0; nf < NI; nf++) {
                acc[mf][nf] = __builtin_amdgcn_mfma_f32_16x16x32_bf16(
                    a[mf][0], b[nf][0], acc[mf][nf], 0, 0, 0);
                acc[mf][nf] = __builtin_amdgcn_mfma_f32_16x16x32_bf16(
                    a[mf][1], b[nf][1], acc[mf][nf], 0, 0, 0);
            }
        __builtin_amdgcn_s_setprio(0);
    }

#pragma unroll
    for (int mf = 0; mf < MI; mf++) {
        const int rowb = mb + wm * (BM / 2) + mf * 16 + lg * 4;
#pragma unroll
        for (int nf = 0; nf < NI; nf++) {
            int col = nb + wn * (BN / 2) + nf * 16 + r16;
            if (col < N) {
#pragma unroll
                for (int j = 0; j < 4; j++) {
                    int row = rowb + j;
                    float v = acc[mf][nf][j];
                    if (EPI == 2) {
                        size_t o = (size_t)row * 768 + col;
                        float xv = fout[o] + v * aux[col];
                        fout[o] = xv; bout[o] = f2bf(xv);
                    } else {
                        bout[(size_t)row * ostride + col] = f2bf(v);
                        int dirc = col >= 3128;
                        int cc = col - dirc * 3128;
                        if (cc >= 3104) {
                            int hh = cc - 3104;
                            float raw = v + aux[dirc * 24 + hh];
                            float dtv = raw > 20.f ? raw : log1pf(__expf(raw));
                            dtAll[((size_t)dirc * 4096 + row) * 24 + hh] = dtv;
                        }
                    }
                }
            }
        }
    }
}

// ---------- LDS-staged GEMM (m97 structure) + bijective XCD swizzle ----------
template<int BM, int BN, int EPI>
__global__ __launch_bounds__(256)
void gemmL(const u16* __restrict__ A, const u16* __restrict__ WT,
           int M, int N, int K,
           float* __restrict__ fout, u16* __restrict__ bout,
           const float* __restrict__ bias, const float* __restrict__ lsv,
           int ostride, int ocoloff,
           size_t aZ, size_t wZ, size_t oZ, int ocolZ)
{
    constexpr int MI = BM / 32, NI = BN / 32;
    constexpr int BUF = (BM + BN) * 32;
    constexpr int RA = BM / 64, RB = BN / 64;
    __shared__ u16 lds[2 * BUF];

    {
        int z = blockIdx.z;
        A += (size_t)z * aZ; WT += (size_t)z * wZ;
        bout += (size_t)(z >> 1) * oZ; ocoloff += (z & 1) * ocolZ;
    }

    int mt, nt;
    {
        int nwg = gridDim.x * gridDim.y;
        int f = blockIdx.y * gridDim.x + blockIdx.x;
        int q = nwg >> 3, r = nwg & 7;
        int xcd = f & 7, lo = f >> 3;
        int wid = (xcd < r ? xcd * (q + 1) : r * (q + 1) + (xcd - r) * q) + lo;
        mt = wid % gridDim.y; nt = wid / gridDim.y;
    }

    const int tid  = threadIdx.x;
    const int lane = tid & 63;
    const int wave = tid >> 6;
    const int wm = wave >> 1, wn = wave & 1;
    const int r16 = lane & 15;
    const int ks  = (lane >> 4) * 8;
    const int mb  = mt * BM;
    const int nb  = nt * BN;
    const int wbase = tid & 192;

    f32x4 acc[MI][NI];
#pragma unroll
    for (int mi = 0; mi < MI; mi++)
#pragma unroll
        for (int ni = 0; ni < NI; ni++)
            acc[mi][ni] = (f32x4){0.f, 0.f, 0.f, 0.f};

    auto stage = [&](int buf, int k0) {
        u16* bufA = &lds[buf * BUF];
        u16* bufB = &lds[buf * BUF + BM * 32];
#pragma unroll
        for (int r = 0; r < RA; r++) {
            int c = r * 256 + tid;
            const u16* g = A + (size_t)(mb + (c >> 2)) * K + k0 + (c & 3) * 8;
            __builtin_amdgcn_global_load_lds(
                (const __attribute__((address_space(1))) void*)g,
                (__attribute__((address_space(3))) void*)&bufA[(r * 256 + wbase) * 8],
                16, 0, 0);
        }
#pragma unroll
        for (int r = 0; r < RB; r++) {
            int c = r * 256 + tid;
            const u16* g = WT + (size_t)(nb + (c >> 2)) * K + k0 + (c & 3) * 8;
            __builtin_amdgcn_global_load_lds(
                (const __attribute__((address_space(1))) void*)g,
                (__attribute__((address_space(3))) void*)&bufB[(r * 256 + wbase) * 8],
                16, 0, 0);
        }
    };
    auto compute = [&](int buf) {
        const u16* bufA = &lds[buf * BUF];
        const u16* bufB = &lds[buf * BUF + BM * 32];
        s16x8 af[MI], bfr[NI];
#pragma unroll
        for (int mi = 0; mi < MI; mi++)
            af[mi] = *(const s16x8*)&bufA[(wm * (BM / 2) + mi * 16 + r16) * 32 + ks];
#pragma unroll
        for (int ni = 0; ni < NI; ni++)
            bfr[ni] = *(const s16x8*)&bufB[(wn * (BN / 2) + ni * 16 + r16) * 32 + ks];
#pragma unroll
        for (int mi = 0; mi < MI; mi++)
#pragma unroll
            for (int ni = 0; ni < NI; ni++)
                acc[mi][ni] = __builtin_amdgcn_mfma_f32_16x16x32_bf16(
                    af[mi], bfr[ni], acc[mi][ni], 0, 0, 0);
    };

    const int nt2 = K >> 5;
    stage(0, 0);
    __syncthreads();
    for (int t = 0; t < nt2; t++) {
        if (t + 1 < nt2) stage((t + 1) & 1, (t + 1) << 5);
        compute(t & 1);
        __syncthreads();
    }

#pragma unroll
    for (int mi = 0; mi < MI; mi++) {
        const int rowb = mb + wm * (BM / 2) + mi * 16 + (lane >> 4) * 4;
#pragma unroll
        for (int ni = 0; ni < NI; ni++) {
            int col = nb + wn * (BN / 2) + ni * 16 + r16;
            if (col < N) {
#pragma unroll
                for (int j = 0; j < 4; j++) {
                    int row = rowb + j;
                    float v = acc[mi][ni][j];
                    if (EPI == 0) {
                        v += bias[col];
                        size_t o = (size_t)row * ostride + col;
                        fout[o] = v; bout[o] = f2bf(v);
                    } else if (EPI == 1) {
                        bout[(size_t)row * ostride + ocoloff + col] = f2bf(v);
                    } else {
                        size_t o = (size_t)row * 768 + col;
                        float xv = fout[o] + v * lsv[col];
                        fout[o] = xv; bout[o] = f2bf(xv);
                    }
                }
            }
        }
    }
}

// ---------- chunked scan pass 1 (conv+silu fused) ----------
__global__ __launch_bounds__(256)
void scan1k(const u16* __restrict__ zxAll, const float* __restrict__ dtAll,
            const float* __restrict__ cw, const float* __restrict__ cb,
            const float* __restrict__ Alog, const float* __restrict__ Dhp,
            u16* __restrict__ yAll, float* __restrict__ states, float* __restrict__ decays)
{
    const int c   = blockIdx.x;
    const int bh  = blockIdx.y;
    const int dir = blockIdx.z;
    const int b = bh / 24, h = bh % 24;
    const float* dtp = dtAll + (size_t)dir * 4096 * 24;
    u16* yp = yAll + dir * 1536;
    const float Av = -__expf(Alog[dir * 24 + h]);
    const float Dv = Dhp[dir * 24 + h];
    const int inst = (dir * 2 + b) * 24 + h;

    const int tid  = threadIdx.x;
    const int lane = tid & 63;
    const int wave = tid >> 6;
    const int r16  = lane & 15;
    const int ks   = (lane >> 4) * 8;

    __shared__ u16 xT[64][72];
    __shared__ u16 Gs[64][72];
    __shared__ u16 Bs[64][40];
    __shared__ u16 Cs[64][40];
    __shared__ u16 SBT[16][72];
    __shared__ float dts[64], cds[64];

    const u16* zxd = zxAll + dir * 3128 + 1536;
    auto growp = [&](int ii) -> const u16* {
        int l = dir ? (2047 - ii) : ii;
        return zxd + ((size_t)b * 2048 + l) * 6256;
    };
    auto rowof = [&](int t) -> size_t {
        int i = c * 64 + t;
        int l = dir ? (2047 - i) : i;
        return (size_t)b * 2048 + l;
    };
    const u16x8 zz = {0,0,0,0,0,0,0,0};

    {
        int tr = tid >> 2, pg = tid & 3;
        int chb = h * 64 + pg * 16;
        int i0 = c * 64 + tr;
        u16x8 tv[4][2];
#pragma unroll
        for (int k = 0; k < 4; k++) {
            int ii = i0 - 3 + k;
            if (ii >= 0) {
                const u16* s = growp(ii) + chb;
                tv[k][0] = *(const u16x8*)s;
                tv[k][1] = *(const u16x8*)(s + 8);
            } else { tv[k][0] = zz; tv[k][1] = zz; }
        }
        const float* cwp = cw + ((size_t)dir * 1568 + chb) * 4;
        const float* cbp = cb + (size_t)dir * 1568 + chb;
#pragma unroll
        for (int j = 0; j < 16; j++) {
            f32x4 wj = *(const f32x4*)(cwp + j * 4);
            float a = cbp[j];
            int hi = j >> 3, lo2 = j & 7;
            a += bf2f(tv[0][hi][lo2]) * wj[0] + bf2f(tv[1][hi][lo2]) * wj[1]
               + bf2f(tv[2][hi][lo2]) * wj[2] + bf2f(tv[3][hi][lo2]) * wj[3];
            a = a / (1.f + __expf(-a));
            xT[pg * 16 + j][tr] = f2bf(a);
        }
    }
    {
        int t = tid & 63, which = tid >> 6;
        if (which < 2) {
            int chb = 1536 + which * 16;
            int i0 = c * 64 + t;
            u16x8 tv[4][2];
#pragma unroll
            for (int k = 0; k < 4; k++) {
                int ii = i0 - 3 + k;
                if (ii >= 0) {
                    const u16* s = growp(ii) + chb;
                    tv[k][0] = *(const u16x8*)s;
                    tv[k][1] = *(const u16x8*)(s + 8);
                } else { tv[k][0] = zz; tv[k][1] = zz; }
            }
            const float* cwp = cw + ((size_t)dir * 1568 + chb) * 4;
            const float* cbp = cb + (size_t)dir * 1568 + chb;
            u16* dst = which ? &Cs[t][0] : &Bs[t][0];
#pragma unroll
            for (int j = 0; j < 16; j++) {
                f32x4 wj = *(const f32x4*)(cwp + j * 4);
                float a = cbp[j];
                int hi = j >> 3, lo2 = j & 7;
                a += bf2f(tv[0][hi][lo2]) * wj[0] + bf2f(tv[1][hi][lo2]) * wj[1]
                   + bf2f(tv[2][hi][lo2]) * wj[2] + bf2f(tv[3][hi][lo2]) * wj[3];
                a = a / (1.f + __expf(-a));
                dst[j] = f2bf(a);
            }
        } else {
            u16* dst = (which == 2) ? &Bs[t][16] : &Cs[t][16];
            *(u16x8*)dst = zz; *(u16x8*)(dst + 8) = zz;
        }
    }
    if (tid < 64) {
        float v = dtp[rowof(tid) * 24 + h];
        dts[tid] = v;
        float s = v;
#pragma unroll
        for (int o = 1; o < 64; o <<= 1) {
            float nvl = __shfl_up(s, o, 64);
            if (lane >= o) s += nvl;
        }
        cds[tid] = s;
    }
    __syncthreads();

    {
        const s16x8 af = *(const s16x8*)&Cs[wave * 16 + r16][ks];
#pragma unroll
        for (int st = 0; st < 4; st++) {
            const s16x8 bfr = *(const s16x8*)&Bs[st * 16 + r16][ks];
            f32x4 a2 = {0.f, 0.f, 0.f, 0.f};
            a2 = __builtin_amdgcn_mfma_f32_16x16x32_bf16(af, bfr, a2, 0, 0, 0);
            int s = st * 16 + (lane & 15);
            int tbase = wave * 16 + (lane >> 4) * 4;
            float cs = cds[s], dtv = dts[s];
#pragma unroll
            for (int j = 0; j < 4; j++) {
                int t = tbase + j;
                float g = 0.f;
                if (s <= t) {
                    g = a2[j] * dtv * __expf(Av * (cds[t] - cs));
                    if (s == t) g += Dv;
                }
                Gs[t][s] = f2bf(g);
            }
        }
    }
    {
        float cdT = cds[63];
        int s = tid & 63;
        float sc = __expf(Av * (cdT - cds[s])) * dts[s];
#pragma unroll
        for (int it = 0; it < 4; it++) {
            int n = (tid >> 6) + it * 4;
            SBT[n][s] = f2bf(sc * bf2f(Bs[s][n]));
        }
    }
    __syncthreads();

    {
#pragma unroll
        for (int pt = 0; pt < 4; pt++) {
            f32x4 a2 = {0.f, 0.f, 0.f, 0.f};
#pragma unroll
            for (int kk = 0; kk < 2; kk++) {
                s16x8 af = *(const s16x8*)&Gs[wave * 16 + r16][kk * 32 + ks];
                s16x8 bfr = *(const s16x8*)&xT[pt * 16 + r16][kk * 32 + ks];
                a2 = __builtin_amdgcn_mfma_f32_16x16x32_bf16(af, bfr, a2, 0, 0, 0);
            }
            int p = pt * 16 + (lane & 15);
            int tbase = wave * 16 + (lane >> 4) * 4;
#pragma unroll
            for (int j = 0; j < 4; j++) {
                size_t row = rowof(tbase + j);
                yp[row * 3072 + h * 64 + p] = f2bf(a2[j]);
            }
        }
    }
    {
        f32x4 a2 = {0.f, 0.f, 0.f, 0.f};
#pragma unroll
        for (int kk = 0; kk < 2; kk++) {
            s16x8 af = *(const s16x8*)&xT[wave * 16 + r16][kk * 32 + ks];
            s16x8 bfr = *(const s16x8*)&SBT[r16][kk * 32 + ks];
            a2 = __builtin_amdgcn_mfma_f32_16x16x32_bf16(af, bfr, a2, 0, 0, 0);
        }
        int n = lane & 15;
        int pbase = wave * 16 + (lane >> 4) * 4;
        float* st = states + ((size_t)inst * 32 + c) * 1024;
#pragma unroll
        for (int j = 0; j < 4; j++) st[(pbase + j) * 16 + n] = a2[j];
        if (tid == 0) decays[inst * 32 + c] = __expf(Av * cds[63]);
    }
}

// ---------- chunked scan pass 2: cross-chunk recurrence ----------
__global__ __launch_bounds__(256)
void scan2k(float* __restrict__ states, const float* __restrict__ decays)
{
    int inst = blockIdx.x;
    int tid = threadIdx.x;
    float* base = states + (size_t)inst * 32 * 1024 + tid * 4;
    const float* dec = decays + inst * 32;
    f32x4 hreg = {0.f, 0.f, 0.f, 0.f};
    f32x4 L = *(f32x4*)base;
    for (int cc = 0; cc < 32; cc++) {
        f32x4 Lnext;
        if (cc + 1 < 32) Lnext = *(f32x4*)(base + (cc + 1) * 1024);
        *(f32x4*)(base + cc * 1024) = hreg;
        float d = dec[cc];
        hreg = hreg * d + L;
        L = Lnext;
    }
}

// ---------- chunked scan pass 3: y += C_t . (exp(A cd_t) h_start), conv fused ----------
__global__ __launch_bounds__(256)
void scan3k(const float* __restrict__ states,
            const u16* __restrict__ zxAll, const float* __restrict__ dtAll,
            const float* __restrict__ cw, const float* __restrict__ cb,
            const float* __restrict__ Alog, u16* __restrict__ yAll)
{
    const int c   = blockIdx.x + 1;
    const int bh  = blockIdx.y;
    const int dir = blockIdx.z;
    const int b = bh / 24, h = bh % 24;
    const float* dtp = dtAll + (size_t)dir * 4096 * 24;
    u16* yp = yAll + dir * 1536;
    const float Av = -__expf(Alog[dir * 24 + h]);
    const int inst = (dir * 2 + b) * 24 + h;
    const int tid = threadIdx.x;

    __shared__ float hs[64][20];
    __shared__ u16 Cs3[64][16];
    __shared__ float ets[64];

    const u16* zxd = zxAll + dir * 3128 + 1536;
    auto growp = [&](int ii) -> const u16* {
        int l = dir ? (2047 - ii) : ii;
        return zxd + ((size_t)b * 2048 + l) * 6256;
    };
    auto rowof = [&](int t) -> size_t {
        int i = c * 64 + t;
        int l = dir ? (2047 - i) : i;
        return (size_t)b * 2048 + l;
    };

    {
        const float* sp = states + ((size_t)inst * 32 + c) * 1024 + tid * 4;
        f32x4 v = *(const f32x4*)sp;
        int e = tid * 4;
        int p = e >> 4, n = e & 15;
        hs[p][n] = v[0]; hs[p][n+1] = v[1]; hs[p][n+2] = v[2]; hs[p][n+3] = v[3];
    }
    if (tid < 64) {
        int i0 = c * 64 + tid;
        u16x8 tv[4][2];
#pragma unroll
        for (int k = 0; k < 4; k++) {
            const u16* s = growp(i0 - 3 + k) + 1552;
            tv[k][0] = *(const u16x8*)s;
            tv[k][1] = *(const u16x8*)(s + 8);
        }
        const float* cwp = cw + ((size_t)dir * 1568 + 1552) * 4;
        const float* cbp = cb + (size_t)dir * 1568 + 1552;
#pragma unroll
        for (int j = 0; j < 16; j++) {
            f32x4 wj = *(const f32x4*)(cwp + j * 4);
            float a = cbp[j];
            int hi = j >> 3, lo2 = j & 7;
            a += bf2f(tv[0][hi][lo2]) * wj[0] + bf2f(tv[1][hi][lo2]) * wj[1]
               + bf2f(tv[2][hi][lo2]) * wj[2] + bf2f(tv[3][hi][lo2]) * wj[3];
            a = a / (1.f + __expf(-a));
            Cs3[tid][j] = f2bf(a);
        }
        float v = dtp[rowof(tid) * 24 + h];
        float s = v;
#pragma unroll
        for (int o = 1; o < 64; o <<= 1) {
            float nvl = __shfl_up(s, o, 64);
            if ((tid & 63) >= o) s += nvl;
        }
        ets[tid] = __expf(Av * s);
    }
    __syncthreads();

    int t = tid >> 2, pg = tid & 3;
    float cv[16];
    float et = ets[t];
#pragma unroll
    for (int n = 0; n < 16; n++) cv[n] = bf2f(Cs3[t][n]) * et;
    size_t row = rowof(t);
    u16* yrow = yp + row * 3072 + h * 64 + pg * 16;
    u16x8 ya = *(u16x8*)yrow;
    u16x8 yb = *(u16x8*)(yrow + 8);
#pragma unroll
    for (int jj = 0; jj < 16; jj++) {
        int p = pg * 16 + jj;
        float acc = 0.f;
#pragma unroll
        for (int q = 0; q < 4; q++) {
            f32x4 hv = *(const f32x4*)&hs[p][q * 4];
            acc += cv[q*4]*hv[0] + cv[q*4+1]*hv[1] + cv[q*4+2]*hv[2] + cv[q*4+3]*hv[3];
        }
        if (jj < 8) ya[jj] = f2bf(bf2f(ya[jj]) + acc);
        else        yb[jj - 8] = f2bf(bf2f(yb[jj - 8]) + acc);
    }
    *(u16x8*)yrow = ya;
    *(u16x8*)(yrow + 8) = yb;
}

// ---------- gating + RMSnorm ----------
__global__ __launch_bounds__(256)
void gatek(const u16* __restrict__ zxAll, u16* __restrict__ yAll,
           const float* __restrict__ nw)
{
    int row = blockIdx.x, dir = blockIdx.y;
    const u16* zx = zxAll + (size_t)row * 6256 + dir * 3128;
    u16* y = yAll + (size_t)row * 3072 + dir * 1536;
    const float* nwp = nw + dir * 1536;
    int tid = threadIdx.x;
    float g[6]; float s = 0.f;
#pragma unroll
    for (int j = 0; j < 6; j++) {
        int c = j * 256 + tid;
        float z  = bf2f(zx[c]);
        float yv = bf2f(y[c]);
        float gv = yv * z / (1.f + __expf(-z));
        g[j] = gv; s += gv * gv;
    }
    __shared__ float red[4];
    for (int o = 32; o; o >>= 1) s += __shfl_down(s, o, 64);
    if ((tid & 63) == 0) red[tid >> 6] = s;
    __syncthreads();
    s = red[0] + red[1] + red[2] + red[3];
    float sc = rsqrtf(s * (1.f / 1536.f) + 1e-5f);
#pragma unroll
    for (int j = 0; j < 6; j++) {
        int c = j * 256 + tid;
        y[c] = f2bf(g[j] * sc * nwp[c]);
    }
}

// ---------- final RMS norm ----------
__global__ __launch_bounds__(256)
void finalk(const float* __restrict__ x, const float* __restrict__ fw, float* __restrict__ out)
{
    int row = blockIdx.x; int tid = threadIdx.x;
    const float* xr = x + (size_t)row * 768;
    float v[3]; float s = 0.f;
#pragma unroll
    for (int j = 0; j < 3; j++) {
        int c = j * 256 + tid;
        v[j] = xr[c]; s += v[j] * v[j];
    }
    __shared__ float red[4];
    for (int o = 32; o; o >>= 1) s += __shfl_down(s, o, 64);
    if ((tid & 63) == 0) red[tid >> 6] = s;
    __syncthreads();
    s = red[0] + red[1] + red[2] + red[3];
    float sc = rsqrtf(s * (1.f / 768.f) + 1e-6f);
#pragma unroll
    for (int j = 0; j < 3; j++) {
        int c = j * 256 + tid;
        out[(size_t)row * 768 + c] = v[j] * sc * (1.f + fw[c]);
    }
}

// ---------- host ----------
extern "C" void kernel_launch(void* const* d_in, const int* in_sizes, int n_in,
                              void* d_out, int out_size, void* d_ws, size_t ws_size,
                              hipStream_t stream)
{
    const float* pe      = (const float*)d_in[0];
    const float* Wp      = (const float*)d_in[1];
    const float* bp      = (const float*)d_in[2];
    const float* in_w    = (const float*)d_in[3];
    const float* conv_w  = (const float*)d_in[4];
    const float* conv_b  = (const float*)d_in[5];
    const float* dt_bias = (const float*)d_in[6];
    const float* A_log   = (const float*)d_in[7];
    const float* Dh      = (const float*)d_in[8];
    const float* norm_w  = (const float*)d_in[9];
    const float* out_w   = (const float*)d_in[10];
    const float* bi_w    = (const float*)d_in[11];
    const float* ls      = (const float*)d_in[12];
    const float* fin_w   = (const float*)d_in[13];

    char* wp = (char*)d_ws;
    auto alloc = [&](size_t bytes) {
        char* r = wp; wp += (bytes + 255) & ~(size_t)255; return r;
    };
    u16*   WpT    = (u16*)  alloc((size_t)768 * 256 * 2);
    u16*   inWT   = (u16*)  alloc((size_t)2 * 6272 * 768 * 2);
    u16*   outWB  = (u16*)  alloc((size_t)4 * 1536 * 768 * 2);
    u16*   biWT   = (u16*)  alloc((size_t)4 * 768 * 768 * 2);
    u16*   WcombT = (u16*)  alloc((size_t)2 * 768 * 3072 * 2);
    u16*   peB    = (u16*)  alloc((size_t)4096 * 256 * 2);
    float* x      = (float*)alloc((size_t)4096 * 768 * 4);
    u16*   xb     = (u16*)  alloc((size_t)4096 * 768 * 2);
    u16*   zxAll  = (u16*)  alloc((size_t)4096 * 6256 * 2);
    float* dtAll  = (float*)alloc((size_t)2 * 4096 * 24 * 4);
    u16*   yAll   = (u16*)  alloc((size_t)4096 * 3072 * 2);
    float* states = (float*)alloc((size_t)96 * 32 * 1024 * 4);
    float* decays = (float*)alloc((size_t)96 * 32 * 4);

    // ---- weight prep (batched over z) ----
    wtransT<<<dim3(24, 8, 1), 256, 0, stream>>>(Wp, WpT, 256, 768, 256, 0, 0, 0);
    wtransT<<<dim3(98, 24, 4), 256, 0, stream>>>(in_w, inWT, 768, 3128, 768,
                                                 2402304, 4816896, 2402304);
    wtransT<<<dim3(24, 24, 4), 256, 0, stream>>>(bi_w, biWT, 768, 768, 768,
                                                 589824, 1179648, 589824);
    cvtk<<<(4 * 1536 * 768 + 255) / 256, 256, 0, stream>>>(out_w, outWB, 4 * 1536 * 768);
    cvtk<<<4096, 256, 0, stream>>>(pe, peB, 4096 * 256);

    // ---- Wcomb (batched) ----
    gemmL<64, 64, 1><<<dim3(24, 12, 4), 256, 0, stream>>>(
        biWT, outWB, 768, 1536, 768, nullptr, WcombT,
        nullptr, nullptr, 3072, 0,
        (size_t)589824, (size_t)1179648, (size_t)768 * 3072, 1536);

    // ---- patch embedding GEMM ----
    gemmL<64, 64, 0><<<dim3(12, 64, 1), 256, 0, stream>>>(
        peB, WpT, 4096, 768, 256, x, xb, bp, nullptr, 768, 0, 0, 0, 0, 0);

    for (int i = 0; i < 2; i++) {
        // merged in_proj (both dirs) + fused dt-softplus epilogue
        gemmP<128, 128, 3><<<dim3(49, 32), 256, 0, stream>>>(
            xb, inWT + (size_t)i * 6272 * 768, 4096, 6256, 768,
            nullptr, zxAll, dt_bias + i * 48, dtAll, 6256);
        scan1k<<<dim3(32, 48, 2), 256, 0, stream>>>(zxAll, dtAll,
                                                    conv_w + (size_t)i * 2 * 1568 * 4,
                                                    conv_b + (size_t)i * 2 * 1568,
                                                    A_log + i * 48, Dh + i * 48,
                                                    yAll, states, decays);
        scan2k<<<96, 256, 0, stream>>>(states, decays);
        scan3k<<<dim3(31, 48, 2), 256, 0, stream>>>(states, zxAll, dtAll,
                                                    conv_w + (size_t)i * 2 * 1568 * 4,
                                                    conv_b + (size_t)i * 2 * 1568,
                                                    A_log + i * 48, yAll);
        gatek<<<dim3(4096, 2), 256, 0, stream>>>(zxAll, yAll, norm_w + (size_t)i * 2 * 1536);
        // fused out_proj + concat + bi_w + residual (pipelined)
        gemmP<128, 64, 2><<<dim3(12, 32), 256, 0, stream>>>(
            yAll, WcombT + (size_t)i * 768 * 3072, 4096, 768, 3072,
            x, xb, ls + i * 768, nullptr, 768);
    }

    finalk<<<4096, 256, 0, stream>>>(x, fin_w, (float*)d_out);
}

// Round 9
// 498.339 us; speedup vs baseline: 1.0560x; 1.0560x over previous
//
#include <hip/hip_runtime.h>

typedef unsigned short u16;
typedef short s16x8 __attribute__((ext_vector_type(8)));
typedef u16 u16x8 __attribute__((ext_vector_type(8)));
typedef float f32x4 __attribute__((ext_vector_type(4)));

// ---------- helpers ----------
__device__ inline float bf2f(u16 u) {
    union { unsigned int i; float f; } w; w.i = ((unsigned int)u) << 16; return w.f;
}
__device__ inline u16 f2bf(float f) {
    union { float f; unsigned int i; } w; w.f = f;
    unsigned int u = w.i;
    u += 0x7fffu + ((u >> 16) & 1u);
    return (u16)(u >> 16);
}

// ---------- tiled transpose + bf16: dst[n*dstride+k] = bf16(src[k*N+n]) ----------
__global__ __launch_bounds__(256)
void wtransT(const float* __restrict__ src, u16* __restrict__ dst,
             int K, int N, int dstride, int src_z, int dz_hi, int dz_lo)
{
    int z = blockIdx.z;
    src += (size_t)z * src_z;
    dst += (size_t)(z >> 1) * dz_hi + (size_t)(z & 1) * dz_lo;
    __shared__ float t[32][33];
    int kt = blockIdx.y * 32, nt0 = blockIdx.x * 32;
    int lx = threadIdx.x & 31, ly = threadIdx.x >> 5;   // 32 x 8
#pragma unroll
    for (int i = 0; i < 32; i += 8) {
        int k = kt + ly + i, n = nt0 + lx;
        t[ly + i][lx] = (k < K && n < N) ? src[(size_t)k * N + n] : 0.f;
    }
    __syncthreads();
#pragma unroll
    for (int i = 0; i < 32; i += 8) {
        int n = nt0 + ly + i, k = kt + lx;
        if (n < N && k < K) dst[(size_t)n * dstride + k] = f2bf(t[lx][ly + i]);
    }
}

// ---------- plain f32 -> bf16 convert ----------
__global__ void cvtk(const float* __restrict__ src, u16* __restrict__ dst, int n) {
    int i = blockIdx.x * 256 + threadIdx.x;
    if (i < n) dst[i] = f2bf(src[i]);
}

// ---------- pipelined GEMM (verbatim r5 config): counted vmcnt, 2-tile lookahead ----------
// C[M,N] = A[M,K] @ WT[N,K]^T ; bf16 out: bout[row*ostride+col].
// BM=BN=128, BK=64, 256 threads (4 waves 2x2), 2 LDS buffers (64 KB).
__global__ __launch_bounds__(256, 2)
void gemm8(const u16* __restrict__ A, const u16* __restrict__ WT,
           int M, int N, int K,
           u16* __restrict__ bout, int ostride)
{
    __shared__ u16 lds8[2 * 16384];          // [buf][A:8192 | B:8192] u16

    // bijective XCD swizzle (m204), wid m-fastest
    int mt, nt;
    {
        int nwg = gridDim.x * gridDim.y;
        int f = blockIdx.y * gridDim.x + blockIdx.x;
        int q = nwg >> 3, r = nwg & 7;
        int xcd = f & 7, lo = f >> 3;
        int wid = (xcd < r ? xcd * (q + 1) : r * (q + 1) + (xcd - r) * q) + lo;
        mt = wid % gridDim.y; nt = wid / gridDim.y;
    }

    const int tid  = threadIdx.x;
    const int lane = tid & 63;
    const int wave = tid >> 6;
    const int wm = wave >> 1, wn = wave & 1;
    const int r16 = lane & 15;
    const int lg  = lane >> 4;               // 0..3
    const int mb  = mt * 128;
    const int nb  = nt * 128;
    const int wbase = tid & 192;

    f32x4 acc[4][4];
#pragma unroll
    for (int mi = 0; mi < 4; mi++)
#pragma unroll
        for (int ni = 0; ni < 4; ni++)
            acc[mi][ni] = (f32x4){0.f, 0.f, 0.f, 0.f};

    auto stage = [&](int buf, int k0) {
        u16* bA = &lds8[buf * 16384];
        u16* bB = bA + 8192;
#pragma unroll
        for (int r = 0; r < 4; r++) {
            int e = r * 256 + tid;
            int row = e >> 3;
            int cbs = (e & 7) ^ (row & 7);
            const u16* g = A + (size_t)(mb + row) * K + k0 + cbs * 8;
            __builtin_amdgcn_global_load_lds(
                (const __attribute__((address_space(1))) void*)g,
                (__attribute__((address_space(3))) void*)&bA[(r * 256 + wbase) * 8],
                16, 0, 0);
        }
#pragma unroll
        for (int r = 0; r < 4; r++) {
            int e = r * 256 + tid;
            int row = e >> 3;
            int cbs = (e & 7) ^ (row & 7);
            const u16* g = WT + (size_t)(nb + row) * K + k0 + cbs * 8;
            __builtin_amdgcn_global_load_lds(
                (const __attribute__((address_space(1))) void*)g,
                (__attribute__((address_space(3))) void*)&bB[(r * 256 + wbase) * 8],
                16, 0, 0);
        }
    };

    const int ntk = K >> 6;                  // K-tiles of 64
    stage(0, 0);
    stage(1, 64);
    asm volatile("s_waitcnt vmcnt(8)" ::: "memory");
    __builtin_amdgcn_sched_barrier(0);
    __builtin_amdgcn_s_barrier();

    for (int t = 0; t < ntk; t++) {
        const int buf = t & 1;
        const u16* bA = &lds8[buf * 16384];
        const u16* bB = bA + 8192;
        s16x8 a[4][2], b[4][2];
#pragma unroll
        for (int mf = 0; mf < 4; mf++)
#pragma unroll
            for (int kk = 0; kk < 2; kk++) {
                int row = wm * 64 + mf * 16 + r16;
                int cb = (kk * 4 + lg) ^ (row & 7);
                a[mf][kk] = *(const s16x8*)&bA[row * 64 + cb * 8];
            }
#pragma unroll
        for (int nf = 0; nf < 4; nf++)
#pragma unroll
            for (int kk = 0; kk < 2; kk++) {
                int row = wn * 64 + nf * 16 + r16;
                int cb = (kk * 4 + lg) ^ (row & 7);
                b[nf][kk] = *(const s16x8*)&bB[row * 64 + cb * 8];
            }
        asm volatile("s_waitcnt lgkmcnt(0)" ::: "memory");
        __builtin_amdgcn_sched_barrier(0);
        __builtin_amdgcn_s_barrier();        // all waves done reading buf
        if (t + 2 < ntk) {
            stage(buf, (t + 2) << 6);        // overwrite just-read buffer
            asm volatile("s_waitcnt vmcnt(8)" ::: "memory");  // tile t+1 complete
        } else {
            asm volatile("s_waitcnt vmcnt(0)" ::: "memory");
        }
        __builtin_amdgcn_sched_barrier(0);
        __builtin_amdgcn_s_barrier();        // buf[t^1] ready for next iter
        __builtin_amdgcn_s_setprio(1);
#pragma unroll
        for (int mf = 0; mf < 4; mf++)
#pragma unroll
            for (int nf = 0; nf < 4; nf++) {
                acc[mf][nf] = __builtin_amdgcn_mfma_f32_16x16x32_bf16(
                    a[mf][0], b[nf][0], acc[mf][nf], 0, 0, 0);
                acc[mf][nf] = __builtin_amdgcn_mfma_f32_16x16x32_bf16(
                    a[mf][1], b[nf][1], acc[mf][nf], 0, 0, 0);
            }
        __builtin_amdgcn_s_setprio(0);
    }

#pragma unroll
    for (int mf = 0; mf < 4; mf++) {
        const int rowb = mb + wm * 64 + mf * 16 + lg * 4;
#pragma unroll
        for (int nf = 0; nf < 4; nf++) {
            int col = nb + wn * 64 + nf * 16 + r16;
            if (col < N) {
#pragma unroll
                for (int j = 0; j < 4; j++)
                    bout[(size_t)(rowb + j) * ostride + col] = f2bf(acc[mf][nf][j]);
            }
        }
    }
}

// ---------- pipelined GEMM 128x64, EPI2 (out_proj fused residual), standalone ----------
// xv = fout[row*768+col] + v*lsv[col]; fout=xv; bout[row*768+col]=bf16(xv)
__global__ __launch_bounds__(256, 2)
void gemm9(const u16* __restrict__ A, const u16* __restrict__ WT, int K,
           float* __restrict__ fout, u16* __restrict__ bout,
           const float* __restrict__ lsv)
{
    __shared__ u16 lds9[2 * 12288];          // [buf][A:8192 | B:4096] u16

    int mt, nt;
    {
        int nwg = gridDim.x * gridDim.y;
        int f = blockIdx.y * gridDim.x + blockIdx.x;
        int q = nwg >> 3, r = nwg & 7;
        int xcd = f & 7, lo = f >> 3;
        int wid = (xcd < r ? xcd * (q + 1) : r * (q + 1) + (xcd - r) * q) + lo;
        mt = wid % gridDim.y; nt = wid / gridDim.y;
    }

    const int tid  = threadIdx.x;
    const int lane = tid & 63;
    const int wave = tid >> 6;
    const int wm = wave >> 1, wn = wave & 1;
    const int r16 = lane & 15;
    const int lg  = lane >> 4;
    const int mb  = mt * 128;
    const int nb  = nt * 64;
    const int wbase = tid & 192;

    f32x4 acc[4][2];
#pragma unroll
    for (int mi = 0; mi < 4; mi++)
#pragma unroll
        for (int ni = 0; ni < 2; ni++)
            acc[mi][ni] = (f32x4){0.f, 0.f, 0.f, 0.f};

    auto stage = [&](int buf, int k0) {
        u16* bA = &lds9[buf * 12288];
#pragma unroll
        for (int rr = 0; rr < 6; rr++) {
            int e = rr * 256 + tid;
            int row = e >> 3;
            int cbs = (e & 7) ^ (row & 7);
            const u16* g = (rr < 4)
                ? A  + (size_t)(mb + row) * K + k0 + cbs * 8
                : WT + (size_t)(nb + row - 128) * K + k0 + cbs * 8;
            __builtin_amdgcn_global_load_lds(
                (const __attribute__((address_space(1))) void*)g,
                (__attribute__((address_space(3))) void*)&bA[(rr * 256 + wbase) * 8],
                16, 0, 0);
        }
    };

    const int ntk = K >> 6;
    stage(0, 0);
    stage(1, 64);
    asm volatile("s_waitcnt vmcnt(6)" ::: "memory");
    __builtin_amdgcn_sched_barrier(0);
    __builtin_amdgcn_s_barrier();

    for (int t = 0; t < ntk; t++) {
        const int buf = t & 1;
        const u16* bA = &lds9[buf * 12288];
        const u16* bB = bA + 8192;
        s16x8 a[4][2], b[2][2];
#pragma unroll
        for (int mf = 0; mf < 4; mf++)
#pragma unroll
            for (int kk = 0; kk < 2; kk++) {
                int row = wm * 64 + mf * 16 + r16;
                int cb = (kk * 4 + lg) ^ (row & 7);
                a[mf][kk] = *(const s16x8*)&bA[row * 64 + cb * 8];
            }
#pragma unroll
        for (int nf = 0; nf < 2; nf++)
#pragma unroll
            for (int kk = 0; kk < 2; kk++) {
                int row = wn * 32 + nf * 16 + r16;
                int cb = (kk * 4 + lg) ^ (row & 7);
                b[nf][kk] = *(const s16x8*)&bB[row * 64 + cb * 8];
            }
        asm volatile("s_waitcnt lgkmcnt(0)" ::: "memory");
        __builtin_amdgcn_sched_barrier(0);
        __builtin_amdgcn_s_barrier();
        if (t + 2 < ntk) {
            stage(buf, (t + 2) << 6);
            asm volatile("s_waitcnt vmcnt(6)" ::: "memory");
        } else {
            asm volatile("s_waitcnt vmcnt(0)" ::: "memory");
        }
        __builtin_amdgcn_sched_barrier(0);
        __builtin_amdgcn_s_barrier();
        __builtin_amdgcn_s_setprio(1);
#pragma unroll
        for (int mf = 0; mf < 4; mf++)
#pragma unroll
            for (int nf = 0; nf < 2; nf++) {
                acc[mf][nf] = __builtin_amdgcn_mfma_f32_16x16x32_bf16(
                    a[mf][0], b[nf][0], acc[mf][nf], 0, 0, 0);
                acc[mf][nf] = __builtin_amdgcn_mfma_f32_16x16x32_bf16(
                    a[mf][1], b[nf][1], acc[mf][nf], 0, 0, 0);
            }
        __builtin_amdgcn_s_setprio(0);
    }

#pragma unroll
    for (int mf = 0; mf < 4; mf++) {
        const int rowb = mb + wm * 64 + mf * 16 + lg * 4;
#pragma unroll
        for (int nf = 0; nf < 2; nf++) {
            int col = nb + wn * 32 + nf * 16 + r16;
#pragma unroll
            for (int j = 0; j < 4; j++) {
                size_t o = (size_t)(rowb + j) * 768 + col;
                float xv = fout[o] + acc[mf][nf][j] * lsv[col];
                fout[o] = xv; bout[o] = f2bf(xv);
            }
        }
    }
}

// ---------- LDS-staged GEMM (m97 structure) + bijective XCD swizzle ----------
template<int BM, int BN, int EPI>
__global__ __launch_bounds__(256)
void gemmL(const u16* __restrict__ A, const u16* __restrict__ WT,
           int M, int N, int K,
           float* __restrict__ fout, u16* __restrict__ bout,
           const float* __restrict__ bias, const float* __restrict__ lsv,
           int ostride, int ocoloff,
           size_t aZ, size_t wZ, size_t oZ, int ocolZ)
{
    constexpr int MI = BM / 32, NI = BN / 32;
    constexpr int BUF = (BM + BN) * 32;
    constexpr int RA = BM / 64, RB = BN / 64;
    __shared__ u16 lds[2 * BUF];

    {
        int z = blockIdx.z;
        A += (size_t)z * aZ; WT += (size_t)z * wZ;
        bout += (size_t)(z >> 1) * oZ; ocoloff += (z & 1) * ocolZ;
    }

    int mt, nt;
    {
        int nwg = gridDim.x * gridDim.y;
        int f = blockIdx.y * gridDim.x + blockIdx.x;
        int q = nwg >> 3, r = nwg & 7;
        int xcd = f & 7, lo = f >> 3;
        int wid = (xcd < r ? xcd * (q + 1) : r * (q + 1) + (xcd - r) * q) + lo;
        mt = wid % gridDim.y; nt = wid / gridDim.y;
    }

    const int tid  = threadIdx.x;
    const int lane = tid & 63;
    const int wave = tid >> 6;
    const int wm = wave >> 1, wn = wave & 1;
    const int r16 = lane & 15;
    const int ks  = (lane >> 4) * 8;
    const int mb  = mt * BM;
    const int nb  = nt * BN;
    const int wbase = tid & 192;

    f32x4 acc[MI][NI];
#pragma unroll
    for (int mi = 0; mi < MI; mi++)
#pragma unroll
        for (int ni = 0; ni < NI; ni++)
            acc[mi][ni] = (f32x4){0.f, 0.f, 0.f, 0.f};

    auto stage = [&](int buf, int k0) {
        u16* bufA = &lds[buf * BUF];
        u16* bufB = &lds[buf * BUF + BM * 32];
#pragma unroll
        for (int r = 0; r < RA; r++) {
            int c = r * 256 + tid;
            const u16* g = A + (size_t)(mb + (c >> 2)) * K + k0 + (c & 3) * 8;
            __builtin_amdgcn_global_load_lds(
                (const __attribute__((address_space(1))) void*)g,
                (__attribute__((address_space(3))) void*)&bufA[(r * 256 + wbase) * 8],
                16, 0, 0);
        }
#pragma unroll
        for (int r = 0; r < RB; r++) {
            int c = r * 256 + tid;
            const u16* g = WT + (size_t)(nb + (c >> 2)) * K + k0 + (c & 3) * 8;
            __builtin_amdgcn_global_load_lds(
                (const __attribute__((address_space(1))) void*)g,
                (__attribute__((address_space(3))) void*)&bufB[(r * 256 + wbase) * 8],
                16, 0, 0);
        }
    };
    auto compute = [&](int buf) {
        const u16* bufA = &lds[buf * BUF];
        const u16* bufB = &lds[buf * BUF + BM * 32];
        s16x8 af[MI], bfr[NI];
#pragma unroll
        for (int mi = 0; mi < MI; mi++)
            af[mi] = *(const s16x8*)&bufA[(wm * (BM / 2) + mi * 16 + r16) * 32 + ks];
#pragma unroll
        for (int ni = 0; ni < NI; ni++)
            bfr[ni] = *(const s16x8*)&bufB[(wn * (BN / 2) + ni * 16 + r16) * 32 + ks];
#pragma unroll
        for (int mi = 0; mi < MI; mi++)
#pragma unroll
            for (int ni = 0; ni < NI; ni++)
                acc[mi][ni] = __builtin_amdgcn_mfma_f32_16x16x32_bf16(
                    af[mi], bfr[ni], acc[mi][ni], 0, 0, 0);
    };

    const int nt2 = K >> 5;
    stage(0, 0);
    __syncthreads();
    for (int t = 0; t < nt2; t++) {
        if (t + 1 < nt2) stage((t + 1) & 1, (t + 1) << 5);
        compute(t & 1);
        __syncthreads();
    }

#pragma unroll
    for (int mi = 0; mi < MI; mi++) {
        const int rowb = mb + wm * (BM / 2) + mi * 16 + (lane >> 4) * 4;
#pragma unroll
        for (int ni = 0; ni < NI; ni++) {
            int col = nb + wn * (BN / 2) + ni * 16 + r16;
            if (col < N) {
#pragma unroll
                for (int j = 0; j < 4; j++) {
                    int row = rowb + j;
                    float v = acc[mi][ni][j];
                    if (EPI == 0) {
                        v += bias[col];
                        size_t o = (size_t)row * ostride + col;
                        fout[o] = v; bout[o] = f2bf(v);
                    } else if (EPI == 1) {
                        bout[(size_t)row * ostride + ocoloff + col] = f2bf(v);
                    } else {
                        size_t o = (size_t)row * 768 + col;
                        float xv = fout[o] + v * lsv[col];
                        fout[o] = xv; bout[o] = f2bf(xv);
                    }
                }
            }
        }
    }
}

// ---------- softplus(dt_raw + dt_bias) ----------
__global__ void dtk(const u16* __restrict__ zxAll, float* __restrict__ dtAll,
                    const float* __restrict__ dtb)
{
    int idx = blockIdx.x * 256 + threadIdx.x;
    if (idx >= 2 * 4096 * 24) return;
    int dir = idx / (4096 * 24);
    int r   = idx % (4096 * 24);
    int row = r / 24, h = r % 24;
    float raw = bf2f(zxAll[(size_t)row * 6256 + dir * 3128 + 3104 + h]) + dtb[dir * 24 + h];
    dtAll[((size_t)dir * 4096 + row) * 24 + h] = raw > 20.f ? raw : log1pf(__expf(raw));
}

// ---------- chunked scan pass 1 (conv+silu fused) ----------
__global__ __launch_bounds__(256)
void scan1k(const u16* __restrict__ zxAll, const float* __restrict__ dtAll,
            const float* __restrict__ cw, const float* __restrict__ cb,
            const float* __restrict__ Alog, const float* __restrict__ Dhp,
            u16* __restrict__ yAll, float* __restrict__ states, float* __restrict__ decays)
{
    const int c   = blockIdx.x;
    const int bh  = blockIdx.y;
    const int dir = blockIdx.z;
    const int b = bh / 24, h = bh % 24;
    const float* dtp = dtAll + (size_t)dir * 4096 * 24;
    u16* yp = yAll + dir * 1536;
    const float Av = -__expf(Alog[dir * 24 + h]);
    const float Dv = Dhp[dir * 24 + h];
    const int inst = (dir * 2 + b) * 24 + h;

    const int tid  = threadIdx.x;
    const int lane = tid & 63;
    const int wave = tid >> 6;
    const int r16  = lane & 15;
    const int ks   = (lane >> 4) * 8;

    __shared__ u16 xT[64][72];
    __shared__ u16 Gs[64][72];
    __shared__ u16 Bs[64][40];
    __shared__ u16 Cs[64][40];
    __shared__ u16 SBT[16][72];
    __shared__ float dts[64], cds[64];

    const u16* zxd = zxAll + dir * 3128 + 1536;
    auto growp = [&](int ii) -> const u16* {
        int l = dir ? (2047 - ii) : ii;
        return zxd + ((size_t)b * 2048 + l) * 6256;
    };
    auto rowof = [&](int t) -> size_t {
        int i = c * 64 + t;
        int l = dir ? (2047 - i) : i;
        return (size_t)b * 2048 + l;
    };
    const u16x8 zz = {0,0,0,0,0,0,0,0};

    {
        int tr = tid >> 2, pg = tid & 3;
        int chb = h * 64 + pg * 16;
        int i0 = c * 64 + tr;
        u16x8 tv[4][2];
#pragma unroll
        for (int k = 0; k < 4; k++) {
            int ii = i0 - 3 + k;
            if (ii >= 0) {
                const u16* s = growp(ii) + chb;
                tv[k][0] = *(const u16x8*)s;
                tv[k][1] = *(const u16x8*)(s + 8);
            } else { tv[k][0] = zz; tv[k][1] = zz; }
        }
        const float* cwp = cw + ((size_t)dir * 1568 + chb) * 4;
        const float* cbp = cb + (size_t)dir * 1568 + chb;
#pragma unroll
        for (int j = 0; j < 16; j++) {
            f32x4 wj = *(const f32x4*)(cwp + j * 4);
            float a = cbp[j];
            int hi = j >> 3, lo2 = j & 7;
            a += bf2f(tv[0][hi][lo2]) * wj[0] + bf2f(tv[1][hi][lo2]) * wj[1]
               + bf2f(tv[2][hi][lo2]) * wj[2] + bf2f(tv[3][hi][lo2]) * wj[3];
            a = a / (1.f + __expf(-a));
            xT[pg * 16 + j][tr] = f2bf(a);
        }
    }
    {
        int t = tid & 63, which = tid >> 6;
        if (which < 2) {
            int chb = 1536 + which * 16;
            int i0 = c * 64 + t;
            u16x8 tv[4][2];
#pragma unroll
            for (int k = 0; k < 4; k++) {
                int ii = i0 - 3 + k;
                if (ii >= 0) {
                    const u16* s = growp(ii) + chb;
                    tv[k][0] = *(const u16x8*)s;
                    tv[k][1] = *(const u16x8*)(s + 8);
                } else { tv[k][0] = zz; tv[k][1] = zz; }
            }
            const float* cwp = cw + ((size_t)dir * 1568 + chb) * 4;
            const float* cbp = cb + (size_t)dir * 1568 + chb;
            u16* dst = which ? &Cs[t][0] : &Bs[t][0];
#pragma unroll
            for (int j = 0; j < 16; j++) {
                f32x4 wj = *(const f32x4*)(cwp + j * 4);
                float a = cbp[j];
                int hi = j >> 3, lo2 = j & 7;
                a += bf2f(tv[0][hi][lo2]) * wj[0] + bf2f(tv[1][hi][lo2]) * wj[1]
                   + bf2f(tv[2][hi][lo2]) * wj[2] + bf2f(tv[3][hi][lo2]) * wj[3];
                a = a / (1.f + __expf(-a));
                dst[j] = f2bf(a);
            }
        } else {
            u16* dst = (which == 2) ? &Bs[t][16] : &Cs[t][16];
            *(u16x8*)dst = zz; *(u16x8*)(dst + 8) = zz;
        }
    }
    if (tid < 64) {
        float v = dtp[rowof(tid) * 24 + h];
        dts[tid] = v;
        float s = v;
#pragma unroll
        for (int o = 1; o < 64; o <<= 1) {
            float nvl = __shfl_up(s, o, 64);
            if (lane >= o) s += nvl;
        }
        cds[tid] = s;
    }
    __syncthreads();

    {
        const s16x8 af = *(const s16x8*)&Cs[wave * 16 + r16][ks];
#pragma unroll
        for (int st = 0; st < 4; st++) {
            const s16x8 bfr = *(const s16x8*)&Bs[st * 16 + r16][ks];
            f32x4 a2 = {0.f, 0.f, 0.f, 0.f};
            a2 = __builtin_amdgcn_mfma_f32_16x16x32_bf16(af, bfr, a2, 0, 0, 0);
            int s = st * 16 + (lane & 15);
            int tbase = wave * 16 + (lane >> 4) * 4;
            float cs = cds[s], dtv = dts[s];
#pragma unroll
            for (int j = 0; j < 4; j++) {
                int t = tbase + j;
                float g = 0.f;
                if (s <= t) {
                    g = a2[j] * dtv * __expf(Av * (cds[t] - cs));
                    if (s == t) g += Dv;
                }
                Gs[t][s] = f2bf(g);
            }
        }
    }
    {
        float cdT = cds[63];
        int s = tid & 63;
        float sc = __expf(Av * (cdT - cds[s])) * dts[s];
#pragma unroll
        for (int it = 0; it < 4; it++) {
            int n = (tid >> 6) + it * 4;
            SBT[n][s] = f2bf(sc * bf2f(Bs[s][n]));
        }
    }
    __syncthreads();

    {
#pragma unroll
        for (int pt = 0; pt < 4; pt++) {
            f32x4 a2 = {0.f, 0.f, 0.f, 0.f};
#pragma unroll
            for (int kk = 0; kk < 2; kk++) {
                s16x8 af = *(const s16x8*)&Gs[wave * 16 + r16][kk * 32 + ks];
                s16x8 bfr = *(const s16x8*)&xT[pt * 16 + r16][kk * 32 + ks];
                a2 = __builtin_amdgcn_mfma_f32_16x16x32_bf16(af, bfr, a2, 0, 0, 0);
            }
            int p = pt * 16 + (lane & 15);
            int tbase = wave * 16 + (lane >> 4) * 4;
#pragma unroll
            for (int j = 0; j < 4; j++) {
                size_t row = rowof(tbase + j);
                yp[row * 3072 + h * 64 + p] = f2bf(a2[j]);
            }
        }
    }
    {
        f32x4 a2 = {0.f, 0.f, 0.f, 0.f};
#pragma unroll
        for (int kk = 0; kk < 2; kk++) {
            s16x8 af = *(const s16x8*)&xT[wave * 16 + r16][kk * 32 + ks];
            s16x8 bfr = *(const s16x8*)&SBT[r16][kk * 32 + ks];
            a2 = __builtin_amdgcn_mfma_f32_16x16x32_bf16(af, bfr, a2, 0, 0, 0);
        }
        int n = lane & 15;
        int pbase = wave * 16 + (lane >> 4) * 4;
        float* st = states + ((size_t)inst * 32 + c) * 1024;
#pragma unroll
        for (int j = 0; j < 4; j++) st[(pbase + j) * 16 + n] = a2[j];
        if (tid == 0) decays[inst * 32 + c] = __expf(Av * cds[63]);
    }
}

// ---------- chunked scan pass 2: cross-chunk recurrence ----------
__global__ __launch_bounds__(256)
void scan2k(float* __restrict__ states, const float* __restrict__ decays)
{
    int inst = blockIdx.x;
    int tid = threadIdx.x;
    float* base = states + (size_t)inst * 32 * 1024 + tid * 4;
    const float* dec = decays + inst * 32;
    f32x4 hreg = {0.f, 0.f, 0.f, 0.f};
    f32x4 L = *(f32x4*)base;
    for (int cc = 0; cc < 32; cc++) {
        f32x4 Lnext;
        if (cc + 1 < 32) Lnext = *(f32x4*)(base + (cc + 1) * 1024);
        *(f32x4*)(base + cc * 1024) = hreg;
        float d = dec[cc];
        hreg = hreg * d + L;
        L = Lnext;
    }
}

// ---------- chunked scan pass 3: y += C_t . (exp(A cd_t) h_start), conv fused ----------
__global__ __launch_bounds__(256)
void scan3k(const float* __restrict__ states,
            const u16* __restrict__ zxAll, const float* __restrict__ dtAll,
            const float* __restrict__ cw, const float* __restrict__ cb,
            const float* __restrict__ Alog, u16* __restrict__ yAll)
{
    const int c   = blockIdx.x + 1;
    const int bh  = blockIdx.y;
    const int dir = blockIdx.z;
    const int b = bh / 24, h = bh % 24;
    const float* dtp = dtAll + (size_t)dir * 4096 * 24;
    u16* yp = yAll + dir * 1536;
    const float Av = -__expf(Alog[dir * 24 + h]);
    const int inst = (dir * 2 + b) * 24 + h;
    const int tid = threadIdx.x;

    __shared__ float hs[64][20];
    __shared__ u16 Cs3[64][16];
    __shared__ float ets[64];

    const u16* zxd = zxAll + dir * 3128 + 1536;
    auto growp = [&](int ii) -> const u16* {
        int l = dir ? (2047 - ii) : ii;
        return zxd + ((size_t)b * 2048 + l) * 6256;
    };
    auto rowof = [&](int t) -> size_t {
        int i = c * 64 + t;
        int l = dir ? (2047 - i) : i;
        return (size_t)b * 2048 + l;
    };

    {
        const float* sp = states + ((size_t)inst * 32 + c) * 1024 + tid * 4;
        f32x4 v = *(const f32x4*)sp;
        int e = tid * 4;
        int p = e >> 4, n = e & 15;
        hs[p][n] = v[0]; hs[p][n+1] = v[1]; hs[p][n+2] = v[2]; hs[p][n+3] = v[3];
    }
    if (tid < 64) {
        int i0 = c * 64 + tid;
        u16x8 tv[4][2];
#pragma unroll
        for (int k = 0; k < 4; k++) {
            const u16* s = growp(i0 - 3 + k) + 1552;
            tv[k][0] = *(const u16x8*)s;
            tv[k][1] = *(const u16x8*)(s + 8);
        }
        const float* cwp = cw + ((size_t)dir * 1568 + 1552) * 4;
        const float* cbp = cb + (size_t)dir * 1568 + 1552;
#pragma unroll
        for (int j = 0; j < 16; j++) {
            f32x4 wj = *(const f32x4*)(cwp + j * 4);
            float a = cbp[j];
            int hi = j >> 3, lo2 = j & 7;
            a += bf2f(tv[0][hi][lo2]) * wj[0] + bf2f(tv[1][hi][lo2]) * wj[1]
               + bf2f(tv[2][hi][lo2]) * wj[2] + bf2f(tv[3][hi][lo2]) * wj[3];
            a = a / (1.f + __expf(-a));
            Cs3[tid][j] = f2bf(a);
        }
        float v = dtp[rowof(tid) * 24 + h];
        float s = v;
#pragma unroll
        for (int o = 1; o < 64; o <<= 1) {
            float nvl = __shfl_up(s, o, 64);
            if ((tid & 63) >= o) s += nvl;
        }
        ets[tid] = __expf(Av * s);
    }
    __syncthreads();

    int t = tid >> 2, pg = tid & 3;
    float cv[16];
    float et = ets[t];
#pragma unroll
    for (int n = 0; n < 16; n++) cv[n] = bf2f(Cs3[t][n]) * et;
    size_t row = rowof(t);
    u16* yrow = yp + row * 3072 + h * 64 + pg * 16;
    u16x8 ya = *(u16x8*)yrow;
    u16x8 yb = *(u16x8*)(yrow + 8);
#pragma unroll
    for (int jj = 0; jj < 16; jj++) {
        int p = pg * 16 + jj;
        float acc = 0.f;
#pragma unroll
        for (int q = 0; q < 4; q++) {
            f32x4 hv = *(const f32x4*)&hs[p][q * 4];
            acc += cv[q*4]*hv[0] + cv[q*4+1]*hv[1] + cv[q*4+2]*hv[2] + cv[q*4+3]*hv[3];
        }
        if (jj < 8) ya[jj] = f2bf(bf2f(ya[jj]) + acc);
        else        yb[jj - 8] = f2bf(bf2f(yb[jj - 8]) + acc);
    }
    *(u16x8*)yrow = ya;
    *(u16x8*)(yrow + 8) = yb;
}

// ---------- gating + RMSnorm ----------
__global__ __launch_bounds__(256)
void gatek(const u16* __restrict__ zxAll, u16* __restrict__ yAll,
           const float* __restrict__ nw)
{
    int row = blockIdx.x, dir = blockIdx.y;
    const u16* zx = zxAll + (size_t)row * 6256 + dir * 3128;
    u16* y = yAll + (size_t)row * 3072 + dir * 1536;
    const float* nwp = nw + dir * 1536;
    int tid = threadIdx.x;
    float g[6]; float s = 0.f;
#pragma unroll
    for (int j = 0; j < 6; j++) {
        int c = j * 256 + tid;
        float z  = bf2f(zx[c]);
        float yv = bf2f(y[c]);
        float gv = yv * z / (1.f + __expf(-z));
        g[j] = gv; s += gv * gv;
    }
    __shared__ float red[4];
    for (int o = 32; o; o >>= 1) s += __shfl_down(s, o, 64);
    if ((tid & 63) == 0) red[tid >> 6] = s;
    __syncthreads();
    s = red[0] + red[1] + red[2] + red[3];
    float sc = rsqrtf(s * (1.f / 1536.f) + 1e-5f);
#pragma unroll
    for (int j = 0; j < 6; j++) {
        int c = j * 256 + tid;
        y[c] = f2bf(g[j] * sc * nwp[c]);
    }
}

// ---------- final RMS norm ----------
__global__ __launch_bounds__(256)
void finalk(const float* __restrict__ x, const float* __restrict__ fw, float* __restrict__ out)
{
    int row = blockIdx.x; int tid = threadIdx.x;
    const float* xr = x + (size_t)row * 768;
    float v[3]; float s = 0.f;
#pragma unroll
    for (int j = 0; j < 3; j++) {
        int c = j * 256 + tid;
        v[j] = xr[c]; s += v[j] * v[j];
    }
    __shared__ float red[4];
    for (int o = 32; o; o >>= 1) s += __shfl_down(s, o, 64);
    if ((tid & 63) == 0) red[tid >> 6] = s;
    __syncthreads();
    s = red[0] + red[1] + red[2] + red[3];
    float sc = rsqrtf(s * (1.f / 768.f) + 1e-6f);
#pragma unroll
    for (int j = 0; j < 3; j++) {
        int c = j * 256 + tid;
        out[(size_t)row * 768 + c] = v[j] * sc * (1.f + fw[c]);
    }
}

// ---------- host ----------
extern "C" void kernel_launch(void* const* d_in, const int* in_sizes, int n_in,
                              void* d_out, int out_size, void* d_ws, size_t ws_size,
                              hipStream_t stream)
{
    const float* pe      = (const float*)d_in[0];
    const float* Wp      = (const float*)d_in[1];
    const float* bp      = (const float*)d_in[2];
    const float* in_w    = (const float*)d_in[3];
    const float* conv_w  = (const float*)d_in[4];
    const float* conv_b  = (const float*)d_in[5];
    const float* dt_bias = (const float*)d_in[6];
    const float* A_log   = (const float*)d_in[7];
    const float* Dh      = (const float*)d_in[8];
    const float* norm_w  = (const float*)d_in[9];
    const float* out_w   = (const float*)d_in[10];
    const float* bi_w    = (const float*)d_in[11];
    const float* ls      = (const float*)d_in[12];
    const float* fin_w   = (const float*)d_in[13];

    char* wp = (char*)d_ws;
    auto alloc = [&](size_t bytes) {
        char* r = wp; wp += (bytes + 255) & ~(size_t)255; return r;
    };
    u16*   WpT    = (u16*)  alloc((size_t)768 * 256 * 2);
    u16*   inWT   = (u16*)  alloc((size_t)2 * 6272 * 768 * 2);
    u16*   outWB  = (u16*)  alloc((size_t)4 * 1536 * 768 * 2);
    u16*   biWT   = (u16*)  alloc((size_t)4 * 768 * 768 * 2);
    u16*   WcombT = (u16*)  alloc((size_t)2 * 768 * 3072 * 2);
    u16*   peB    = (u16*)  alloc((size_t)4096 * 256 * 2);
    float* x      = (float*)alloc((size_t)4096 * 768 * 4);
    u16*   xb     = (u16*)  alloc((size_t)4096 * 768 * 2);
    u16*   zxAll  = (u16*)  alloc((size_t)4096 * 6256 * 2);
    float* dtAll  = (float*)alloc((size_t)2 * 4096 * 24 * 4);
    u16*   yAll   = (u16*)  alloc((size_t)4096 * 3072 * 2);
    float* states = (float*)alloc((size_t)96 * 32 * 1024 * 4);
    float* decays = (float*)alloc((size_t)96 * 32 * 4);

    // ---- weight prep (batched over z) ----
    wtransT<<<dim3(24, 8, 1), 256, 0, stream>>>(Wp, WpT, 256, 768, 256, 0, 0, 0);
    wtransT<<<dim3(98, 24, 4), 256, 0, stream>>>(in_w, inWT, 768, 3128, 768,
                                                 2402304, 4816896, 2402304);
    wtransT<<<dim3(24, 24, 4), 256, 0, stream>>>(bi_w, biWT, 768, 768, 768,
                                                 589824, 1179648, 589824);
    cvtk<<<(4 * 1536 * 768 + 255) / 256, 256, 0, stream>>>(out_w, outWB, 4 * 1536 * 768);
    cvtk<<<4096, 256, 0, stream>>>(pe, peB, 4096 * 256);

    // ---- Wcomb (batched) ----
    gemmL<64, 64, 1><<<dim3(24, 12, 4), 256, 0, stream>>>(
        biWT, outWB, 768, 1536, 768, nullptr, WcombT,
        nullptr, nullptr, 3072, 0,
        (size_t)589824, (size_t)1179648, (size_t)768 * 3072, 1536);

    // ---- patch embedding GEMM ----
    gemmL<64, 64, 0><<<dim3(12, 64, 1), 256, 0, stream>>>(
        peB, WpT, 4096, 768, 256, x, xb, bp, nullptr, 768, 0, 0, 0, 0, 0);

    for (int i = 0; i < 2; i++) {
        // merged in_proj (both dirs), verbatim r5 pipelined GEMM
        gemm8<<<dim3(49, 32, 1), 256, 0, stream>>>(
            xb, inWT + (size_t)i * 6272 * 768, 4096, 6256, 768, zxAll, 6256);
        dtk<<<(2 * 4096 * 24 + 255) / 256, 256, 0, stream>>>(zxAll, dtAll, dt_bias + i * 48);
        scan1k<<<dim3(32, 48, 2), 256, 0, stream>>>(zxAll, dtAll,
                                                    conv_w + (size_t)i * 2 * 1568 * 4,
                                                    conv_b + (size_t)i * 2 * 1568,
                                                    A_log + i * 48, Dh + i * 48,
                                                    yAll, states, decays);
        scan2k<<<96, 256, 0, stream>>>(states, decays);
        scan3k<<<dim3(31, 48, 2), 256, 0, stream>>>(states, zxAll, dtAll,
                                                    conv_w + (size_t)i * 2 * 1568 * 4,
                                                    conv_b + (size_t)i * 2 * 1568,
                                                    A_log + i * 48, yAll);
        gatek<<<dim3(4096, 2), 256, 0, stream>>>(zxAll, yAll, norm_w + (size_t)i * 2 * 1536);
        // fused out_proj + concat + bi_w + residual (pipelined 128x64)
        gemm9<<<dim3(12, 32, 1), 256, 0, stream>>>(
            yAll, WcombT + (size_t)i * 768 * 3072, 3072, x, xb, ls + i * 768);
    }

    finalk<<<4096, 256, 0, stream>>>(x, fin_w, (float*)d_out);
}

// Round 10
// 475.243 us; speedup vs baseline: 1.1074x; 1.0486x over previous
//
#include <hip/hip_runtime.h>

typedef unsigned short u16;
typedef short s16x8 __attribute__((ext_vector_type(8)));
typedef u16 u16x8 __attribute__((ext_vector_type(8)));
typedef float f32x4 __attribute__((ext_vector_type(4)));

// ---------- helpers ----------
__device__ inline float bf2f(u16 u) {
    union { unsigned int i; float f; } w; w.i = ((unsigned int)u) << 16; return w.f;
}
__device__ inline u16 f2bf(float f) {
    union { float f; unsigned int i; } w; w.f = f;
    unsigned int u = w.i;
    u += 0x7fffu + ((u >> 16) & 1u);
    return (u16)(u >> 16);
}

// ---------- tiled transpose + bf16: dst[n*dstride+k] = bf16(src[k*N+n]) ----------
__global__ __launch_bounds__(256)
void wtransT(const float* __restrict__ src, u16* __restrict__ dst,
             int K, int N, int dstride, int src_z, int dz_hi, int dz_lo)
{
    int z = blockIdx.z;
    src += (size_t)z * src_z;
    dst += (size_t)(z >> 1) * dz_hi + (size_t)(z & 1) * dz_lo;
    __shared__ float t[32][33];
    int kt = blockIdx.y * 32, nt0 = blockIdx.x * 32;
    int lx = threadIdx.x & 31, ly = threadIdx.x >> 5;   // 32 x 8
#pragma unroll
    for (int i = 0; i < 32; i += 8) {
        int k = kt + ly + i, n = nt0 + lx;
        t[ly + i][lx] = (k < K && n < N) ? src[(size_t)k * N + n] : 0.f;
    }
    __syncthreads();
#pragma unroll
    for (int i = 0; i < 32; i += 8) {
        int n = nt0 + ly + i, k = kt + lx;
        if (n < N && k < K) dst[(size_t)n * dstride + k] = f2bf(t[lx][ly + i]);
    }
}

// ---------- plain f32 -> bf16 convert ----------
__global__ void cvtk(const float* __restrict__ src, u16* __restrict__ dst, int n) {
    int i = blockIdx.x * 256 + threadIdx.x;
    if (i < n) dst[i] = f2bf(src[i]);
}

// ---------- pipelined GEMM (verbatim r5 config): counted vmcnt, 2-tile lookahead ----------
// C[M,N] = A[M,K] @ WT[N,K]^T ; bf16 out: bout[row*ostride+col].
// BM=BN=128, BK=64, 256 threads (4 waves 2x2), 2 LDS buffers (64 KB).
__global__ __launch_bounds__(256, 2)
void gemm8(const u16* __restrict__ A, const u16* __restrict__ WT,
           int M, int N, int K,
           u16* __restrict__ bout, int ostride)
{
    __shared__ u16 lds8[2 * 16384];          // [buf][A:8192 | B:8192] u16

    // bijective XCD swizzle (m204), wid m-fastest
    int mt, nt;
    {
        int nwg = gridDim.x * gridDim.y;
        int f = blockIdx.y * gridDim.x + blockIdx.x;
        int q = nwg >> 3, r = nwg & 7;
        int xcd = f & 7, lo = f >> 3;
        int wid = (xcd < r ? xcd * (q + 1) : r * (q + 1) + (xcd - r) * q) + lo;
        mt = wid % gridDim.y; nt = wid / gridDim.y;
    }

    const int tid  = threadIdx.x;
    const int lane = tid & 63;
    const int wave = tid >> 6;
    const int wm = wave >> 1, wn = wave & 1;
    const int r16 = lane & 15;
    const int lg  = lane >> 4;               // 0..3
    const int mb  = mt * 128;
    const int nb  = nt * 128;
    const int wbase = tid & 192;

    f32x4 acc[4][4];
#pragma unroll
    for (int mi = 0; mi < 4; mi++)
#pragma unroll
        for (int ni = 0; ni < 4; ni++)
            acc[mi][ni] = (f32x4){0.f, 0.f, 0.f, 0.f};

    auto stage = [&](int buf, int k0) {
        u16* bA = &lds8[buf * 16384];
        u16* bB = bA + 8192;
#pragma unroll
        for (int r = 0; r < 4; r++) {
            int e = r * 256 + tid;
            int row = e >> 3;
            int cbs = (e & 7) ^ (row & 7);
            const u16* g = A + (size_t)(mb + row) * K + k0 + cbs * 8;
            __builtin_amdgcn_global_load_lds(
                (const __attribute__((address_space(1))) void*)g,
                (__attribute__((address_space(3))) void*)&bA[(r * 256 + wbase) * 8],
                16, 0, 0);
        }
#pragma unroll
        for (int r = 0; r < 4; r++) {
            int e = r * 256 + tid;
            int row = e >> 3;
            int cbs = (e & 7) ^ (row & 7);
            const u16* g = WT + (size_t)(nb + row) * K + k0 + cbs * 8;
            __builtin_amdgcn_global_load_lds(
                (const __attribute__((address_space(1))) void*)g,
                (__attribute__((address_space(3))) void*)&bB[(r * 256 + wbase) * 8],
                16, 0, 0);
        }
    };

    const int ntk = K >> 6;                  // K-tiles of 64
    stage(0, 0);
    stage(1, 64);
    asm volatile("s_waitcnt vmcnt(8)" ::: "memory");
    __builtin_amdgcn_sched_barrier(0);
    __builtin_amdgcn_s_barrier();

    for (int t = 0; t < ntk; t++) {
        const int buf = t & 1;
        const u16* bA = &lds8[buf * 16384];
        const u16* bB = bA + 8192;
        s16x8 a[4][2], b[4][2];
#pragma unroll
        for (int mf = 0; mf < 4; mf++)
#pragma unroll
            for (int kk = 0; kk < 2; kk++) {
                int row = wm * 64 + mf * 16 + r16;
                int cb = (kk * 4 + lg) ^ (row & 7);
                a[mf][kk] = *(const s16x8*)&bA[row * 64 + cb * 8];
            }
#pragma unroll
        for (int nf = 0; nf < 4; nf++)
#pragma unroll
            for (int kk = 0; kk < 2; kk++) {
                int row = wn * 64 + nf * 16 + r16;
                int cb = (kk * 4 + lg) ^ (row & 7);
                b[nf][kk] = *(const s16x8*)&bB[row * 64 + cb * 8];
            }
        asm volatile("s_waitcnt lgkmcnt(0)" ::: "memory");
        __builtin_amdgcn_sched_barrier(0);
        __builtin_amdgcn_s_barrier();        // all waves done reading buf
        if (t + 2 < ntk) {
            stage(buf, (t + 2) << 6);        // overwrite just-read buffer
            asm volatile("s_waitcnt vmcnt(8)" ::: "memory");  // tile t+1 complete
        } else {
            asm volatile("s_waitcnt vmcnt(0)" ::: "memory");
        }
        __builtin_amdgcn_sched_barrier(0);
        __builtin_amdgcn_s_barrier();        // buf[t^1] ready for next iter
        __builtin_amdgcn_s_setprio(1);
#pragma unroll
        for (int mf = 0; mf < 4; mf++)
#pragma unroll
            for (int nf = 0; nf < 4; nf++) {
                acc[mf][nf] = __builtin_amdgcn_mfma_f32_16x16x32_bf16(
                    a[mf][0], b[nf][0], acc[mf][nf], 0, 0, 0);
                acc[mf][nf] = __builtin_amdgcn_mfma_f32_16x16x32_bf16(
                    a[mf][1], b[nf][1], acc[mf][nf], 0, 0, 0);
            }
        __builtin_amdgcn_s_setprio(0);
    }

#pragma unroll
    for (int mf = 0; mf < 4; mf++) {
        const int rowb = mb + wm * 64 + mf * 16 + lg * 4;
#pragma unroll
        for (int nf = 0; nf < 4; nf++) {
            int col = nb + wn * 64 + nf * 16 + r16;
            if (col < N) {
#pragma unroll
                for (int j = 0; j < 4; j++)
                    bout[(size_t)(rowb + j) * ostride + col] = f2bf(acc[mf][nf][j]);
            }
        }
    }
}

// ---------- pipelined GEMM 128x64, EPI2 (out_proj fused residual), standalone ----------
// xv = fout[row*768+col] + v*lsv[col]; fout=xv; bout[row*768+col]=bf16(xv)
__global__ __launch_bounds__(256, 2)
void gemm9(const u16* __restrict__ A, const u16* __restrict__ WT, int K,
           float* __restrict__ fout, u16* __restrict__ bout,
           const float* __restrict__ lsv)
{
    __shared__ u16 lds9[2 * 12288];          // [buf][A:8192 | B:4096] u16

    int mt, nt;
    {
        int nwg = gridDim.x * gridDim.y;
        int f = blockIdx.y * gridDim.x + blockIdx.x;
        int q = nwg >> 3, r = nwg & 7;
        int xcd = f & 7, lo = f >> 3;
        int wid = (xcd < r ? xcd * (q + 1) : r * (q + 1) + (xcd - r) * q) + lo;
        mt = wid % gridDim.y; nt = wid / gridDim.y;
    }

    const int tid  = threadIdx.x;
    const int lane = tid & 63;
    const int wave = tid >> 6;
    const int wm = wave >> 1, wn = wave & 1;
    const int r16 = lane & 15;
    const int lg  = lane >> 4;
    const int mb  = mt * 128;
    const int nb  = nt * 64;
    const int wbase = tid & 192;

    f32x4 acc[4][2];
#pragma unroll
    for (int mi = 0; mi < 4; mi++)
#pragma unroll
        for (int ni = 0; ni < 2; ni++)
            acc[mi][ni] = (f32x4){0.f, 0.f, 0.f, 0.f};

    auto stage = [&](int buf, int k0) {
        u16* bA = &lds9[buf * 12288];
#pragma unroll
        for (int rr = 0; rr < 6; rr++) {
            int e = rr * 256 + tid;
            int row = e >> 3;
            int cbs = (e & 7) ^ (row & 7);
            const u16* g = (rr < 4)
                ? A  + (size_t)(mb + row) * K + k0 + cbs * 8
                : WT + (size_t)(nb + row - 128) * K + k0 + cbs * 8;
            __builtin_amdgcn_global_load_lds(
                (const __attribute__((address_space(1))) void*)g,
                (__attribute__((address_space(3))) void*)&bA[(rr * 256 + wbase) * 8],
                16, 0, 0);
        }
    };

    const int ntk = K >> 6;
    stage(0, 0);
    stage(1, 64);
    asm volatile("s_waitcnt vmcnt(6)" ::: "memory");
    __builtin_amdgcn_sched_barrier(0);
    __builtin_amdgcn_s_barrier();

    for (int t = 0; t < ntk; t++) {
        const int buf = t & 1;
        const u16* bA = &lds9[buf * 12288];
        const u16* bB = bA + 8192;
        s16x8 a[4][2], b[2][2];
#pragma unroll
        for (int mf = 0; mf < 4; mf++)
#pragma unroll
            for (int kk = 0; kk < 2; kk++) {
                int row = wm * 64 + mf * 16 + r16;
                int cb = (kk * 4 + lg) ^ (row & 7);
                a[mf][kk] = *(const s16x8*)&bA[row * 64 + cb * 8];
            }
#pragma unroll
        for (int nf = 0; nf < 2; nf++)
#pragma unroll
            for (int kk = 0; kk < 2; kk++) {
                int row = wn * 32 + nf * 16 + r16;
                int cb = (kk * 4 + lg) ^ (row & 7);
                b[nf][kk] = *(const s16x8*)&bB[row * 64 + cb * 8];
            }
        asm volatile("s_waitcnt lgkmcnt(0)" ::: "memory");
        __builtin_amdgcn_sched_barrier(0);
        __builtin_amdgcn_s_barrier();
        if (t + 2 < ntk) {
            stage(buf, (t + 2) << 6);
            asm volatile("s_waitcnt vmcnt(6)" ::: "memory");
        } else {
            asm volatile("s_waitcnt vmcnt(0)" ::: "memory");
        }
        __builtin_amdgcn_sched_barrier(0);
        __builtin_amdgcn_s_barrier();
        __builtin_amdgcn_s_setprio(1);
#pragma unroll
        for (int mf = 0; mf < 4; mf++)
#pragma unroll
            for (int nf = 0; nf < 2; nf++) {
                acc[mf][nf] = __builtin_amdgcn_mfma_f32_16x16x32_bf16(
                    a[mf][0], b[nf][0], acc[mf][nf], 0, 0, 0);
                acc[mf][nf] = __builtin_amdgcn_mfma_f32_16x16x32_bf16(
                    a[mf][1], b[nf][1], acc[mf][nf], 0, 0, 0);
            }
        __builtin_amdgcn_s_setprio(0);
    }

#pragma unroll
    for (int mf = 0; mf < 4; mf++) {
        const int rowb = mb + wm * 64 + mf * 16 + lg * 4;
#pragma unroll
        for (int nf = 0; nf < 2; nf++) {
            int col = nb + wn * 32 + nf * 16 + r16;
#pragma unroll
            for (int j = 0; j < 4; j++) {
                size_t o = (size_t)(rowb + j) * 768 + col;
                float xv = fout[o] + acc[mf][nf][j] * lsv[col];
                fout[o] = xv; bout[o] = f2bf(xv);
            }
        }
    }
}

// ---------- pipelined GEMM 128x64, batched (Wcomb), plain bf16 out with col offset ----------
// z: A += z*aZ; WT += z*wZ; out row m: bout[(z>>1)*oZ + m*ostride + (z&1)*ocolZ + col]
__global__ __launch_bounds__(256, 2)
void gemm10(const u16* __restrict__ A, const u16* __restrict__ WT, int K,
            u16* __restrict__ bout, int ostride,
            size_t aZ, size_t wZ, size_t oZ, int ocolZ)
{
    __shared__ u16 ldsA[2 * 12288];

    {
        int z = blockIdx.z;
        A += (size_t)z * aZ; WT += (size_t)z * wZ;
        bout += (size_t)(z >> 1) * oZ + (size_t)(z & 1) * ocolZ;
    }
    int mt, nt;
    {
        int nwg = gridDim.x * gridDim.y;
        int f = blockIdx.y * gridDim.x + blockIdx.x;
        int q = nwg >> 3, r = nwg & 7;
        int xcd = f & 7, lo = f >> 3;
        int wid = (xcd < r ? xcd * (q + 1) : r * (q + 1) + (xcd - r) * q) + lo;
        mt = wid % gridDim.y; nt = wid / gridDim.y;
    }

    const int tid  = threadIdx.x;
    const int lane = tid & 63;
    const int wave = tid >> 6;
    const int wm = wave >> 1, wn = wave & 1;
    const int r16 = lane & 15;
    const int lg  = lane >> 4;
    const int mb  = mt * 128;
    const int nb  = nt * 64;
    const int wbase = tid & 192;

    f32x4 acc[4][2];
#pragma unroll
    for (int mi = 0; mi < 4; mi++)
#pragma unroll
        for (int ni = 0; ni < 2; ni++)
            acc[mi][ni] = (f32x4){0.f, 0.f, 0.f, 0.f};

    auto stage = [&](int buf, int k0) {
        u16* bA = &ldsA[buf * 12288];
#pragma unroll
        for (int rr = 0; rr < 6; rr++) {
            int e = rr * 256 + tid;
            int row = e >> 3;
            int cbs = (e & 7) ^ (row & 7);
            const u16* g = (rr < 4)
                ? A  + (size_t)(mb + row) * K + k0 + cbs * 8
                : WT + (size_t)(nb + row - 128) * K + k0 + cbs * 8;
            __builtin_amdgcn_global_load_lds(
                (const __attribute__((address_space(1))) void*)g,
                (__attribute__((address_space(3))) void*)&bA[(rr * 256 + wbase) * 8],
                16, 0, 0);
        }
    };

    const int ntk = K >> 6;
    stage(0, 0);
    stage(1, 64);
    asm volatile("s_waitcnt vmcnt(6)" ::: "memory");
    __builtin_amdgcn_sched_barrier(0);
    __builtin_amdgcn_s_barrier();

    for (int t = 0; t < ntk; t++) {
        const int buf = t & 1;
        const u16* bA = &ldsA[buf * 12288];
        const u16* bB = bA + 8192;
        s16x8 a[4][2], b[2][2];
#pragma unroll
        for (int mf = 0; mf < 4; mf++)
#pragma unroll
            for (int kk = 0; kk < 2; kk++) {
                int row = wm * 64 + mf * 16 + r16;
                int cb = (kk * 4 + lg) ^ (row & 7);
                a[mf][kk] = *(const s16x8*)&bA[row * 64 + cb * 8];
            }
#pragma unroll
        for (int nf = 0; nf < 2; nf++)
#pragma unroll
            for (int kk = 0; kk < 2; kk++) {
                int row = wn * 32 + nf * 16 + r16;
                int cb = (kk * 4 + lg) ^ (row & 7);
                b[nf][kk] = *(const s16x8*)&bB[row * 64 + cb * 8];
            }
        asm volatile("s_waitcnt lgkmcnt(0)" ::: "memory");
        __builtin_amdgcn_sched_barrier(0);
        __builtin_amdgcn_s_barrier();
        if (t + 2 < ntk) {
            stage(buf, (t + 2) << 6);
            asm volatile("s_waitcnt vmcnt(6)" ::: "memory");
        } else {
            asm volatile("s_waitcnt vmcnt(0)" ::: "memory");
        }
        __builtin_amdgcn_sched_barrier(0);
        __builtin_amdgcn_s_barrier();
        __builtin_amdgcn_s_setprio(1);
#pragma unroll
        for (int mf = 0; mf < 4; mf++)
#pragma unroll
            for (int nf = 0; nf < 2; nf++) {
                acc[mf][nf] = __builtin_amdgcn_mfma_f32_16x16x32_bf16(
                    a[mf][0], b[nf][0], acc[mf][nf], 0, 0, 0);
                acc[mf][nf] = __builtin_amdgcn_mfma_f32_16x16x32_bf16(
                    a[mf][1], b[nf][1], acc[mf][nf], 0, 0, 0);
            }
        __builtin_amdgcn_s_setprio(0);
    }

#pragma unroll
    for (int mf = 0; mf < 4; mf++) {
        const int rowb = mb + wm * 64 + mf * 16 + lg * 4;
#pragma unroll
        for (int nf = 0; nf < 2; nf++) {
            int col = nb + wn * 32 + nf * 16 + r16;
#pragma unroll
            for (int j = 0; j < 4; j++)
                bout[(size_t)(rowb + j) * ostride + col] = f2bf(acc[mf][nf][j]);
        }
    }
}

// ---------- pipelined GEMM 128x64 (patch): v += bias; f32 + bf16 out ----------
__global__ __launch_bounds__(256, 2)
void gemm11(const u16* __restrict__ A, const u16* __restrict__ WT, int K,
            float* __restrict__ fout, u16* __restrict__ bout,
            const float* __restrict__ bias)
{
    __shared__ u16 ldsB[2 * 12288];

    int mt, nt;
    {
        int nwg = gridDim.x * gridDim.y;
        int f = blockIdx.y * gridDim.x + blockIdx.x;
        int q = nwg >> 3, r = nwg & 7;
        int xcd = f & 7, lo = f >> 3;
        int wid = (xcd < r ? xcd * (q + 1) : r * (q + 1) + (xcd - r) * q) + lo;
        mt = wid % gridDim.y; nt = wid / gridDim.y;
    }

    const int tid  = threadIdx.x;
    const int lane = tid & 63;
    const int wave = tid >> 6;
    const int wm = wave >> 1, wn = wave & 1;
    const int r16 = lane & 15;
    const int lg  = lane >> 4;
    const int mb  = mt * 128;
    const int nb  = nt * 64;
    const int wbase = tid & 192;

    f32x4 acc[4][2];
#pragma unroll
    for (int mi = 0; mi < 4; mi++)
#pragma unroll
        for (int ni = 0; ni < 2; ni++)
            acc[mi][ni] = (f32x4){0.f, 0.f, 0.f, 0.f};

    auto stage = [&](int buf, int k0) {
        u16* bA = &ldsB[buf * 12288];
#pragma unroll
        for (int rr = 0; rr < 6; rr++) {
            int e = rr * 256 + tid;
            int row = e >> 3;
            int cbs = (e & 7) ^ (row & 7);
            const u16* g = (rr < 4)
                ? A  + (size_t)(mb + row) * K + k0 + cbs * 8
                : WT + (size_t)(nb + row - 128) * K + k0 + cbs * 8;
            __builtin_amdgcn_global_load_lds(
                (const __attribute__((address_space(1))) void*)g,
                (__attribute__((address_space(3))) void*)&bA[(rr * 256 + wbase) * 8],
                16, 0, 0);
        }
    };

    const int ntk = K >> 6;
    stage(0, 0);
    stage(1, 64);
    asm volatile("s_waitcnt vmcnt(6)" ::: "memory");
    __builtin_amdgcn_sched_barrier(0);
    __builtin_amdgcn_s_barrier();

    for (int t = 0; t < ntk; t++) {
        const int buf = t & 1;
        const u16* bA = &ldsB[buf * 12288];
        const u16* bB = bA + 8192;
        s16x8 a[4][2], b[2][2];
#pragma unroll
        for (int mf = 0; mf < 4; mf++)
#pragma unroll
            for (int kk = 0; kk < 2; kk++) {
                int row = wm * 64 + mf * 16 + r16;
                int cb = (kk * 4 + lg) ^ (row & 7);
                a[mf][kk] = *(const s16x8*)&bA[row * 64 + cb * 8];
            }
#pragma unroll
        for (int nf = 0; nf < 2; nf++)
#pragma unroll
            for (int kk = 0; kk < 2; kk++) {
                int row = wn * 32 + nf * 16 + r16;
                int cb = (kk * 4 + lg) ^ (row & 7);
                b[nf][kk] = *(const s16x8*)&bB[row * 64 + cb * 8];
            }
        asm volatile("s_waitcnt lgkmcnt(0)" ::: "memory");
        __builtin_amdgcn_sched_barrier(0);
        __builtin_amdgcn_s_barrier();
        if (t + 2 < ntk) {
            stage(buf, (t + 2) << 6);
            asm volatile("s_waitcnt vmcnt(6)" ::: "memory");
        } else {
            asm volatile("s_waitcnt vmcnt(0)" ::: "memory");
        }
        __builtin_amdgcn_sched_barrier(0);
        __builtin_amdgcn_s_barrier();
        __builtin_amdgcn_s_setprio(1);
#pragma unroll
        for (int mf = 0; mf < 4; mf++)
#pragma unroll
            for (int nf = 0; nf < 2; nf++) {
                acc[mf][nf] = __builtin_amdgcn_mfma_f32_16x16x32_bf16(
                    a[mf][0], b[nf][0], acc[mf][nf], 0, 0, 0);
                acc[mf][nf] = __builtin_amdgcn_mfma_f32_16x16x32_bf16(
                    a[mf][1], b[nf][1], acc[mf][nf], 0, 0, 0);
            }
        __builtin_amdgcn_s_setprio(0);
    }

#pragma unroll
    for (int mf = 0; mf < 4; mf++) {
        const int rowb = mb + wm * 64 + mf * 16 + lg * 4;
#pragma unroll
        for (int nf = 0; nf < 2; nf++) {
            int col = nb + wn * 32 + nf * 16 + r16;
#pragma unroll
            for (int j = 0; j < 4; j++) {
                float v = acc[mf][nf][j] + bias[col];
                size_t o = (size_t)(rowb + j) * 768 + col;
                fout[o] = v; bout[o] = f2bf(v);
            }
        }
    }
}

// ---------- preK: dt softplus + conv'd B/C (bit-identical to old in-scan conv) ----------
__global__ void preK(const u16* __restrict__ zxAll, float* __restrict__ dtAll,
                     u16* __restrict__ bcAll, const float* __restrict__ dtb,
                     const float* __restrict__ cw, const float* __restrict__ cb)
{
    int idx = blockIdx.x * 256 + threadIdx.x;
    if (idx < 2 * 4096 * 24) {
        int dir = idx / (4096 * 24);
        int r   = idx % (4096 * 24);
        int row = r / 24, h = r % 24;
        float raw = bf2f(zxAll[(size_t)row * 6256 + dir * 3128 + 3104 + h]) + dtb[dir * 24 + h];
        dtAll[((size_t)dir * 4096 + row) * 24 + h] = raw > 20.f ? raw : log1pf(__expf(raw));
        return;
    }
    int v = idx - 2 * 4096 * 24;
    if (v >= 2 * 4096 * 32) return;
    int ch  = v & 31;
    int row = (v >> 5) & 4095;
    int dir = v >> 17;
    int l   = row & 2047;
    int chg = 1536 + ch;
    float acc = cb[dir * 1568 + chg];
    const float* w = cw + ((size_t)dir * 1568 + chg) * 4;
#pragma unroll
    for (int k = 0; k < 4; k++) {
        int ll = dir ? (l + 3 - k) : (l - 3 + k);
        if (ll >= 0 && ll < 2048)
            acc += bf2f(zxAll[(size_t)(row + (ll - l)) * 6256 + dir * 3128 + chg]) * w[k];
    }
    acc = acc / (1.f + __expf(-acc));
    bcAll[((size_t)dir * 4096 + row) * 32 + ch] = f2bf(acc);
}

// ---------- chunked scan pass 1 (x-conv fused; B/C from bcAll) ----------
__global__ __launch_bounds__(256)
void scan1k(const u16* __restrict__ zxAll, const float* __restrict__ dtAll,
            const u16* __restrict__ bcAll,
            const float* __restrict__ cw, const float* __restrict__ cb,
            const float* __restrict__ Alog, const float* __restrict__ Dhp,
            u16* __restrict__ yAll, float* __restrict__ states, float* __restrict__ decays)
{
    const int c   = blockIdx.x;
    const int bh  = blockIdx.y;
    const int dir = blockIdx.z;
    const int b = bh / 24, h = bh % 24;
    const float* dtp = dtAll + (size_t)dir * 4096 * 24;
    const u16* bcp = bcAll + (size_t)dir * 4096 * 32;
    u16* yp = yAll + dir * 1536;
    const float Av = -__expf(Alog[dir * 24 + h]);
    const float Dv = Dhp[dir * 24 + h];
    const int inst = (dir * 2 + b) * 24 + h;

    const int tid  = threadIdx.x;
    const int lane = tid & 63;
    const int wave = tid >> 6;
    const int r16  = lane & 15;
    const int ks   = (lane >> 4) * 8;

    __shared__ u16 xT[64][72];
    __shared__ u16 Gs[64][72];
    __shared__ u16 Bs[64][40];
    __shared__ u16 Cs[64][40];
    __shared__ u16 SBT[16][72];
    __shared__ float dts[64], cds[64];

    const u16* zxd = zxAll + dir * 3128 + 1536;
    auto growp = [&](int ii) -> const u16* {
        int l = dir ? (2047 - ii) : ii;
        return zxd + ((size_t)b * 2048 + l) * 6256;
    };
    auto rowof = [&](int t) -> size_t {
        int i = c * 64 + t;
        int l = dir ? (2047 - i) : i;
        return (size_t)b * 2048 + l;
    };
    const u16x8 zz = {0,0,0,0,0,0,0,0};

    {
        int tr = tid >> 2, pg = tid & 3;
        int chb = h * 64 + pg * 16;
        int i0 = c * 64 + tr;
        u16x8 tv[4][2];
#pragma unroll
        for (int k = 0; k < 4; k++) {
            int ii = i0 - 3 + k;
            if (ii >= 0) {
                const u16* s = growp(ii) + chb;
                tv[k][0] = *(const u16x8*)s;
                tv[k][1] = *(const u16x8*)(s + 8);
            } else { tv[k][0] = zz; tv[k][1] = zz; }
        }
        const float* cwp = cw + ((size_t)dir * 1568 + chb) * 4;
        const float* cbp = cb + (size_t)dir * 1568 + chb;
#pragma unroll
        for (int j = 0; j < 16; j++) {
            f32x4 wj = *(const f32x4*)(cwp + j * 4);
            float a = cbp[j];
            int hi = j >> 3, lo2 = j & 7;
            a += bf2f(tv[0][hi][lo2]) * wj[0] + bf2f(tv[1][hi][lo2]) * wj[1]
               + bf2f(tv[2][hi][lo2]) * wj[2] + bf2f(tv[3][hi][lo2]) * wj[3];
            a = a / (1.f + __expf(-a));
            xT[pg * 16 + j][tr] = f2bf(a);
        }
    }
    {
        int t = tid & 63, which = tid >> 6;
        if (which < 2) {
            const u16* src = bcp + rowof(t) * 32 + which * 16;
            u16* dst = which ? &Cs[t][0] : &Bs[t][0];
            *(u16x8*)dst = *(const u16x8*)src;
            *(u16x8*)(dst + 8) = *(const u16x8*)(src + 8);
        } else {
            u16* dst = (which == 2) ? &Bs[t][16] : &Cs[t][16];
            *(u16x8*)dst = zz; *(u16x8*)(dst + 8) = zz;
        }
    }
    if (tid < 64) {
        float v = dtp[rowof(tid) * 24 + h];
        dts[tid] = v;
        float s = v;
#pragma unroll
        for (int o = 1; o < 64; o <<= 1) {
            float nvl = __shfl_up(s, o, 64);
            if (lane >= o) s += nvl;
        }
        cds[tid] = s;
    }
    __syncthreads();

    {
        const s16x8 af = *(const s16x8*)&Cs[wave * 16 + r16][ks];
#pragma unroll
        for (int st = 0; st < 4; st++) {
            const s16x8 bfr = *(const s16x8*)&Bs[st * 16 + r16][ks];
            f32x4 a2 = {0.f, 0.f, 0.f, 0.f};
            a2 = __builtin_amdgcn_mfma_f32_16x16x32_bf16(af, bfr, a2, 0, 0, 0);
            int s = st * 16 + (lane & 15);
            int tbase = wave * 16 + (lane >> 4) * 4;
            float cs = cds[s], dtv = dts[s];
#pragma unroll
            for (int j = 0; j < 4; j++) {
                int t = tbase + j;
                float g = 0.f;
                if (s <= t) {
                    g = a2[j] * dtv * __expf(Av * (cds[t] - cs));
                    if (s == t) g += Dv;
                }
                Gs[t][s] = f2bf(g);
            }
        }
    }
    {
        float cdT = cds[63];
        int s = tid & 63;
        float sc = __expf(Av * (cdT - cds[s])) * dts[s];
#pragma unroll
        for (int it = 0; it < 4; it++) {
            int n = (tid >> 6) + it * 4;
            SBT[n][s] = f2bf(sc * bf2f(Bs[s][n]));
        }
    }
    __syncthreads();

    {
#pragma unroll
        for (int pt = 0; pt < 4; pt++) {
            f32x4 a2 = {0.f, 0.f, 0.f, 0.f};
#pragma unroll
            for (int kk = 0; kk < 2; kk++) {
                s16x8 af = *(const s16x8*)&Gs[wave * 16 + r16][kk * 32 + ks];
                s16x8 bfr = *(const s16x8*)&xT[pt * 16 + r16][kk * 32 + ks];
                a2 = __builtin_amdgcn_mfma_f32_16x16x32_bf16(af, bfr, a2, 0, 0, 0);
            }
            int p = pt * 16 + (lane & 15);
            int tbase = wave * 16 + (lane >> 4) * 4;
#pragma unroll
            for (int j = 0; j < 4; j++) {
                size_t row = rowof(tbase + j);
                yp[row * 3072 + h * 64 + p] = f2bf(a2[j]);
            }
        }
    }
    {
        f32x4 a2 = {0.f, 0.f, 0.f, 0.f};
#pragma unroll
        for (int kk = 0; kk < 2; kk++) {
            s16x8 af = *(const s16x8*)&xT[wave * 16 + r16][kk * 32 + ks];
            s16x8 bfr = *(const s16x8*)&SBT[r16][kk * 32 + ks];
            a2 = __builtin_amdgcn_mfma_f32_16x16x32_bf16(af, bfr, a2, 0, 0, 0);
        }
        int n = lane & 15;
        int pbase = wave * 16 + (lane >> 4) * 4;
        float* st = states + ((size_t)inst * 32 + c) * 1024;
#pragma unroll
        for (int j = 0; j < 4; j++) st[(pbase + j) * 16 + n] = a2[j];
        if (tid == 0) decays[inst * 32 + c] = __expf(Av * cds[63]);
    }
}

// ---------- chunked scan pass 2: cross-chunk recurrence ----------
__global__ __launch_bounds__(256)
void scan2k(float* __restrict__ states, const float* __restrict__ decays)
{
    int inst = blockIdx.x;
    int tid = threadIdx.x;
    float* base = states + (size_t)inst * 32 * 1024 + tid * 4;
    const float* dec = decays + inst * 32;
    f32x4 hreg = {0.f, 0.f, 0.f, 0.f};
    f32x4 L = *(f32x4*)base;
    for (int cc = 0; cc < 32; cc++) {
        f32x4 Lnext;
        if (cc + 1 < 32) Lnext = *(f32x4*)(base + (cc + 1) * 1024);
        *(f32x4*)(base + cc * 1024) = hreg;
        float d = dec[cc];
        hreg = hreg * d + L;
        L = Lnext;
    }
}

// ---------- chunked scan pass 3: y += C_t . (exp(A cd_t) h_start), C from bcAll ----------
__global__ __launch_bounds__(256)
void scan3k(const float* __restrict__ states,
            const u16* __restrict__ bcAll, const float* __restrict__ dtAll,
            const float* __restrict__ Alog, u16* __restrict__ yAll)
{
    const int c   = blockIdx.x + 1;
    const int bh  = blockIdx.y;
    const int dir = blockIdx.z;
    const int b = bh / 24, h = bh % 24;
    const float* dtp = dtAll + (size_t)dir * 4096 * 24;
    const u16* bcp = bcAll + (size_t)dir * 4096 * 32;
    u16* yp = yAll + dir * 1536;
    const float Av = -__expf(Alog[dir * 24 + h]);
    const int inst = (dir * 2 + b) * 24 + h;
    const int tid = threadIdx.x;

    __shared__ float hs[64][20];
    __shared__ u16 Cs3[64][16];
    __shared__ float ets[64];

    auto rowof = [&](int t) -> size_t {
        int i = c * 64 + t;
        int l = dir ? (2047 - i) : i;
        return (size_t)b * 2048 + l;
    };

    {
        const float* sp = states + ((size_t)inst * 32 + c) * 1024 + tid * 4;
        f32x4 v = *(const f32x4*)sp;
        int e = tid * 4;
        int p = e >> 4, n = e & 15;
        hs[p][n] = v[0]; hs[p][n+1] = v[1]; hs[p][n+2] = v[2]; hs[p][n+3] = v[3];
    }
    if (tid < 64) {
        size_t row = rowof(tid);
        const u16* src = bcp + row * 32 + 16;
        *(u16x8*)&Cs3[tid][0] = *(const u16x8*)src;
        *(u16x8*)&Cs3[tid][8] = *(const u16x8*)(src + 8);
        float v = dtp[row * 24 + h];
        float s = v;
#pragma unroll
        for (int o = 1; o < 64; o <<= 1) {
            float nvl = __shfl_up(s, o, 64);
            if ((tid & 63) >= o) s += nvl;
        }
        ets[tid] = __expf(Av * s);
    }
    __syncthreads();

    int t = tid >> 2, pg = tid & 3;
    float cv[16];
    float et = ets[t];
#pragma unroll
    for (int n = 0; n < 16; n++) cv[n] = bf2f(Cs3[t][n]) * et;
    size_t row = rowof(t);
    u16* yrow = yp + row * 3072 + h * 64 + pg * 16;
    u16x8 ya = *(u16x8*)yrow;
    u16x8 yb = *(u16x8*)(yrow + 8);
#pragma unroll
    for (int jj = 0; jj < 16; jj++) {
        int p = pg * 16 + jj;
        float acc = 0.f;
#pragma unroll
        for (int q = 0; q < 4; q++) {
            f32x4 hv = *(const f32x4*)&hs[p][q * 4];
            acc += cv[q*4]*hv[0] + cv[q*4+1]*hv[1] + cv[q*4+2]*hv[2] + cv[q*4+3]*hv[3];
        }
        if (jj < 8) ya[jj] = f2bf(bf2f(ya[jj]) + acc);
        else        yb[jj - 8] = f2bf(bf2f(yb[jj - 8]) + acc);
    }
    *(u16x8*)yrow = ya;
    *(u16x8*)(yrow + 8) = yb;
}

// ---------- gating + RMSnorm ----------
__global__ __launch_bounds__(256)
void gatek(const u16* __restrict__ zxAll, u16* __restrict__ yAll,
           const float* __restrict__ nw)
{
    int row = blockIdx.x, dir = blockIdx.y;
    const u16* zx = zxAll + (size_t)row * 6256 + dir * 3128;
    u16* y = yAll + (size_t)row * 3072 + dir * 1536;
    const float* nwp = nw + dir * 1536;
    int tid = threadIdx.x;
    float g[6]; float s = 0.f;
#pragma unroll
    for (int j = 0; j < 6; j++) {
        int c = j * 256 + tid;
        float z  = bf2f(zx[c]);
        float yv = bf2f(y[c]);
        float gv = yv * z / (1.f + __expf(-z));
        g[j] = gv; s += gv * gv;
    }
    __shared__ float red[4];
    for (int o = 32; o; o >>= 1) s += __shfl_down(s, o, 64);
    if ((tid & 63) == 0) red[tid >> 6] = s;
    __syncthreads();
    s = red[0] + red[1] + red[2] + red[3];
    float sc = rsqrtf(s * (1.f / 1536.f) + 1e-5f);
#pragma unroll
    for (int j = 0; j < 6; j++) {
        int c = j * 256 + tid;
        y[c] = f2bf(g[j] * sc * nwp[c]);
    }
}

// ---------- final RMS norm ----------
__global__ __launch_bounds__(256)
void finalk(const float* __restrict__ x, const float* __restrict__ fw, float* __restrict__ out)
{
    int row = blockIdx.x; int tid = threadIdx.x;
    const float* xr = x + (size_t)row * 768;
    float v[3]; float s = 0.f;
#pragma unroll
    for (int j = 0; j < 3; j++) {
        int c = j * 256 + tid;
        v[j] = xr[c]; s += v[j] * v[j];
    }
    __shared__ float red[4];
    for (int o = 32; o; o >>= 1) s += __shfl_down(s, o, 64);
    if ((tid & 63) == 0) red[tid >> 6] = s;
    __syncthreads();
    s = red[0] + red[1] + red[2] + red[3];
    float sc = rsqrtf(s * (1.f / 768.f) + 1e-6f);
#pragma unroll
    for (int j = 0; j < 3; j++) {
        int c = j * 256 + tid;
        out[(size_t)row * 768 + c] = v[j] * sc * (1.f + fw[c]);
    }
}

// ---------- host ----------
extern "C" void kernel_launch(void* const* d_in, const int* in_sizes, int n_in,
                              void* d_out, int out_size, void* d_ws, size_t ws_size,
                              hipStream_t stream)
{
    const float* pe      = (const float*)d_in[0];
    const float* Wp      = (const float*)d_in[1];
    const float* bp      = (const float*)d_in[2];
    const float* in_w    = (const float*)d_in[3];
    const float* conv_w  = (const float*)d_in[4];
    const float* conv_b  = (const float*)d_in[5];
    const float* dt_bias = (const float*)d_in[6];
    const float* A_log   = (const float*)d_in[7];
    const float* Dh      = (const float*)d_in[8];
    const float* norm_w  = (const float*)d_in[9];
    const float* out_w   = (const float*)d_in[10];
    const float* bi_w    = (const float*)d_in[11];
    const float* ls      = (const float*)d_in[12];
    const float* fin_w   = (const float*)d_in[13];

    char* wp = (char*)d_ws;
    auto alloc = [&](size_t bytes) {
        char* r = wp; wp += (bytes + 255) & ~(size_t)255; return r;
    };
    u16*   WpT    = (u16*)  alloc((size_t)768 * 256 * 2);
    u16*   inWT   = (u16*)  alloc((size_t)2 * 6272 * 768 * 2);
    u16*   outWB  = (u16*)  alloc((size_t)4 * 1536 * 768 * 2);
    u16*   biWT   = (u16*)  alloc((size_t)4 * 768 * 768 * 2);
    u16*   WcombT = (u16*)  alloc((size_t)2 * 768 * 3072 * 2);
    u16*   peB    = (u16*)  alloc((size_t)4096 * 256 * 2);
    float* x      = (float*)alloc((size_t)4096 * 768 * 4);
    u16*   xb     = (u16*)  alloc((size_t)4096 * 768 * 2);
    u16*   zxAll  = (u16*)  alloc((size_t)4096 * 6256 * 2);
    float* dtAll  = (float*)alloc((size_t)2 * 4096 * 24 * 4);
    u16*   bcAll  = (u16*)  alloc((size_t)2 * 4096 * 32 * 2);
    u16*   yAll   = (u16*)  alloc((size_t)4096 * 3072 * 2);
    float* states = (float*)alloc((size_t)96 * 32 * 1024 * 4);
    float* decays = (float*)alloc((size_t)96 * 32 * 4);

    // ---- weight prep (batched over z) ----
    wtransT<<<dim3(24, 8, 1), 256, 0, stream>>>(Wp, WpT, 256, 768, 256, 0, 0, 0);
    wtransT<<<dim3(98, 24, 4), 256, 0, stream>>>(in_w, inWT, 768, 3128, 768,
                                                 2402304, 4816896, 2402304);
    wtransT<<<dim3(24, 24, 4), 256, 0, stream>>>(bi_w, biWT, 768, 768, 768,
                                                 589824, 1179648, 589824);
    cvtk<<<(4 * 1536 * 768 + 255) / 256, 256, 0, stream>>>(out_w, outWB, 4 * 1536 * 768);
    cvtk<<<4096, 256, 0, stream>>>(pe, peB, 4096 * 256);

    // ---- Wcomb (batched, pipelined) ----
    gemm10<<<dim3(24, 6, 4), 256, 0, stream>>>(
        biWT, outWB, 768, WcombT, 3072,
        (size_t)589824, (size_t)1179648, (size_t)768 * 3072, 1536);

    // ---- patch embedding GEMM (pipelined) ----
    gemm11<<<dim3(12, 32), 256, 0, stream>>>(peB, WpT, 256, x, xb, bp);

    for (int i = 0; i < 2; i++) {
        // merged in_proj (both dirs), verbatim r5 pipelined GEMM
        gemm8<<<dim3(49, 32, 1), 256, 0, stream>>>(
            xb, inWT + (size_t)i * 6272 * 768, 4096, 6256, 768, zxAll, 6256);
        preK<<<(2 * 4096 * 56 + 255) / 256, 256, 0, stream>>>(
            zxAll, dtAll, bcAll, dt_bias + i * 48,
            conv_w + (size_t)i * 2 * 1568 * 4, conv_b + (size_t)i * 2 * 1568);
        scan1k<<<dim3(32, 48, 2), 256, 0, stream>>>(zxAll, dtAll, bcAll,
                                                    conv_w + (size_t)i * 2 * 1568 * 4,
                                                    conv_b + (size_t)i * 2 * 1568,
                                                    A_log + i * 48, Dh + i * 48,
                                                    yAll, states, decays);
        scan2k<<<96, 256, 0, stream>>>(states, decays);
        scan3k<<<dim3(31, 48, 2), 256, 0, stream>>>(states, bcAll, dtAll,
                                                    A_log + i * 48, yAll);
        gatek<<<dim3(4096, 2), 256, 0, stream>>>(zxAll, yAll, norm_w + (size_t)i * 2 * 1536);
        // fused out_proj + concat + bi_w + residual (pipelined 128x64)
        gemm9<<<dim3(12, 32, 1), 256, 0, stream>>>(
            yAll, WcombT + (size_t)i * 768 * 3072, 3072, x, xb, ls + i * 768);
    }

    finalk<<<4096, 256, 0, stream>>>(x, fin_w, (float*)d_out);
}

// Round 11
// 454.896 us; speedup vs baseline: 1.1569x; 1.0447x over previous
//
#include <hip/hip_runtime.h>

typedef unsigned short u16;
typedef short s16x8 __attribute__((ext_vector_type(8)));
typedef u16 u16x8 __attribute__((ext_vector_type(8)));
typedef float f32x4 __attribute__((ext_vector_type(4)));

// ---------- helpers ----------
__device__ inline float bf2f(u16 u) {
    union { unsigned int i; float f; } w; w.i = ((unsigned int)u) << 16; return w.f;
}
__device__ inline u16 f2bf(float f) {
    union { float f; unsigned int i; } w; w.f = f;
    unsigned int u = w.i;
    u += 0x7fffu + ((u >> 16) & 1u);
    return (u16)(u >> 16);
}

// ---------- tiled transpose + bf16: dst[n*dstride+k] = bf16(src[k*N+n]) ----------
__global__ __launch_bounds__(256)
void wtransT(const float* __restrict__ src, u16* __restrict__ dst,
             int K, int N, int dstride, int src_z, int dz_hi, int dz_lo)
{
    int z = blockIdx.z;
    src += (size_t)z * src_z;
    dst += (size_t)(z >> 1) * dz_hi + (size_t)(z & 1) * dz_lo;
    __shared__ float t[32][33];
    int kt = blockIdx.y * 32, nt0 = blockIdx.x * 32;
    int lx = threadIdx.x & 31, ly = threadIdx.x >> 5;   // 32 x 8
#pragma unroll
    for (int i = 0; i < 32; i += 8) {
        int k = kt + ly + i, n = nt0 + lx;
        t[ly + i][lx] = (k < K && n < N) ? src[(size_t)k * N + n] : 0.f;
    }
    __syncthreads();
#pragma unroll
    for (int i = 0; i < 32; i += 8) {
        int n = nt0 + ly + i, k = kt + lx;
        if (n < N && k < K) dst[(size_t)n * dstride + k] = f2bf(t[lx][ly + i]);
    }
}

// ---------- plain f32 -> bf16 convert ----------
__global__ void cvtk(const float* __restrict__ src, u16* __restrict__ dst, int n) {
    int i = blockIdx.x * 256 + threadIdx.x;
    if (i < n) dst[i] = f2bf(src[i]);
}

// ---------- 256x256 4-phase pipelined GEMM (in_proj) ----------
// C[4096,N] = A[4096,K] @ WT[Npad,K]^T, bf16 out. 512 thr = 8 waves (2M x 4N).
// BK=64, 2 LDS K-tile buffers (128 KB dynamic). Per tile: 4 phases, each
// {stage 1-3 gloads, ds_read next A-quadrant, lgkmcnt(4), 16 MFMA}; vmcnt(7)
// once per tile. K%64==0, K/64>=2. WT must be padded to 256-multiple rows.
__global__ __launch_bounds__(512, 1)
void gemmY(const u16* __restrict__ A, const u16* __restrict__ WT,
           int N, int K,
           u16* __restrict__ bout, int ostride)
{
    extern __shared__ u16 ldsY[];            // 2 * 32768 u16 = 128 KB

    int mt, nt;
    {
        int nwg = gridDim.x * gridDim.y;
        int f = blockIdx.y * gridDim.x + blockIdx.x;
        int q = nwg >> 3, r = nwg & 7;
        int xcd = f & 7, lo = f >> 3;
        int wid = (xcd < r ? xcd * (q + 1) : r * (q + 1) + (xcd - r) * q) + lo;
        mt = wid % gridDim.y; nt = wid / gridDim.y;
    }

    const int tid  = threadIdx.x;
    const int lane = tid & 63;
    const int wv   = tid >> 6;               // 0..7
    const int wm   = wv >> 2;                // 0..1
    const int wn   = wv & 3;                 // 0..3
    const int r16  = lane & 15;
    const int lg   = lane >> 4;
    const int mb   = mt * 256;
    const int nb   = nt * 256;

    f32x4 acc[8][4];
#pragma unroll
    for (int i = 0; i < 8; i++)
#pragma unroll
        for (int c = 0; c < 4; c++)
            acc[i][c] = (f32x4){0.f, 0.f, 0.f, 0.f};

    // stage A-quarter q (rows q*32..+31 and 128+q*32..+31), 1 gload/thread
    auto stageAq = [&](int buf, int k0, int q) {
        int lr = tid >> 3, c8 = tid & 7;
        int row = (lr < 32) ? (q * 32 + lr) : (128 + q * 32 + (lr - 32));
        int cbs = c8 ^ (row & 7);
        const u16* g = A + (size_t)(mb + row) * K + k0 + cbs * 8;
        int dstelem = buf * 32768 +
            ((wv < 4) ? (q * 2048 + wv * 512) : (8192 + q * 2048 + (wv - 4) * 512));
        __builtin_amdgcn_global_load_lds(
            (const __attribute__((address_space(1))) void*)g,
            (__attribute__((address_space(3))) void*)&ldsY[dstelem], 16, 0, 0);
    };
    // stage B-quarter bq (rows bq*64..+63), 1 gload/thread
    auto stageBq = [&](int buf, int k0, int bq) {
        int row = bq * 64 + (tid >> 3), c8 = tid & 7;
        int cbs = c8 ^ (row & 7);
        const u16* g = WT + (size_t)(nb + row) * K + k0 + cbs * 8;
        int dstelem = buf * 32768 + 16384 + bq * 4096 + wv * 512;
        __builtin_amdgcn_global_load_lds(
            (const __attribute__((address_space(1))) void*)g,
            (__attribute__((address_space(3))) void*)&ldsY[dstelem], 16, 0, 0);
    };

    const int ntk = K >> 6;
    // prologue: tile0 full (8), tile1 minus A-q3 (7) -> 15 outstanding
#pragma unroll
    for (int q = 0; q < 4; q++) stageAq(0, 0, q);
#pragma unroll
    for (int q = 0; q < 4; q++) stageBq(0, 0, q);
    stageAq(1, 64, 0); stageAq(1, 64, 1); stageAq(1, 64, 2);
#pragma unroll
    for (int q = 0; q < 4; q++) stageBq(1, 64, q);

    s16x8 b[4][2], aA[2][2], aB[2][2];

    for (int t = 0; t < ntk; t++) {
        const int buf = t & 1;
        const int bA0 = buf * 32768;
        const int bB0 = buf * 32768 + 16384;
        const int k1 = (t + 1) << 6;         // may overrun K at tail: harmless
        const int k2 = (t + 2) << 6;

        // ---- phase 0 ----
        asm volatile("s_waitcnt vmcnt(7)" ::: "memory");
        __builtin_amdgcn_sched_barrier(0);
        __builtin_amdgcn_s_barrier();
        __builtin_amdgcn_sched_barrier(0);
        stageAq(buf ^ 1, k1, 3);             // deferred A-q3 of tile t+1
#pragma unroll
        for (int c = 0; c < 4; c++)
#pragma unroll
            for (int kk = 0; kk < 2; kk++) {
                int row = wn * 64 + c * 16 + r16;
                b[c][kk] = *(const s16x8*)&ldsY[bB0 + row * 64 + ((kk * 4 + lg) ^ (row & 7)) * 8];
            }
#pragma unroll
        for (int i = 0; i < 2; i++)
#pragma unroll
            for (int kk = 0; kk < 2; kk++) {
                int row = wm * 128 + i * 16 + r16;
                aA[i][kk] = *(const s16x8*)&ldsY[bA0 + row * 64 + ((kk * 4 + lg) ^ (row & 7)) * 8];
            }
#pragma unroll
        for (int i = 0; i < 2; i++)
#pragma unroll
            for (int kk = 0; kk < 2; kk++) {
                int row = wm * 128 + (2 + i) * 16 + r16;
                aB[i][kk] = *(const s16x8*)&ldsY[bA0 + row * 64 + ((kk * 4 + lg) ^ (row & 7)) * 8];
            }
        __builtin_amdgcn_sched_barrier(0);
        asm volatile("s_waitcnt lgkmcnt(4)" ::: "memory");
        __builtin_amdgcn_sched_barrier(0);
        __builtin_amdgcn_s_setprio(1);
#pragma unroll
        for (int i = 0; i < 2; i++)
#pragma unroll
            for (int c = 0; c < 4; c++) {
                acc[i][c] = __builtin_amdgcn_mfma_f32_16x16x32_bf16(aA[i][0], b[c][0], acc[i][c], 0, 0, 0);
                acc[i][c] = __builtin_amdgcn_mfma_f32_16x16x32_bf16(aA[i][1], b[c][1], acc[i][c], 0, 0, 0);
            }
        __builtin_amdgcn_s_setprio(0);

        // ---- phase 1 ----
        __builtin_amdgcn_sched_barrier(0);
        __builtin_amdgcn_s_barrier();
        __builtin_amdgcn_sched_barrier(0);
        stageAq(buf, k2, 0); stageBq(buf, k2, 0); stageBq(buf, k2, 1);
#pragma unroll
        for (int i = 0; i < 2; i++)
#pragma unroll
            for (int kk = 0; kk < 2; kk++) {
                int row = wm * 128 + (4 + i) * 16 + r16;
                aA[i][kk] = *(const s16x8*)&ldsY[bA0 + row * 64 + ((kk * 4 + lg) ^ (row & 7)) * 8];
            }
        __builtin_amdgcn_sched_barrier(0);
        asm volatile("s_waitcnt lgkmcnt(4)" ::: "memory");
        __builtin_amdgcn_sched_barrier(0);
        __builtin_amdgcn_s_setprio(1);
#pragma unroll
        for (int i = 0; i < 2; i++)
#pragma unroll
            for (int c = 0; c < 4; c++) {
                acc[2 + i][c] = __builtin_amdgcn_mfma_f32_16x16x32_bf16(aB[i][0], b[c][0], acc[2 + i][c], 0, 0, 0);
                acc[2 + i][c] = __builtin_amdgcn_mfma_f32_16x16x32_bf16(aB[i][1], b[c][1], acc[2 + i][c], 0, 0, 0);
            }
        __builtin_amdgcn_s_setprio(0);

        // ---- phase 2 ----
        __builtin_amdgcn_sched_barrier(0);
        __builtin_amdgcn_s_barrier();
        __builtin_amdgcn_sched_barrier(0);
        stageAq(buf, k2, 1); stageBq(buf, k2, 2);
#pragma unroll
        for (int i = 0; i < 2; i++)
#pragma unroll
            for (int kk = 0; kk < 2; kk++) {
                int row = wm * 128 + (6 + i) * 16 + r16;
                aB[i][kk] = *(const s16x8*)&ldsY[bA0 + row * 64 + ((kk * 4 + lg) ^ (row & 7)) * 8];
            }
        __builtin_amdgcn_sched_barrier(0);
        asm volatile("s_waitcnt lgkmcnt(4)" ::: "memory");
        __builtin_amdgcn_sched_barrier(0);
        __builtin_amdgcn_s_setprio(1);
#pragma unroll
        for (int i = 0; i < 2; i++)
#pragma unroll
            for (int c = 0; c < 4; c++) {
                acc[4 + i][c] = __builtin_amdgcn_mfma_f32_16x16x32_bf16(aA[i][0], b[c][0], acc[4 + i][c], 0, 0, 0);
                acc[4 + i][c] = __builtin_amdgcn_mfma_f32_16x16x32_bf16(aA[i][1], b[c][1], acc[4 + i][c], 0, 0, 0);
            }
        __builtin_amdgcn_s_setprio(0);

        // ---- phase 3 ----
        __builtin_amdgcn_sched_barrier(0);
        __builtin_amdgcn_s_barrier();
        __builtin_amdgcn_sched_barrier(0);
        stageAq(buf, k2, 2); stageBq(buf, k2, 3);
        __builtin_amdgcn_sched_barrier(0);
        asm volatile("s_waitcnt lgkmcnt(0)" ::: "memory");
        __builtin_amdgcn_sched_barrier(0);
        __builtin_amdgcn_s_setprio(1);
#pragma unroll
        for (int i = 0; i < 2; i++)
#pragma unroll
            for (int c = 0; c < 4; c++) {
                acc[6 + i][c] = __builtin_amdgcn_mfma_f32_16x16x32_bf16(aB[i][0], b[c][0], acc[6 + i][c], 0, 0, 0);
                acc[6 + i][c] = __builtin_amdgcn_mfma_f32_16x16x32_bf16(aB[i][1], b[c][1], acc[6 + i][c], 0, 0, 0);
            }
        __builtin_amdgcn_s_setprio(0);
        __builtin_amdgcn_sched_barrier(0);
    }

#pragma unroll
    for (int fr = 0; fr < 8; fr++) {
        const int rowb = mb + wm * 128 + fr * 16 + lg * 4;
#pragma unroll
        for (int c = 0; c < 4; c++) {
            int col = nb + wn * 64 + c * 16 + r16;
            if (col < N) {
#pragma unroll
                for (int j = 0; j < 4; j++)
                    bout[(size_t)(rowb + j) * ostride + col] = f2bf(acc[fr][c][j]);
            }
        }
    }
}

// ---------- pipelined GEMM 128x64, EPI2 (out_proj fused residual), standalone ----------
// xv = fout[row*768+col] + v*lsv[col]; fout=xv; bout[row*768+col]=bf16(xv)
__global__ __launch_bounds__(256, 2)
void gemm9(const u16* __restrict__ A, const u16* __restrict__ WT, int K,
           float* __restrict__ fout, u16* __restrict__ bout,
           const float* __restrict__ lsv)
{
    __shared__ u16 lds9[2 * 12288];          // [buf][A:8192 | B:4096] u16

    int mt, nt;
    {
        int nwg = gridDim.x * gridDim.y;
        int f = blockIdx.y * gridDim.x + blockIdx.x;
        int q = nwg >> 3, r = nwg & 7;
        int xcd = f & 7, lo = f >> 3;
        int wid = (xcd < r ? xcd * (q + 1) : r * (q + 1) + (xcd - r) * q) + lo;
        mt = wid % gridDim.y; nt = wid / gridDim.y;
    }

    const int tid  = threadIdx.x;
    const int lane = tid & 63;
    const int wave = tid >> 6;
    const int wm = wave >> 1, wn = wave & 1;
    const int r16 = lane & 15;
    const int lg  = lane >> 4;
    const int mb  = mt * 128;
    const int nb  = nt * 64;
    const int wbase = tid & 192;

    f32x4 acc[4][2];
#pragma unroll
    for (int mi = 0; mi < 4; mi++)
#pragma unroll
        for (int ni = 0; ni < 2; ni++)
            acc[mi][ni] = (f32x4){0.f, 0.f, 0.f, 0.f};

    auto stage = [&](int buf, int k0) {
        u16* bA = &lds9[buf * 12288];
#pragma unroll
        for (int rr = 0; rr < 6; rr++) {
            int e = rr * 256 + tid;
            int row = e >> 3;
            int cbs = (e & 7) ^ (row & 7);
            const u16* g = (rr < 4)
                ? A  + (size_t)(mb + row) * K + k0 + cbs * 8
                : WT + (size_t)(nb + row - 128) * K + k0 + cbs * 8;
            __builtin_amdgcn_global_load_lds(
                (const __attribute__((address_space(1))) void*)g,
                (__attribute__((address_space(3))) void*)&bA[(rr * 256 + wbase) * 8],
                16, 0, 0);
        }
    };

    const int ntk = K >> 6;
    stage(0, 0);
    stage(1, 64);
    asm volatile("s_waitcnt vmcnt(6)" ::: "memory");
    __builtin_amdgcn_sched_barrier(0);
    __builtin_amdgcn_s_barrier();

    for (int t = 0; t < ntk; t++) {
        const int buf = t & 1;
        const u16* bA = &lds9[buf * 12288];
        const u16* bB = bA + 8192;
        s16x8 a[4][2], b[2][2];
#pragma unroll
        for (int mf = 0; mf < 4; mf++)
#pragma unroll
            for (int kk = 0; kk < 2; kk++) {
                int row = wm * 64 + mf * 16 + r16;
                int cb = (kk * 4 + lg) ^ (row & 7);
                a[mf][kk] = *(const s16x8*)&bA[row * 64 + cb * 8];
            }
#pragma unroll
        for (int nf = 0; nf < 2; nf++)
#pragma unroll
            for (int kk = 0; kk < 2; kk++) {
                int row = wn * 32 + nf * 16 + r16;
                int cb = (kk * 4 + lg) ^ (row & 7);
                b[nf][kk] = *(const s16x8*)&bB[row * 64 + cb * 8];
            }
        asm volatile("s_waitcnt lgkmcnt(0)" ::: "memory");
        __builtin_amdgcn_sched_barrier(0);
        __builtin_amdgcn_s_barrier();
        if (t + 2 < ntk) {
            stage(buf, (t + 2) << 6);
            asm volatile("s_waitcnt vmcnt(6)" ::: "memory");
        } else {
            asm volatile("s_waitcnt vmcnt(0)" ::: "memory");
        }
        __builtin_amdgcn_sched_barrier(0);
        __builtin_amdgcn_s_barrier();
        __builtin_amdgcn_s_setprio(1);
#pragma unroll
        for (int mf = 0; mf < 4; mf++)
#pragma unroll
            for (int nf = 0; nf < 2; nf++) {
                acc[mf][nf] = __builtin_amdgcn_mfma_f32_16x16x32_bf16(
                    a[mf][0], b[nf][0], acc[mf][nf], 0, 0, 0);
                acc[mf][nf] = __builtin_amdgcn_mfma_f32_16x16x32_bf16(
                    a[mf][1], b[nf][1], acc[mf][nf], 0, 0, 0);
            }
        __builtin_amdgcn_s_setprio(0);
    }

#pragma unroll
    for (int mf = 0; mf < 4; mf++) {
        const int rowb = mb + wm * 64 + mf * 16 + lg * 4;
#pragma unroll
        for (int nf = 0; nf < 2; nf++) {
            int col = nb + wn * 32 + nf * 16 + r16;
#pragma unroll
            for (int j = 0; j < 4; j++) {
                size_t o = (size_t)(rowb + j) * 768 + col;
                float xv = fout[o] + acc[mf][nf][j] * lsv[col];
                fout[o] = xv; bout[o] = f2bf(xv);
            }
        }
    }
}

// ---------- pipelined GEMM 128x64, batched (Wcomb), plain bf16 out with col offset ----------
__global__ __launch_bounds__(256, 2)
void gemm10(const u16* __restrict__ A, const u16* __restrict__ WT, int K,
            u16* __restrict__ bout, int ostride,
            size_t aZ, size_t wZ, size_t oZ, int ocolZ)
{
    __shared__ u16 ldsA[2 * 12288];

    {
        int z = blockIdx.z;
        A += (size_t)z * aZ; WT += (size_t)z * wZ;
        bout += (size_t)(z >> 1) * oZ + (size_t)(z & 1) * ocolZ;
    }
    int mt, nt;
    {
        int nwg = gridDim.x * gridDim.y;
        int f = blockIdx.y * gridDim.x + blockIdx.x;
        int q = nwg >> 3, r = nwg & 7;
        int xcd = f & 7, lo = f >> 3;
        int wid = (xcd < r ? xcd * (q + 1) : r * (q + 1) + (xcd - r) * q) + lo;
        mt = wid % gridDim.y; nt = wid / gridDim.y;
    }

    const int tid  = threadIdx.x;
    const int lane = tid & 63;
    const int wave = tid >> 6;
    const int wm = wave >> 1, wn = wave & 1;
    const int r16 = lane & 15;
    const int lg  = lane >> 4;
    const int mb  = mt * 128;
    const int nb  = nt * 64;
    const int wbase = tid & 192;

    f32x4 acc[4][2];
#pragma unroll
    for (int mi = 0; mi < 4; mi++)
#pragma unroll
        for (int ni = 0; ni < 2; ni++)
            acc[mi][ni] = (f32x4){0.f, 0.f, 0.f, 0.f};

    auto stage = [&](int buf, int k0) {
        u16* bA = &ldsA[buf * 12288];
#pragma unroll
        for (int rr = 0; rr < 6; rr++) {
            int e = rr * 256 + tid;
            int row = e >> 3;
            int cbs = (e & 7) ^ (row & 7);
            const u16* g = (rr < 4)
                ? A  + (size_t)(mb + row) * K + k0 + cbs * 8
                : WT + (size_t)(nb + row - 128) * K + k0 + cbs * 8;
            __builtin_amdgcn_global_load_lds(
                (const __attribute__((address_space(1))) void*)g,
                (__attribute__((address_space(3))) void*)&bA[(rr * 256 + wbase) * 8],
                16, 0, 0);
        }
    };

    const int ntk = K >> 6;
    stage(0, 0);
    stage(1, 64);
    asm volatile("s_waitcnt vmcnt(6)" ::: "memory");
    __builtin_amdgcn_sched_barrier(0);
    __builtin_amdgcn_s_barrier();

    for (int t = 0; t < ntk; t++) {
        const int buf = t & 1;
        const u16* bA = &ldsA[buf * 12288];
        const u16* bB = bA + 8192;
        s16x8 a[4][2], b[2][2];
#pragma unroll
        for (int mf = 0; mf < 4; mf++)
#pragma unroll
            for (int kk = 0; kk < 2; kk++) {
                int row = wm * 64 + mf * 16 + r16;
                int cb = (kk * 4 + lg) ^ (row & 7);
                a[mf][kk] = *(const s16x8*)&bA[row * 64 + cb * 8];
            }
#pragma unroll
        for (int nf = 0; nf < 2; nf++)
#pragma unroll
            for (int kk = 0; kk < 2; kk++) {
                int row = wn * 32 + nf * 16 + r16;
                int cb = (kk * 4 + lg) ^ (row & 7);
                b[nf][kk] = *(const s16x8*)&bB[row * 64 + cb * 8];
            }
        asm volatile("s_waitcnt lgkmcnt(0)" ::: "memory");
        __builtin_amdgcn_sched_barrier(0);
        __builtin_amdgcn_s_barrier();
        if (t + 2 < ntk) {
            stage(buf, (t + 2) << 6);
            asm volatile("s_waitcnt vmcnt(6)" ::: "memory");
        } else {
            asm volatile("s_waitcnt vmcnt(0)" ::: "memory");
        }
        __builtin_amdgcn_sched_barrier(0);
        __builtin_amdgcn_s_barrier();
        __builtin_amdgcn_s_setprio(1);
#pragma unroll
        for (int mf = 0; mf < 4; mf++)
#pragma unroll
            for (int nf = 0; nf < 2; nf++) {
                acc[mf][nf] = __builtin_amdgcn_mfma_f32_16x16x32_bf16(
                    a[mf][0], b[nf][0], acc[mf][nf], 0, 0, 0);
                acc[mf][nf] = __builtin_amdgcn_mfma_f32_16x16x32_bf16(
                    a[mf][1], b[nf][1], acc[mf][nf], 0, 0, 0);
            }
        __builtin_amdgcn_s_setprio(0);
    }

#pragma unroll
    for (int mf = 0; mf < 4; mf++) {
        const int rowb = mb + wm * 64 + mf * 16 + lg * 4;
#pragma unroll
        for (int nf = 0; nf < 2; nf++) {
            int col = nb + wn * 32 + nf * 16 + r16;
#pragma unroll
            for (int j = 0; j < 4; j++)
                bout[(size_t)(rowb + j) * ostride + col] = f2bf(acc[mf][nf][j]);
        }
    }
}

// ---------- pipelined GEMM 128x64 (patch): v += bias; f32 + bf16 out ----------
__global__ __launch_bounds__(256, 2)
void gemm11(const u16* __restrict__ A, const u16* __restrict__ WT, int K,
            float* __restrict__ fout, u16* __restrict__ bout,
            const float* __restrict__ bias)
{
    __shared__ u16 ldsB[2 * 12288];

    int mt, nt;
    {
        int nwg = gridDim.x * gridDim.y;
        int f = blockIdx.y * gridDim.x + blockIdx.x;
        int q = nwg >> 3, r = nwg & 7;
        int xcd = f & 7, lo = f >> 3;
        int wid = (xcd < r ? xcd * (q + 1) : r * (q + 1) + (xcd - r) * q) + lo;
        mt = wid % gridDim.y; nt = wid / gridDim.y;
    }

    const int tid  = threadIdx.x;
    const int lane = tid & 63;
    const int wave = tid >> 6;
    const int wm = wave >> 1, wn = wave & 1;
    const int r16 = lane & 15;
    const int lg  = lane >> 4;
    const int mb  = mt * 128;
    const int nb  = nt * 64;
    const int wbase = tid & 192;

    f32x4 acc[4][2];
#pragma unroll
    for (int mi = 0; mi < 4; mi++)
#pragma unroll
        for (int ni = 0; ni < 2; ni++)
            acc[mi][ni] = (f32x4){0.f, 0.f, 0.f, 0.f};

    auto stage = [&](int buf, int k0) {
        u16* bA = &ldsB[buf * 12288];
#pragma unroll
        for (int rr = 0; rr < 6; rr++) {
            int e = rr * 256 + tid;
            int row = e >> 3;
            int cbs = (e & 7) ^ (row & 7);
            const u16* g = (rr < 4)
                ? A  + (size_t)(mb + row) * K + k0 + cbs * 8
                : WT + (size_t)(nb + row - 128) * K + k0 + cbs * 8;
            __builtin_amdgcn_global_load_lds(
                (const __attribute__((address_space(1))) void*)g,
                (__attribute__((address_space(3))) void*)&bA[(rr * 256 + wbase) * 8],
                16, 0, 0);
        }
    };

    const int ntk = K >> 6;
    stage(0, 0);
    stage(1, 64);
    asm volatile("s_waitcnt vmcnt(6)" ::: "memory");
    __builtin_amdgcn_sched_barrier(0);
    __builtin_amdgcn_s_barrier();

    for (int t = 0; t < ntk; t++) {
        const int buf = t & 1;
        const u16* bA = &ldsB[buf * 12288];
        const u16* bB = bA + 8192;
        s16x8 a[4][2], b[2][2];
#pragma unroll
        for (int mf = 0; mf < 4; mf++)
#pragma unroll
            for (int kk = 0; kk < 2; kk++) {
                int row = wm * 64 + mf * 16 + r16;
                int cb = (kk * 4 + lg) ^ (row & 7);
                a[mf][kk] = *(const s16x8*)&bA[row * 64 + cb * 8];
            }
#pragma unroll
        for (int nf = 0; nf < 2; nf++)
#pragma unroll
            for (int kk = 0; kk < 2; kk++) {
                int row = wn * 32 + nf * 16 + r16;
                int cb = (kk * 4 + lg) ^ (row & 7);
                b[nf][kk] = *(const s16x8*)&bB[row * 64 + cb * 8];
            }
        asm volatile("s_waitcnt lgkmcnt(0)" ::: "memory");
        __builtin_amdgcn_sched_barrier(0);
        __builtin_amdgcn_s_barrier();
        if (t + 2 < ntk) {
            stage(buf, (t + 2) << 6);
            asm volatile("s_waitcnt vmcnt(6)" ::: "memory");
        } else {
            asm volatile("s_waitcnt vmcnt(0)" ::: "memory");
        }
        __builtin_amdgcn_sched_barrier(0);
        __builtin_amdgcn_s_barrier();
        __builtin_amdgcn_s_setprio(1);
#pragma unroll
        for (int mf = 0; mf < 4; mf++)
#pragma unroll
            for (int nf = 0; nf < 2; nf++) {
                acc[mf][nf] = __builtin_amdgcn_mfma_f32_16x16x32_bf16(
                    a[mf][0], b[nf][0], acc[mf][nf], 0, 0, 0);
                acc[mf][nf] = __builtin_amdgcn_mfma_f32_16x16x32_bf16(
                    a[mf][1], b[nf][1], acc[mf][nf], 0, 0, 0);
            }
        __builtin_amdgcn_s_setprio(0);
    }

#pragma unroll
    for (int mf = 0; mf < 4; mf++) {
        const int rowb = mb + wm * 64 + mf * 16 + lg * 4;
#pragma unroll
        for (int nf = 0; nf < 2; nf++) {
            int col = nb + wn * 32 + nf * 16 + r16;
#pragma unroll
            for (int j = 0; j < 4; j++) {
                float v = acc[mf][nf][j] + bias[col];
                size_t o = (size_t)(rowb + j) * 768 + col;
                fout[o] = v; bout[o] = f2bf(v);
            }
        }
    }
}

// ---------- preK: dt softplus + conv'd B/C (bit-identical to old in-scan conv) ----------
__global__ void preK(const u16* __restrict__ zxAll, float* __restrict__ dtAll,
                     u16* __restrict__ bcAll, const float* __restrict__ dtb,
                     const float* __restrict__ cw, const float* __restrict__ cb)
{
    int idx = blockIdx.x * 256 + threadIdx.x;
    if (idx < 2 * 4096 * 24) {
        int dir = idx / (4096 * 24);
        int r   = idx % (4096 * 24);
        int row = r / 24, h = r % 24;
        float raw = bf2f(zxAll[(size_t)row * 6256 + dir * 3128 + 3104 + h]) + dtb[dir * 24 + h];
        dtAll[((size_t)dir * 4096 + row) * 24 + h] = raw > 20.f ? raw : log1pf(__expf(raw));
        return;
    }
    int v = idx - 2 * 4096 * 24;
    if (v >= 2 * 4096 * 32) return;
    int ch  = v & 31;
    int row = (v >> 5) & 4095;
    int dir = v >> 17;
    int l   = row & 2047;
    int chg = 1536 + ch;
    float acc = cb[dir * 1568 + chg];
    const float* w = cw + ((size_t)dir * 1568 + chg) * 4;
#pragma unroll
    for (int k = 0; k < 4; k++) {
        int ll = dir ? (l + 3 - k) : (l - 3 + k);
        if (ll >= 0 && ll < 2048)
            acc += bf2f(zxAll[(size_t)(row + (ll - l)) * 6256 + dir * 3128 + chg]) * w[k];
    }
    acc = acc / (1.f + __expf(-acc));
    bcAll[((size_t)dir * 4096 + row) * 32 + ch] = f2bf(acc);
}

// ---------- chunked scan pass 1 (x-conv fused; B/C from bcAll) ----------
__global__ __launch_bounds__(256)
void scan1k(const u16* __restrict__ zxAll, const float* __restrict__ dtAll,
            const u16* __restrict__ bcAll,
            const float* __restrict__ cw, const float* __restrict__ cb,
            const float* __restrict__ Alog, const float* __restrict__ Dhp,
            u16* __restrict__ yAll, float* __restrict__ states, float* __restrict__ decays)
{
    const int c   = blockIdx.x;
    const int bh  = blockIdx.y;
    const int dir = blockIdx.z;
    const int b = bh / 24, h = bh % 24;
    const float* dtp = dtAll + (size_t)dir * 4096 * 24;
    const u16* bcp = bcAll + (size_t)dir * 4096 * 32;
    u16* yp = yAll + dir * 1536;
    const float Av = -__expf(Alog[dir * 24 + h]);
    const float Dv = Dhp[dir * 24 + h];
    const int inst = (dir * 2 + b) * 24 + h;

    const int tid  = threadIdx.x;
    const int lane = tid & 63;
    const int wave = tid >> 6;
    const int r16  = lane & 15;
    const int ks   = (lane >> 4) * 8;

    __shared__ u16 xT[64][72];
    __shared__ u16 Gs[64][72];
    __shared__ u16 Bs[64][40];
    __shared__ u16 Cs[64][40];
    __shared__ u16 SBT[16][72];
    __shared__ float dts[64], cds[64];

    const u16* zxd = zxAll + dir * 3128 + 1536;
    auto growp = [&](int ii) -> const u16* {
        int l = dir ? (2047 - ii) : ii;
        return zxd + ((size_t)b * 2048 + l) * 6256;
    };
    auto rowof = [&](int t) -> size_t {
        int i = c * 64 + t;
        int l = dir ? (2047 - i) : i;
        return (size_t)b * 2048 + l;
    };
    const u16x8 zz = {0,0,0,0,0,0,0,0};

    {
        int tr = tid >> 2, pg = tid & 3;
        int chb = h * 64 + pg * 16;
        int i0 = c * 64 + tr;
        u16x8 tv[4][2];
#pragma unroll
        for (int k = 0; k < 4; k++) {
            int ii = i0 - 3 + k;
            if (ii >= 0) {
                const u16* s = growp(ii) + chb;
                tv[k][0] = *(const u16x8*)s;
                tv[k][1] = *(const u16x8*)(s + 8);
            } else { tv[k][0] = zz; tv[k][1] = zz; }
        }
        const float* cwp = cw + ((size_t)dir * 1568 + chb) * 4;
        const float* cbp = cb + (size_t)dir * 1568 + chb;
#pragma unroll
        for (int j = 0; j < 16; j++) {
            f32x4 wj = *(const f32x4*)(cwp + j * 4);
            float a = cbp[j];
            int hi = j >> 3, lo2 = j & 7;
            a += bf2f(tv[0][hi][lo2]) * wj[0] + bf2f(tv[1][hi][lo2]) * wj[1]
               + bf2f(tv[2][hi][lo2]) * wj[2] + bf2f(tv[3][hi][lo2]) * wj[3];
            a = a / (1.f + __expf(-a));
            xT[pg * 16 + j][tr] = f2bf(a);
        }
    }
    {
        int t = tid & 63, which = tid >> 6;
        if (which < 2) {
            const u16* src = bcp + rowof(t) * 32 + which * 16;
            u16* dst = which ? &Cs[t][0] : &Bs[t][0];
            *(u16x8*)dst = *(const u16x8*)src;
            *(u16x8*)(dst + 8) = *(const u16x8*)(src + 8);
        } else {
            u16* dst = (which == 2) ? &Bs[t][16] : &Cs[t][16];
            *(u16x8*)dst = zz; *(u16x8*)(dst + 8) = zz;
        }
    }
    if (tid < 64) {
        float v = dtp[rowof(tid) * 24 + h];
        dts[tid] = v;
        float s = v;
#pragma unroll
        for (int o = 1; o < 64; o <<= 1) {
            float nvl = __shfl_up(s, o, 64);
            if (lane >= o) s += nvl;
        }
        cds[tid] = s;
    }
    __syncthreads();

    {
        const s16x8 af = *(const s16x8*)&Cs[wave * 16 + r16][ks];
#pragma unroll
        for (int st = 0; st < 4; st++) {
            const s16x8 bfr = *(const s16x8*)&Bs[st * 16 + r16][ks];
            f32x4 a2 = {0.f, 0.f, 0.f, 0.f};
            a2 = __builtin_amdgcn_mfma_f32_16x16x32_bf16(af, bfr, a2, 0, 0, 0);
            int s = st * 16 + (lane & 15);
            int tbase = wave * 16 + (lane >> 4) * 4;
            float cs = cds[s], dtv = dts[s];
#pragma unroll
            for (int j = 0; j < 4; j++) {
                int t = tbase + j;
                float g = 0.f;
                if (s <= t) {
                    g = a2[j] * dtv * __expf(Av * (cds[t] - cs));
                    if (s == t) g += Dv;
                }
                Gs[t][s] = f2bf(g);
            }
        }
    }
    {
        float cdT = cds[63];
        int s = tid & 63;
        float sc = __expf(Av * (cdT - cds[s])) * dts[s];
#pragma unroll
        for (int it = 0; it < 4; it++) {
            int n = (tid >> 6) + it * 4;
            SBT[n][s] = f2bf(sc * bf2f(Bs[s][n]));
        }
    }
    __syncthreads();

    {
#pragma unroll
        for (int pt = 0; pt < 4; pt++) {
            f32x4 a2 = {0.f, 0.f, 0.f, 0.f};
#pragma unroll
            for (int kk = 0; kk < 2; kk++) {
                s16x8 af = *(const s16x8*)&Gs[wave * 16 + r16][kk * 32 + ks];
                s16x8 bfr = *(const s16x8*)&xT[pt * 16 + r16][kk * 32 + ks];
                a2 = __builtin_amdgcn_mfma_f32_16x16x32_bf16(af, bfr, a2, 0, 0, 0);
            }
            int p = pt * 16 + (lane & 15);
            int tbase = wave * 16 + (lane >> 4) * 4;
#pragma unroll
            for (int j = 0; j < 4; j++) {
                size_t row = rowof(tbase + j);
                yp[row * 3072 + h * 64 + p] = f2bf(a2[j]);
            }
        }
    }
    {
        f32x4 a2 = {0.f, 0.f, 0.f, 0.f};
#pragma unroll
        for (int kk = 0; kk < 2; kk++) {
            s16x8 af = *(const s16x8*)&xT[wave * 16 + r16][kk * 32 + ks];
            s16x8 bfr = *(const s16x8*)&SBT[r16][kk * 32 + ks];
            a2 = __builtin_amdgcn_mfma_f32_16x16x32_bf16(af, bfr, a2, 0, 0, 0);
        }
        int n = lane & 15;
        int pbase = wave * 16 + (lane >> 4) * 4;
        float* st = states + ((size_t)inst * 32 + c) * 1024;
#pragma unroll
        for (int j = 0; j < 4; j++) st[(pbase + j) * 16 + n] = a2[j];
        if (tid == 0) decays[inst * 32 + c] = __expf(Av * cds[63]);
    }
}

// ---------- chunked scan pass 2: cross-chunk recurrence ----------
__global__ __launch_bounds__(256)
void scan2k(float* __restrict__ states, const float* __restrict__ decays)
{
    int inst = blockIdx.x;
    int tid = threadIdx.x;
    float* base = states + (size_t)inst * 32 * 1024 + tid * 4;
    const float* dec = decays + inst * 32;
    f32x4 hreg = {0.f, 0.f, 0.f, 0.f};
    f32x4 L = *(f32x4*)base;
    for (int cc = 0; cc < 32; cc++) {
        f32x4 Lnext;
        if (cc + 1 < 32) Lnext = *(f32x4*)(base + (cc + 1) * 1024);
        *(f32x4*)(base + cc * 1024) = hreg;
        float d = dec[cc];
        hreg = hreg * d + L;
        L = Lnext;
    }
}

// ---------- chunked scan pass 3: y += C_t . (exp(A cd_t) h_start), C from bcAll ----------
__global__ __launch_bounds__(256)
void scan3k(const float* __restrict__ states,
            const u16* __restrict__ bcAll, const float* __restrict__ dtAll,
            const float* __restrict__ Alog, u16* __restrict__ yAll)
{
    const int c   = blockIdx.x + 1;
    const int bh  = blockIdx.y;
    const int dir = blockIdx.z;
    const int b = bh / 24, h = bh % 24;
    const float* dtp = dtAll + (size_t)dir * 4096 * 24;
    const u16* bcp = bcAll + (size_t)dir * 4096 * 32;
    u16* yp = yAll + dir * 1536;
    const float Av = -__expf(Alog[dir * 24 + h]);
    const int inst = (dir * 2 + b) * 24 + h;
    const int tid = threadIdx.x;

    __shared__ float hs[64][20];
    __shared__ u16 Cs3[64][16];
    __shared__ float ets[64];

    auto rowof = [&](int t) -> size_t {
        int i = c * 64 + t;
        int l = dir ? (2047 - i) : i;
        return (size_t)b * 2048 + l;
    };

    {
        const float* sp = states + ((size_t)inst * 32 + c) * 1024 + tid * 4;
        f32x4 v = *(const f32x4*)sp;
        int e = tid * 4;
        int p = e >> 4, n = e & 15;
        hs[p][n] = v[0]; hs[p][n+1] = v[1]; hs[p][n+2] = v[2]; hs[p][n+3] = v[3];
    }
    if (tid < 64) {
        size_t row = rowof(tid);
        const u16* src = bcp + row * 32 + 16;
        *(u16x8*)&Cs3[tid][0] = *(const u16x8*)src;
        *(u16x8*)&Cs3[tid][8] = *(const u16x8*)(src + 8);
        float v = dtp[row * 24 + h];
        float s = v;
#pragma unroll
        for (int o = 1; o < 64; o <<= 1) {
            float nvl = __shfl_up(s, o, 64);
            if ((tid & 63) >= o) s += nvl;
        }
        ets[tid] = __expf(Av * s);
    }
    __syncthreads();

    int t = tid >> 2, pg = tid & 3;
    float cv[16];
    float et = ets[t];
#pragma unroll
    for (int n = 0; n < 16; n++) cv[n] = bf2f(Cs3[t][n]) * et;
    size_t row = rowof(t);
    u16* yrow = yp + row * 3072 + h * 64 + pg * 16;
    u16x8 ya = *(u16x8*)yrow;
    u16x8 yb = *(u16x8*)(yrow + 8);
#pragma unroll
    for (int jj = 0; jj < 16; jj++) {
        int p = pg * 16 + jj;
        float acc = 0.f;
#pragma unroll
        for (int q = 0; q < 4; q++) {
            f32x4 hv = *(const f32x4*)&hs[p][q * 4];
            acc += cv[q*4]*hv[0] + cv[q*4+1]*hv[1] + cv[q*4+2]*hv[2] + cv[q*4+3]*hv[3];
        }
        if (jj < 8) ya[jj] = f2bf(bf2f(ya[jj]) + acc);
        else        yb[jj - 8] = f2bf(bf2f(yb[jj - 8]) + acc);
    }
    *(u16x8*)yrow = ya;
    *(u16x8*)(yrow + 8) = yb;
}

// ---------- gating + RMSnorm ----------
__global__ __launch_bounds__(256)
void gatek(const u16* __restrict__ zxAll, u16* __restrict__ yAll,
           const float* __restrict__ nw)
{
    int row = blockIdx.x, dir = blockIdx.y;
    const u16* zx = zxAll + (size_t)row * 6256 + dir * 3128;
    u16* y = yAll + (size_t)row * 3072 + dir * 1536;
    const float* nwp = nw + dir * 1536;
    int tid = threadIdx.x;
    float g[6]; float s = 0.f;
#pragma unroll
    for (int j = 0; j < 6; j++) {
        int c = j * 256 + tid;
        float z  = bf2f(zx[c]);
        float yv = bf2f(y[c]);
        float gv = yv * z / (1.f + __expf(-z));
        g[j] = gv; s += gv * gv;
    }
    __shared__ float red[4];
    for (int o = 32; o; o >>= 1) s += __shfl_down(s, o, 64);
    if ((tid & 63) == 0) red[tid >> 6] = s;
    __syncthreads();
    s = red[0] + red[1] + red[2] + red[3];
    float sc = rsqrtf(s * (1.f / 1536.f) + 1e-5f);
#pragma unroll
    for (int j = 0; j < 6; j++) {
        int c = j * 256 + tid;
        y[c] = f2bf(g[j] * sc * nwp[c]);
    }
}

// ---------- final RMS norm ----------
__global__ __launch_bounds__(256)
void finalk(const float* __restrict__ x, const float* __restrict__ fw, float* __restrict__ out)
{
    int row = blockIdx.x; int tid = threadIdx.x;
    const float* xr = x + (size_t)row * 768;
    float v[3]; float s = 0.f;
#pragma unroll
    for (int j = 0; j < 3; j++) {
        int c = j * 256 + tid;
        v[j] = xr[c]; s += v[j] * v[j];
    }
    __shared__ float red[4];
    for (int o = 32; o; o >>= 1) s += __shfl_down(s, o, 64);
    if ((tid & 63) == 0) red[tid >> 6] = s;
    __syncthreads();
    s = red[0] + red[1] + red[2] + red[3];
    float sc = rsqrtf(s * (1.f / 768.f) + 1e-6f);
#pragma unroll
    for (int j = 0; j < 3; j++) {
        int c = j * 256 + tid;
        out[(size_t)row * 768 + c] = v[j] * sc * (1.f + fw[c]);
    }
}

// ---------- host ----------
extern "C" void kernel_launch(void* const* d_in, const int* in_sizes, int n_in,
                              void* d_out, int out_size, void* d_ws, size_t ws_size,
                              hipStream_t stream)
{
    const float* pe      = (const float*)d_in[0];
    const float* Wp      = (const float*)d_in[1];
    const float* bp      = (const float*)d_in[2];
    const float* in_w    = (const float*)d_in[3];
    const float* conv_w  = (const float*)d_in[4];
    const float* conv_b  = (const float*)d_in[5];
    const float* dt_bias = (const float*)d_in[6];
    const float* A_log   = (const float*)d_in[7];
    const float* Dh      = (const float*)d_in[8];
    const float* norm_w  = (const float*)d_in[9];
    const float* out_w   = (const float*)d_in[10];
    const float* bi_w    = (const float*)d_in[11];
    const float* ls      = (const float*)d_in[12];
    const float* fin_w   = (const float*)d_in[13];

    char* wp = (char*)d_ws;
    auto alloc = [&](size_t bytes) {
        char* r = wp; wp += (bytes + 255) & ~(size_t)255; return r;
    };
    u16*   WpT    = (u16*)  alloc((size_t)768 * 256 * 2);
    u16*   inWT   = (u16*)  alloc(((size_t)2 * 6400 * 768 + 4096) * 2);  // padded N=6400 + tail slack
    u16*   outWB  = (u16*)  alloc((size_t)4 * 1536 * 768 * 2);
    u16*   biWT   = (u16*)  alloc((size_t)4 * 768 * 768 * 2);
    u16*   WcombT = (u16*)  alloc((size_t)2 * 768 * 3072 * 2);
    u16*   peB    = (u16*)  alloc((size_t)4096 * 256 * 2);
    float* x      = (float*)alloc((size_t)4096 * 768 * 4);
    u16*   xb     = (u16*)  alloc((size_t)4096 * 768 * 2);
    u16*   zxAll  = (u16*)  alloc((size_t)4096 * 6256 * 2);
    float* dtAll  = (float*)alloc((size_t)2 * 4096 * 24 * 4);
    u16*   bcAll  = (u16*)  alloc((size_t)2 * 4096 * 32 * 2);
    u16*   yAll   = (u16*)  alloc((size_t)4096 * 3072 * 2);
    float* states = (float*)alloc((size_t)96 * 32 * 1024 * 4);
    float* decays = (float*)alloc((size_t)96 * 32 * 4);

    // ---- weight prep (batched over z) ----
    wtransT<<<dim3(24, 8, 1), 256, 0, stream>>>(Wp, WpT, 256, 768, 256, 0, 0, 0);
    wtransT<<<dim3(98, 24, 4), 256, 0, stream>>>(in_w, inWT, 768, 3128, 768,
                                                 2402304, 4915200, 2402304);
    wtransT<<<dim3(24, 24, 4), 256, 0, stream>>>(bi_w, biWT, 768, 768, 768,
                                                 589824, 1179648, 589824);
    cvtk<<<(4 * 1536 * 768 + 255) / 256, 256, 0, stream>>>(out_w, outWB, 4 * 1536 * 768);
    cvtk<<<4096, 256, 0, stream>>>(pe, peB, 4096 * 256);

    // ---- Wcomb (batched, pipelined) ----
    gemm10<<<dim3(24, 6, 4), 256, 0, stream>>>(
        biWT, outWB, 768, WcombT, 3072,
        (size_t)589824, (size_t)1179648, (size_t)768 * 3072, 1536);

    // ---- patch embedding GEMM (pipelined) ----
    gemm11<<<dim3(12, 32), 256, 0, stream>>>(peB, WpT, 256, x, xb, bp);

    hipFuncSetAttribute((const void*)gemmY,
                        hipFuncAttributeMaxDynamicSharedMemorySize, 131072);

    for (int i = 0; i < 2; i++) {
        // merged in_proj (both dirs), 256x256 4-phase pipelined GEMM
        gemmY<<<dim3(25, 16), 512, 131072, stream>>>(
            xb, inWT + (size_t)i * 6400 * 768, 6256, 768, zxAll, 6256);
        preK<<<(2 * 4096 * 56 + 255) / 256, 256, 0, stream>>>(
            zxAll, dtAll, bcAll, dt_bias + i * 48,
            conv_w + (size_t)i * 2 * 1568 * 4, conv_b + (size_t)i * 2 * 1568);
        scan1k<<<dim3(32, 48, 2), 256, 0, stream>>>(zxAll, dtAll, bcAll,
                                                    conv_w + (size_t)i * 2 * 1568 * 4,
                                                    conv_b + (size_t)i * 2 * 1568,
                                                    A_log + i * 48, Dh + i * 48,
                                                    yAll, states, decays);
        scan2k<<<96, 256, 0, stream>>>(states, decays);
        scan3k<<<dim3(31, 48, 2), 256, 0, stream>>>(states, bcAll, dtAll,
                                                    A_log + i * 48, yAll);
        gatek<<<dim3(4096, 2), 256, 0, stream>>>(zxAll, yAll, norm_w + (size_t)i * 2 * 1536);
        // fused out_proj + concat + bi_w + residual (pipelined 128x64)
        gemm9<<<dim3(12, 32, 1), 256, 0, stream>>>(
            yAll, WcombT + (size_t)i * 768 * 3072, 3072, x, xb, ls + i * 768);
    }

    finalk<<<4096, 256, 0, stream>>>(x, fin_w, (float*)d_out);
}

// Round 12
// 451.999 us; speedup vs baseline: 1.1643x; 1.0064x over previous
//
#include <hip/hip_runtime.h>

typedef unsigned short u16;
typedef short s16x8 __attribute__((ext_vector_type(8)));
typedef u16 u16x8 __attribute__((ext_vector_type(8)));
typedef float f32x4 __attribute__((ext_vector_type(4)));

// ---------- helpers ----------
__device__ inline float bf2f(u16 u) {
    union { unsigned int i; float f; } w; w.i = ((unsigned int)u) << 16; return w.f;
}
__device__ inline u16 f2bf(float f) {
    union { float f; unsigned int i; } w; w.f = f;
    unsigned int u = w.i;
    u += 0x7fffu + ((u >> 16) & 1u);
    return (u16)(u >> 16);
}

// ---------- tiled transpose + bf16: dst[n*dstride+k] = bf16(src[k*N+n]) ----------
__global__ __launch_bounds__(256)
void wtransT(const float* __restrict__ src, u16* __restrict__ dst,
             int K, int N, int dstride, int src_z, int dz_hi, int dz_lo)
{
    int z = blockIdx.z;
    src += (size_t)z * src_z;
    dst += (size_t)(z >> 1) * dz_hi + (size_t)(z & 1) * dz_lo;
    __shared__ float t[32][33];
    int kt = blockIdx.y * 32, nt0 = blockIdx.x * 32;
    int lx = threadIdx.x & 31, ly = threadIdx.x >> 5;   // 32 x 8
#pragma unroll
    for (int i = 0; i < 32; i += 8) {
        int k = kt + ly + i, n = nt0 + lx;
        t[ly + i][lx] = (k < K && n < N) ? src[(size_t)k * N + n] : 0.f;
    }
    __syncthreads();
#pragma unroll
    for (int i = 0; i < 32; i += 8) {
        int n = nt0 + ly + i, k = kt + lx;
        if (n < N && k < K) dst[(size_t)n * dstride + k] = f2bf(t[lx][ly + i]);
    }
}

// ---------- merged f32 -> bf16 convert (two ranges, one launch) ----------
__global__ void cvt2k(const float* __restrict__ s1, u16* __restrict__ d1, int n1,
                      const float* __restrict__ s2, u16* __restrict__ d2, int n2)
{
    int i = blockIdx.x * 256 + threadIdx.x;
    if (i < n1) d1[i] = f2bf(s1[i]);
    else if (i < n1 + n2) d2[i - n1] = f2bf(s2[i - n1]);
}

// ---------- 256x256 4-phase pipelined GEMM (in_proj) ----------
// C[4096,N] = A[4096,K] @ WT[Npad,K]^T, bf16 out. 512 thr = 8 waves (2M x 4N).
// BK=64, 2 LDS K-tile buffers (128 KB dynamic). Per tile: 4 phases, each
// {stage 1-3 gloads, ds_read next A-quadrant, lgkmcnt(4), 16 MFMA}; vmcnt(7)
// once per tile. K%64==0, K/64>=2. WT must be padded to 256-multiple rows.
__global__ __launch_bounds__(512, 1)
void gemmY(const u16* __restrict__ A, const u16* __restrict__ WT,
           int N, int K,
           u16* __restrict__ bout, int ostride)
{
    extern __shared__ u16 ldsY[];            // 2 * 32768 u16 = 128 KB

    int mt, nt;
    {
        int nwg = gridDim.x * gridDim.y;
        int f = blockIdx.y * gridDim.x + blockIdx.x;
        int q = nwg >> 3, r = nwg & 7;
        int xcd = f & 7, lo = f >> 3;
        int wid = (xcd < r ? xcd * (q + 1) : r * (q + 1) + (xcd - r) * q) + lo;
        mt = wid % gridDim.y; nt = wid / gridDim.y;
    }

    const int tid  = threadIdx.x;
    const int lane = tid & 63;
    const int wv   = tid >> 6;               // 0..7
    const int wm   = wv >> 2;                // 0..1
    const int wn   = wv & 3;                 // 0..3
    const int r16  = lane & 15;
    const int lg   = lane >> 4;
    const int mb   = mt * 256;
    const int nb   = nt * 256;

    f32x4 acc[8][4];
#pragma unroll
    for (int i = 0; i < 8; i++)
#pragma unroll
        for (int c = 0; c < 4; c++)
            acc[i][c] = (f32x4){0.f, 0.f, 0.f, 0.f};

    // stage A-quarter q (rows q*32..+31 and 128+q*32..+31), 1 gload/thread
    auto stageAq = [&](int buf, int k0, int q) {
        int lr = tid >> 3, c8 = tid & 7;
        int row = (lr < 32) ? (q * 32 + lr) : (128 + q * 32 + (lr - 32));
        int cbs = c8 ^ (row & 7);
        const u16* g = A + (size_t)(mb + row) * K + k0 + cbs * 8;
        int dstelem = buf * 32768 +
            ((wv < 4) ? (q * 2048 + wv * 512) : (8192 + q * 2048 + (wv - 4) * 512));
        __builtin_amdgcn_global_load_lds(
            (const __attribute__((address_space(1))) void*)g,
            (__attribute__((address_space(3))) void*)&ldsY[dstelem], 16, 0, 0);
    };
    // stage B-quarter bq (rows bq*64..+63), 1 gload/thread
    auto stageBq = [&](int buf, int k0, int bq) {
        int row = bq * 64 + (tid >> 3), c8 = tid & 7;
        int cbs = c8 ^ (row & 7);
        const u16* g = WT + (size_t)(nb + row) * K + k0 + cbs * 8;
        int dstelem = buf * 32768 + 16384 + bq * 4096 + wv * 512;
        __builtin_amdgcn_global_load_lds(
            (const __attribute__((address_space(1))) void*)g,
            (__attribute__((address_space(3))) void*)&ldsY[dstelem], 16, 0, 0);
    };

    const int ntk = K >> 6;
    // prologue: tile0 full (8), tile1 minus A-q3 (7) -> 15 outstanding
#pragma unroll
    for (int q = 0; q < 4; q++) stageAq(0, 0, q);
#pragma unroll
    for (int q = 0; q < 4; q++) stageBq(0, 0, q);
    stageAq(1, 64, 0); stageAq(1, 64, 1); stageAq(1, 64, 2);
#pragma unroll
    for (int q = 0; q < 4; q++) stageBq(1, 64, q);

    s16x8 b[4][2], aA[2][2], aB[2][2];

    for (int t = 0; t < ntk; t++) {
        const int buf = t & 1;
        const int bA0 = buf * 32768;
        const int bB0 = buf * 32768 + 16384;
        const int k1 = (t + 1) << 6;         // may overrun K at tail: harmless
        const int k2 = (t + 2) << 6;

        // ---- phase 0 ----
        asm volatile("s_waitcnt vmcnt(7)" ::: "memory");
        __builtin_amdgcn_sched_barrier(0);
        __builtin_amdgcn_s_barrier();
        __builtin_amdgcn_sched_barrier(0);
        stageAq(buf ^ 1, k1, 3);             // deferred A-q3 of tile t+1
#pragma unroll
        for (int c = 0; c < 4; c++)
#pragma unroll
            for (int kk = 0; kk < 2; kk++) {
                int row = wn * 64 + c * 16 + r16;
                b[c][kk] = *(const s16x8*)&ldsY[bB0 + row * 64 + ((kk * 4 + lg) ^ (row & 7)) * 8];
            }
#pragma unroll
        for (int i = 0; i < 2; i++)
#pragma unroll
            for (int kk = 0; kk < 2; kk++) {
                int row = wm * 128 + i * 16 + r16;
                aA[i][kk] = *(const s16x8*)&ldsY[bA0 + row * 64 + ((kk * 4 + lg) ^ (row & 7)) * 8];
            }
#pragma unroll
        for (int i = 0; i < 2; i++)
#pragma unroll
            for (int kk = 0; kk < 2; kk++) {
                int row = wm * 128 + (2 + i) * 16 + r16;
                aB[i][kk] = *(const s16x8*)&ldsY[bA0 + row * 64 + ((kk * 4 + lg) ^ (row & 7)) * 8];
            }
        __builtin_amdgcn_sched_barrier(0);
        asm volatile("s_waitcnt lgkmcnt(4)" ::: "memory");
        __builtin_amdgcn_sched_barrier(0);
        __builtin_amdgcn_s_setprio(1);
#pragma unroll
        for (int i = 0; i < 2; i++)
#pragma unroll
            for (int c = 0; c < 4; c++) {
                acc[i][c] = __builtin_amdgcn_mfma_f32_16x16x32_bf16(aA[i][0], b[c][0], acc[i][c], 0, 0, 0);
                acc[i][c] = __builtin_amdgcn_mfma_f32_16x16x32_bf16(aA[i][1], b[c][1], acc[i][c], 0, 0, 0);
            }
        __builtin_amdgcn_s_setprio(0);

        // ---- phase 1 ----
        __builtin_amdgcn_sched_barrier(0);
        __builtin_amdgcn_s_barrier();
        __builtin_amdgcn_sched_barrier(0);
        stageAq(buf, k2, 0); stageBq(buf, k2, 0); stageBq(buf, k2, 1);
#pragma unroll
        for (int i = 0; i < 2; i++)
#pragma unroll
            for (int kk = 0; kk < 2; kk++) {
                int row = wm * 128 + (4 + i) * 16 + r16;
                aA[i][kk] = *(const s16x8*)&ldsY[bA0 + row * 64 + ((kk * 4 + lg) ^ (row & 7)) * 8];
            }
        __builtin_amdgcn_sched_barrier(0);
        asm volatile("s_waitcnt lgkmcnt(4)" ::: "memory");
        __builtin_amdgcn_sched_barrier(0);
        __builtin_amdgcn_s_setprio(1);
#pragma unroll
        for (int i = 0; i < 2; i++)
#pragma unroll
            for (int c = 0; c < 4; c++) {
                acc[2 + i][c] = __builtin_amdgcn_mfma_f32_16x16x32_bf16(aB[i][0], b[c][0], acc[2 + i][c], 0, 0, 0);
                acc[2 + i][c] = __builtin_amdgcn_mfma_f32_16x16x32_bf16(aB[i][1], b[c][1], acc[2 + i][c], 0, 0, 0);
            }
        __builtin_amdgcn_s_setprio(0);

        // ---- phase 2 ----
        __builtin_amdgcn_sched_barrier(0);
        __builtin_amdgcn_s_barrier();
        __builtin_amdgcn_sched_barrier(0);
        stageAq(buf, k2, 1); stageBq(buf, k2, 2);
#pragma unroll
        for (int i = 0; i < 2; i++)
#pragma unroll
            for (int kk = 0; kk < 2; kk++) {
                int row = wm * 128 + (6 + i) * 16 + r16;
                aB[i][kk] = *(const s16x8*)&ldsY[bA0 + row * 64 + ((kk * 4 + lg) ^ (row & 7)) * 8];
            }
        __builtin_amdgcn_sched_barrier(0);
        asm volatile("s_waitcnt lgkmcnt(4)" ::: "memory");
        __builtin_amdgcn_sched_barrier(0);
        __builtin_amdgcn_s_setprio(1);
#pragma unroll
        for (int i = 0; i < 2; i++)
#pragma unroll
            for (int c = 0; c < 4; c++) {
                acc[4 + i][c] = __builtin_amdgcn_mfma_f32_16x16x32_bf16(aA[i][0], b[c][0], acc[4 + i][c], 0, 0, 0);
                acc[4 + i][c] = __builtin_amdgcn_mfma_f32_16x16x32_bf16(aA[i][1], b[c][1], acc[4 + i][c], 0, 0, 0);
            }
        __builtin_amdgcn_s_setprio(0);

        // ---- phase 3 ----
        __builtin_amdgcn_sched_barrier(0);
        __builtin_amdgcn_s_barrier();
        __builtin_amdgcn_sched_barrier(0);
        stageAq(buf, k2, 2); stageBq(buf, k2, 3);
        __builtin_amdgcn_sched_barrier(0);
        asm volatile("s_waitcnt lgkmcnt(0)" ::: "memory");
        __builtin_amdgcn_sched_barrier(0);
        __builtin_amdgcn_s_setprio(1);
#pragma unroll
        for (int i = 0; i < 2; i++)
#pragma unroll
            for (int c = 0; c < 4; c++) {
                acc[6 + i][c] = __builtin_amdgcn_mfma_f32_16x16x32_bf16(aB[i][0], b[c][0], acc[6 + i][c], 0, 0, 0);
                acc[6 + i][c] = __builtin_amdgcn_mfma_f32_16x16x32_bf16(aB[i][1], b[c][1], acc[6 + i][c], 0, 0, 0);
            }
        __builtin_amdgcn_s_setprio(0);
        __builtin_amdgcn_sched_barrier(0);
    }

#pragma unroll
    for (int fr = 0; fr < 8; fr++) {
        const int rowb = mb + wm * 128 + fr * 16 + lg * 4;
#pragma unroll
        for (int c = 0; c < 4; c++) {
            int col = nb + wn * 64 + c * 16 + r16;
            if (col < N) {
#pragma unroll
                for (int j = 0; j < 4; j++)
                    bout[(size_t)(rowb + j) * ostride + col] = f2bf(acc[fr][c][j]);
            }
        }
    }
}

// ---------- pipelined GEMM 128x64 EPI2 (out_proj): 3-buffer, 1 barrier/tile ----------
// NEW SCHEDULE (r12): tile t = {barrier; stage((t+2)%3); ds_read(buf t%3);
// lgkmcnt(0); MFMA; vmcnt(6)}. Invariant: the tile-t barrier certifies all
// waves passed vmcnt(6)@t-1 (=> buf t staged, cross-wave) and lgkmcnt(0)@t-1
// (=> buf (t+2)%3 = (t-1)%3 free to overwrite). Arithmetic order unchanged.
__global__ __launch_bounds__(256, 2)
void gemm9(const u16* __restrict__ A, const u16* __restrict__ WT, int K,
           float* __restrict__ fout, u16* __restrict__ bout,
           const float* __restrict__ lsv)
{
    __shared__ u16 lds9[3 * 12288];          // 3 x [A:8192 | B:4096] u16 = 72 KB

    int mt, nt;
    {
        int nwg = gridDim.x * gridDim.y;
        int f = blockIdx.y * gridDim.x + blockIdx.x;
        int q = nwg >> 3, r = nwg & 7;
        int xcd = f & 7, lo = f >> 3;
        int wid = (xcd < r ? xcd * (q + 1) : r * (q + 1) + (xcd - r) * q) + lo;
        mt = wid % gridDim.y; nt = wid / gridDim.y;
    }

    const int tid  = threadIdx.x;
    const int lane = tid & 63;
    const int wave = tid >> 6;
    const int wm = wave >> 1, wn = wave & 1;
    const int r16 = lane & 15;
    const int lg  = lane >> 4;
    const int mb  = mt * 128;
    const int nb  = nt * 64;
    const int wbase = tid & 192;

    f32x4 acc[4][2];
#pragma unroll
    for (int mi = 0; mi < 4; mi++)
#pragma unroll
        for (int ni = 0; ni < 2; ni++)
            acc[mi][ni] = (f32x4){0.f, 0.f, 0.f, 0.f};

    auto stage = [&](int buf, int k0) {
        u16* bA = &lds9[buf * 12288];
#pragma unroll
        for (int rr = 0; rr < 6; rr++) {
            int e = rr * 256 + tid;
            int row = e >> 3;
            int cbs = (e & 7) ^ (row & 7);
            const u16* g = (rr < 4)
                ? A  + (size_t)(mb + row) * K + k0 + cbs * 8
                : WT + (size_t)(nb + row - 128) * K + k0 + cbs * 8;
            __builtin_amdgcn_global_load_lds(
                (const __attribute__((address_space(1))) void*)g,
                (__attribute__((address_space(3))) void*)&bA[(rr * 256 + wbase) * 8],
                16, 0, 0);
        }
    };

    const int ntk = K >> 6;
    stage(0, 0);
    stage(1, 64);
    asm volatile("s_waitcnt vmcnt(6)" ::: "memory");   // stage(0) complete (12 -> <=6)
    __builtin_amdgcn_sched_barrier(0);
    __builtin_amdgcn_s_barrier();                      // all waves' stage(0) complete

    for (int t = 0; t < ntk; t++) {
        const int buf = t % 3;
        const u16* bA = &lds9[buf * 12288];
        const u16* bB = bA + 8192;
        if (t + 2 < ntk) stage((t + 2) % 3, (t + 2) << 6);
        s16x8 a[4][2], b[2][2];
#pragma unroll
        for (int mf = 0; mf < 4; mf++)
#pragma unroll
            for (int kk = 0; kk < 2; kk++) {
                int row = wm * 64 + mf * 16 + r16;
                int cb = (kk * 4 + lg) ^ (row & 7);
                a[mf][kk] = *(const s16x8*)&bA[row * 64 + cb * 8];
            }
#pragma unroll
        for (int nf = 0; nf < 2; nf++)
#pragma unroll
            for (int kk = 0; kk < 2; kk++) {
                int row = wn * 32 + nf * 16 + r16;
                int cb = (kk * 4 + lg) ^ (row & 7);
                b[nf][kk] = *(const s16x8*)&bB[row * 64 + cb * 8];
            }
        asm volatile("s_waitcnt lgkmcnt(0)" ::: "memory");
        __builtin_amdgcn_sched_barrier(0);
        __builtin_amdgcn_s_setprio(1);
#pragma unroll
        for (int mf = 0; mf < 4; mf++)
#pragma unroll
            for (int nf = 0; nf < 2; nf++) {
                acc[mf][nf] = __builtin_amdgcn_mfma_f32_16x16x32_bf16(
                    a[mf][0], b[nf][0], acc[mf][nf], 0, 0, 0);
                acc[mf][nf] = __builtin_amdgcn_mfma_f32_16x16x32_bf16(
                    a[mf][1], b[nf][1], acc[mf][nf], 0, 0, 0);
            }
        __builtin_amdgcn_s_setprio(0);
        __builtin_amdgcn_sched_barrier(0);
        if (t + 2 < ntk) asm volatile("s_waitcnt vmcnt(6)" ::: "memory");
        else             asm volatile("s_waitcnt vmcnt(0)" ::: "memory");
        __builtin_amdgcn_sched_barrier(0);
        __builtin_amdgcn_s_barrier();        // certifies next tile's buf + frees (t)%3 later
    }

#pragma unroll
    for (int mf = 0; mf < 4; mf++) {
        const int rowb = mb + wm * 64 + mf * 16 + lg * 4;
#pragma unroll
        for (int nf = 0; nf < 2; nf++) {
            int col = nb + wn * 32 + nf * 16 + r16;
#pragma unroll
            for (int j = 0; j < 4; j++) {
                size_t o = (size_t)(rowb + j) * 768 + col;
                float xv = fout[o] + acc[mf][nf][j] * lsv[col];
                fout[o] = xv; bout[o] = f2bf(xv);
            }
        }
    }
}

// ---------- pipelined GEMM 128x64, batched (Wcomb), plain bf16 out with col offset ----------
__global__ __launch_bounds__(256, 2)
void gemm10(const u16* __restrict__ A, const u16* __restrict__ WT, int K,
            u16* __restrict__ bout, int ostride,
            size_t aZ, size_t wZ, size_t oZ, int ocolZ)
{
    __shared__ u16 ldsA[2 * 12288];

    {
        int z = blockIdx.z;
        A += (size_t)z * aZ; WT += (size_t)z * wZ;
        bout += (size_t)(z >> 1) * oZ + (size_t)(z & 1) * ocolZ;
    }
    int mt, nt;
    {
        int nwg = gridDim.x * gridDim.y;
        int f = blockIdx.y * gridDim.x + blockIdx.x;
        int q = nwg >> 3, r = nwg & 7;
        int xcd = f & 7, lo = f >> 3;
        int wid = (xcd < r ? xcd * (q + 1) : r * (q + 1) + (xcd - r) * q) + lo;
        mt = wid % gridDim.y; nt = wid / gridDim.y;
    }

    const int tid  = threadIdx.x;
    const int lane = tid & 63;
    const int wave = tid >> 6;
    const int wm = wave >> 1, wn = wave & 1;
    const int r16 = lane & 15;
    const int lg  = lane >> 4;
    const int mb  = mt * 128;
    const int nb  = nt * 64;
    const int wbase = tid & 192;

    f32x4 acc[4][2];
#pragma unroll
    for (int mi = 0; mi < 4; mi++)
#pragma unroll
        for (int ni = 0; ni < 2; ni++)
            acc[mi][ni] = (f32x4){0.f, 0.f, 0.f, 0.f};

    auto stage = [&](int buf, int k0) {
        u16* bA = &ldsA[buf * 12288];
#pragma unroll
        for (int rr = 0; rr < 6; rr++) {
            int e = rr * 256 + tid;
            int row = e >> 3;
            int cbs = (e & 7) ^ (row & 7);
            const u16* g = (rr < 4)
                ? A  + (size_t)(mb + row) * K + k0 + cbs * 8
                : WT + (size_t)(nb + row - 128) * K + k0 + cbs * 8;
            __builtin_amdgcn_global_load_lds(
                (const __attribute__((address_space(1))) void*)g,
                (__attribute__((address_space(3))) void*)&bA[(rr * 256 + wbase) * 8],
                16, 0, 0);
        }
    };

    const int ntk = K >> 6;
    stage(0, 0);
    stage(1, 64);
    asm volatile("s_waitcnt vmcnt(6)" ::: "memory");
    __builtin_amdgcn_sched_barrier(0);
    __builtin_amdgcn_s_barrier();

    for (int t = 0; t < ntk; t++) {
        const int buf = t & 1;
        const u16* bA = &ldsA[buf * 12288];
        const u16* bB = bA + 8192;
        s16x8 a[4][2], b[2][2];
#pragma unroll
        for (int mf = 0; mf < 4; mf++)
#pragma unroll
            for (int kk = 0; kk < 2; kk++) {
                int row = wm * 64 + mf * 16 + r16;
                int cb = (kk * 4 + lg) ^ (row & 7);
                a[mf][kk] = *(const s16x8*)&bA[row * 64 + cb * 8];
            }
#pragma unroll
        for (int nf = 0; nf < 2; nf++)
#pragma unroll
            for (int kk = 0; kk < 2; kk++) {
                int row = wn * 32 + nf * 16 + r16;
                int cb = (kk * 4 + lg) ^ (row & 7);
                b[nf][kk] = *(const s16x8*)&bB[row * 64 + cb * 8];
            }
        asm volatile("s_waitcnt lgkmcnt(0)" ::: "memory");
        __builtin_amdgcn_sched_barrier(0);
        __builtin_amdgcn_s_barrier();
        if (t + 2 < ntk) {
            stage(buf, (t + 2) << 6);
            asm volatile("s_waitcnt vmcnt(6)" ::: "memory");
        } else {
            asm volatile("s_waitcnt vmcnt(0)" ::: "memory");
        }
        __builtin_amdgcn_sched_barrier(0);
        __builtin_amdgcn_s_barrier();
        __builtin_amdgcn_s_setprio(1);
#pragma unroll
        for (int mf = 0; mf < 4; mf++)
#pragma unroll
            for (int nf = 0; nf < 2; nf++) {
                acc[mf][nf] = __builtin_amdgcn_mfma_f32_16x16x32_bf16(
                    a[mf][0], b[nf][0], acc[mf][nf], 0, 0, 0);
                acc[mf][nf] = __builtin_amdgcn_mfma_f32_16x16x32_bf16(
                    a[mf][1], b[nf][1], acc[mf][nf], 0, 0, 0);
            }
        __builtin_amdgcn_s_setprio(0);
    }

#pragma unroll
    for (int mf = 0; mf < 4; mf++) {
        const int rowb = mb + wm * 64 + mf * 16 + lg * 4;
#pragma unroll
        for (int nf = 0; nf < 2; nf++) {
            int col = nb + wn * 32 + nf * 16 + r16;
#pragma unroll
            for (int j = 0; j < 4; j++)
                bout[(size_t)(rowb + j) * ostride + col] = f2bf(acc[mf][nf][j]);
        }
    }
}

// ---------- pipelined GEMM 128x64 (patch): v += bias; f32 + bf16 out ----------
__global__ __launch_bounds__(256, 2)
void gemm11(const u16* __restrict__ A, const u16* __restrict__ WT, int K,
            float* __restrict__ fout, u16* __restrict__ bout,
            const float* __restrict__ bias)
{
    __shared__ u16 ldsB[2 * 12288];

    int mt, nt;
    {
        int nwg = gridDim.x * gridDim.y;
        int f = blockIdx.y * gridDim.x + blockIdx.x;
        int q = nwg >> 3, r = nwg & 7;
        int xcd = f & 7, lo = f >> 3;
        int wid = (xcd < r ? xcd * (q + 1) : r * (q + 1) + (xcd - r) * q) + lo;
        mt = wid % gridDim.y; nt = wid / gridDim.y;
    }

    const int tid  = threadIdx.x;
    const int lane = tid & 63;
    const int wave = tid >> 6;
    const int wm = wave >> 1, wn = wave & 1;
    const int r16 = lane & 15;
    const int lg  = lane >> 4;
    const int mb  = mt * 128;
    const int nb  = nt * 64;
    const int wbase = tid & 192;

    f32x4 acc[4][2];
#pragma unroll
    for (int mi = 0; mi < 4; mi++)
#pragma unroll
        for (int ni = 0; ni < 2; ni++)
            acc[mi][ni] = (f32x4){0.f, 0.f, 0.f, 0.f};

    auto stage = [&](int buf, int k0) {
        u16* bA = &ldsB[buf * 12288];
#pragma unroll
        for (int rr = 0; rr < 6; rr++) {
            int e = rr * 256 + tid;
            int row = e >> 3;
            int cbs = (e & 7) ^ (row & 7);
            const u16* g = (rr < 4)
                ? A  + (size_t)(mb + row) * K + k0 + cbs * 8
                : WT + (size_t)(nb + row - 128) * K + k0 + cbs * 8;
            __builtin_amdgcn_global_load_lds(
                (const __attribute__((address_space(1))) void*)g,
                (__attribute__((address_space(3))) void*)&bA[(rr * 256 + wbase) * 8],
                16, 0, 0);
        }
    };

    const int ntk = K >> 6;
    stage(0, 0);
    stage(1, 64);
    asm volatile("s_waitcnt vmcnt(6)" ::: "memory");
    __builtin_amdgcn_sched_barrier(0);
    __builtin_amdgcn_s_barrier();

    for (int t = 0; t < ntk; t++) {
        const int buf = t & 1;
        const u16* bA = &ldsB[buf * 12288];
        const u16* bB = bA + 8192;
        s16x8 a[4][2], b[2][2];
#pragma unroll
        for (int mf = 0; mf < 4; mf++)
#pragma unroll
            for (int kk = 0; kk < 2; kk++) {
                int row = wm * 64 + mf * 16 + r16;
                int cb = (kk * 4 + lg) ^ (row & 7);
                a[mf][kk] = *(const s16x8*)&bA[row * 64 + cb * 8];
            }
#pragma unroll
        for (int nf = 0; nf < 2; nf++)
#pragma unroll
            for (int kk = 0; kk < 2; kk++) {
                int row = wn * 32 + nf * 16 + r16;
                int cb = (kk * 4 + lg) ^ (row & 7);
                b[nf][kk] = *(const s16x8*)&bB[row * 64 + cb * 8];
            }
        asm volatile("s_waitcnt lgkmcnt(0)" ::: "memory");
        __builtin_amdgcn_sched_barrier(0);
        __builtin_amdgcn_s_barrier();
        if (t + 2 < ntk) {
            stage(buf, (t + 2) << 6);
            asm volatile("s_waitcnt vmcnt(6)" ::: "memory");
        } else {
            asm volatile("s_waitcnt vmcnt(0)" ::: "memory");
        }
        __builtin_amdgcn_sched_barrier(0);
        __builtin_amdgcn_s_barrier();
        __builtin_amdgcn_s_setprio(1);
#pragma unroll
        for (int mf = 0; mf < 4; mf++)
#pragma unroll
            for (int nf = 0; nf < 2; nf++) {
                acc[mf][nf] = __builtin_amdgcn_mfma_f32_16x16x32_bf16(
                    a[mf][0], b[nf][0], acc[mf][nf], 0, 0, 0);
                acc[mf][nf] = __builtin_amdgcn_mfma_f32_16x16x32_bf16(
                    a[mf][1], b[nf][1], acc[mf][nf], 0, 0, 0);
            }
        __builtin_amdgcn_s_setprio(0);
    }

#pragma unroll
    for (int mf = 0; mf < 4; mf++) {
        const int rowb = mb + wm * 64 + mf * 16 + lg * 4;
#pragma unroll
        for (int nf = 0; nf < 2; nf++) {
            int col = nb + wn * 32 + nf * 16 + r16;
#pragma unroll
            for (int j = 0; j < 4; j++) {
                float v = acc[mf][nf][j] + bias[col];
                size_t o = (size_t)(rowb + j) * 768 + col;
                fout[o] = v; bout[o] = f2bf(v);
            }
        }
    }
}

// ---------- preK: dt softplus + conv'd B/C (bit-identical to old in-scan conv) ----------
__global__ void preK(const u16* __restrict__ zxAll, float* __restrict__ dtAll,
                     u16* __restrict__ bcAll, const float* __restrict__ dtb,
                     const float* __restrict__ cw, const float* __restrict__ cb)
{
    int idx = blockIdx.x * 256 + threadIdx.x;
    if (idx < 2 * 4096 * 24) {
        int dir = idx / (4096 * 24);
        int r   = idx % (4096 * 24);
        int row = r / 24, h = r % 24;
        float raw = bf2f(zxAll[(size_t)row * 6256 + dir * 3128 + 3104 + h]) + dtb[dir * 24 + h];
        dtAll[((size_t)dir * 4096 + row) * 24 + h] = raw > 20.f ? raw : log1pf(__expf(raw));
        return;
    }
    int v = idx - 2 * 4096 * 24;
    if (v >= 2 * 4096 * 32) return;
    int ch  = v & 31;
    int row = (v >> 5) & 4095;
    int dir = v >> 17;
    int l   = row & 2047;
    int chg = 1536 + ch;
    float acc = cb[dir * 1568 + chg];
    const float* w = cw + ((size_t)dir * 1568 + chg) * 4;
#pragma unroll
    for (int k = 0; k < 4; k++) {
        int ll = dir ? (l + 3 - k) : (l - 3 + k);
        if (ll >= 0 && ll < 2048)
            acc += bf2f(zxAll[(size_t)(row + (ll - l)) * 6256 + dir * 3128 + chg]) * w[k];
    }
    acc = acc / (1.f + __expf(-acc));
    bcAll[((size_t)dir * 4096 + row) * 32 + ch] = f2bf(acc);
}

// ---------- chunked scan pass 1 (x-conv fused; B/C from bcAll) ----------
__global__ __launch_bounds__(256)
void scan1k(const u16* __restrict__ zxAll, const float* __restrict__ dtAll,
            const u16* __restrict__ bcAll,
            const float* __restrict__ cw, const float* __restrict__ cb,
            const float* __restrict__ Alog, const float* __restrict__ Dhp,
            u16* __restrict__ yAll, float* __restrict__ states, float* __restrict__ decays)
{
    const int c   = blockIdx.x;
    const int bh  = blockIdx.y;
    const int dir = blockIdx.z;
    const int b = bh / 24, h = bh % 24;
    const float* dtp = dtAll + (size_t)dir * 4096 * 24;
    const u16* bcp = bcAll + (size_t)dir * 4096 * 32;
    u16* yp = yAll + dir * 1536;
    const float Av = -__expf(Alog[dir * 24 + h]);
    const float Dv = Dhp[dir * 24 + h];
    const int inst = (dir * 2 + b) * 24 + h;

    const int tid  = threadIdx.x;
    const int lane = tid & 63;
    const int wave = tid >> 6;
    const int r16  = lane & 15;
    const int ks   = (lane >> 4) * 8;

    __shared__ u16 xT[64][72];
    __shared__ u16 Gs[64][72];
    __shared__ u16 Bs[64][40];
    __shared__ u16 Cs[64][40];
    __shared__ u16 SBT[16][72];
    __shared__ float dts[64], cds[64];

    const u16* zxd = zxAll + dir * 3128 + 1536;
    auto growp = [&](int ii) -> const u16* {
        int l = dir ? (2047 - ii) : ii;
        return zxd + ((size_t)b * 2048 + l) * 6256;
    };
    auto rowof = [&](int t) -> size_t {
        int i = c * 64 + t;
        int l = dir ? (2047 - i) : i;
        return (size_t)b * 2048 + l;
    };
    const u16x8 zz = {0,0,0,0,0,0,0,0};

    {
        int tr = tid >> 2, pg = tid & 3;
        int chb = h * 64 + pg * 16;
        int i0 = c * 64 + tr;
        u16x8 tv[4][2];
#pragma unroll
        for (int k = 0; k < 4; k++) {
            int ii = i0 - 3 + k;
            if (ii >= 0) {
                const u16* s = growp(ii) + chb;
                tv[k][0] = *(const u16x8*)s;
                tv[k][1] = *(const u16x8*)(s + 8);
            } else { tv[k][0] = zz; tv[k][1] = zz; }
        }
        const float* cwp = cw + ((size_t)dir * 1568 + chb) * 4;
        const float* cbp = cb + (size_t)dir * 1568 + chb;
#pragma unroll
        for (int j = 0; j < 16; j++) {
            f32x4 wj = *(const f32x4*)(cwp + j * 4);
            float a = cbp[j];
            int hi = j >> 3, lo2 = j & 7;
            a += bf2f(tv[0][hi][lo2]) * wj[0] + bf2f(tv[1][hi][lo2]) * wj[1]
               + bf2f(tv[2][hi][lo2]) * wj[2] + bf2f(tv[3][hi][lo2]) * wj[3];
            a = a / (1.f + __expf(-a));
            xT[pg * 16 + j][tr] = f2bf(a);
        }
    }
    {
        int t = tid & 63, which = tid >> 6;
        if (which < 2) {
            const u16* src = bcp + rowof(t) * 32 + which * 16;
            u16* dst = which ? &Cs[t][0] : &Bs[t][0];
            *(u16x8*)dst = *(const u16x8*)src;
            *(u16x8*)(dst + 8) = *(const u16x8*)(src + 8);
        } else {
            u16* dst = (which == 2) ? &Bs[t][16] : &Cs[t][16];
            *(u16x8*)dst = zz; *(u16x8*)(dst + 8) = zz;
        }
    }
    if (tid < 64) {
        float v = dtp[rowof(tid) * 24 + h];
        dts[tid] = v;
        float s = v;
#pragma unroll
        for (int o = 1; o < 64; o <<= 1) {
            float nvl = __shfl_up(s, o, 64);
            if (lane >= o) s += nvl;
        }
        cds[tid] = s;
    }
    __syncthreads();

    {
        const s16x8 af = *(const s16x8*)&Cs[wave * 16 + r16][ks];
#pragma unroll
        for (int st = 0; st < 4; st++) {
            const s16x8 bfr = *(const s16x8*)&Bs[st * 16 + r16][ks];
            f32x4 a2 = {0.f, 0.f, 0.f, 0.f};
            a2 = __builtin_amdgcn_mfma_f32_16x16x32_bf16(af, bfr, a2, 0, 0, 0);
            int s = st * 16 + (lane & 15);
            int tbase = wave * 16 + (lane >> 4) * 4;
            float cs = cds[s], dtv = dts[s];
#pragma unroll
            for (int j = 0; j < 4; j++) {
                int t = tbase + j;
                float g = 0.f;
                if (s <= t) {
                    g = a2[j] * dtv * __expf(Av * (cds[t] - cs));
                    if (s == t) g += Dv;
                }
                Gs[t][s] = f2bf(g);
            }
        }
    }
    {
        float cdT = cds[63];
        int s = tid & 63;
        float sc = __expf(Av * (cdT - cds[s])) * dts[s];
#pragma unroll
        for (int it = 0; it < 4; it++) {
            int n = (tid >> 6) + it * 4;
            SBT[n][s] = f2bf(sc * bf2f(Bs[s][n]));
        }
    }
    __syncthreads();

    {
#pragma unroll
        for (int pt = 0; pt < 4; pt++) {
            f32x4 a2 = {0.f, 0.f, 0.f, 0.f};
#pragma unroll
            for (int kk = 0; kk < 2; kk++) {
                s16x8 af = *(const s16x8*)&Gs[wave * 16 + r16][kk * 32 + ks];
                s16x8 bfr = *(const s16x8*)&xT[pt * 16 + r16][kk * 32 + ks];
                a2 = __builtin_amdgcn_mfma_f32_16x16x32_bf16(af, bfr, a2, 0, 0, 0);
            }
            int p = pt * 16 + (lane & 15);
            int tbase = wave * 16 + (lane >> 4) * 4;
#pragma unroll
            for (int j = 0; j < 4; j++) {
                size_t row = rowof(tbase + j);
                yp[row * 3072 + h * 64 + p] = f2bf(a2[j]);
            }
        }
    }
    {
        f32x4 a2 = {0.f, 0.f, 0.f, 0.f};
#pragma unroll
        for (int kk = 0; kk < 2; kk++) {
            s16x8 af = *(const s16x8*)&xT[wave * 16 + r16][kk * 32 + ks];
            s16x8 bfr = *(const s16x8*)&SBT[r16][kk * 32 + ks];
            a2 = __builtin_amdgcn_mfma_f32_16x16x32_bf16(af, bfr, a2, 0, 0, 0);
        }
        int n = lane & 15;
        int pbase = wave * 16 + (lane >> 4) * 4;
        float* st = states + ((size_t)inst * 32 + c) * 1024;
#pragma unroll
        for (int j = 0; j < 4; j++) st[(pbase + j) * 16 + n] = a2[j];
        if (tid == 0) decays[inst * 32 + c] = __expf(Av * cds[63]);
    }
}

// ---------- chunked scan pass 2: cross-chunk recurrence ----------
__global__ __launch_bounds__(256)
void scan2k(float* __restrict__ states, const float* __restrict__ decays)
{
    int inst = blockIdx.x;
    int tid = threadIdx.x;
    float* base = states + (size_t)inst * 32 * 1024 + tid * 4;
    const float* dec = decays + inst * 32;
    f32x4 hreg = {0.f, 0.f, 0.f, 0.f};
    f32x4 L = *(f32x4*)base;
    for (int cc = 0; cc < 32; cc++) {
        f32x4 Lnext;
        if (cc + 1 < 32) Lnext = *(f32x4*)(base + (cc + 1) * 1024);
        *(f32x4*)(base + cc * 1024) = hreg;
        float d = dec[cc];
        hreg = hreg * d + L;
        L = Lnext;
    }
}

// ---------- chunked scan pass 3: y += C_t . (exp(A cd_t) h_start), C from bcAll ----------
__global__ __launch_bounds__(256)
void scan3k(const float* __restrict__ states,
            const u16* __restrict__ bcAll, const float* __restrict__ dtAll,
            const float* __restrict__ Alog, u16* __restrict__ yAll)
{
    const int c   = blockIdx.x + 1;
    const int bh  = blockIdx.y;
    const int dir = blockIdx.z;
    const int b = bh / 24, h = bh % 24;
    const float* dtp = dtAll + (size_t)dir * 4096 * 24;
    const u16* bcp = bcAll + (size_t)dir * 4096 * 32;
    u16* yp = yAll + dir * 1536;
    const float Av = -__expf(Alog[dir * 24 + h]);
    const int inst = (dir * 2 + b) * 24 + h;
    const int tid = threadIdx.x;

    __shared__ float hs[64][20];
    __shared__ u16 Cs3[64][16];
    __shared__ float ets[64];

    auto rowof = [&](int t) -> size_t {
        int i = c * 64 + t;
        int l = dir ? (2047 - i) : i;
        return (size_t)b * 2048 + l;
    };

    {
        const float* sp = states + ((size_t)inst * 32 + c) * 1024 + tid * 4;
        f32x4 v = *(const f32x4*)sp;
        int e = tid * 4;
        int p = e >> 4, n = e & 15;
        hs[p][n] = v[0]; hs[p][n+1] = v[1]; hs[p][n+2] = v[2]; hs[p][n+3] = v[3];
    }
    if (tid < 64) {
        size_t row = rowof(tid);
        const u16* src = bcp + row * 32 + 16;
        *(u16x8*)&Cs3[tid][0] = *(const u16x8*)src;
        *(u16x8*)&Cs3[tid][8] = *(const u16x8*)(src + 8);
        float v = dtp[row * 24 + h];
        float s = v;
#pragma unroll
        for (int o = 1; o < 64; o <<= 1) {
            float nvl = __shfl_up(s, o, 64);
            if ((tid & 63) >= o) s += nvl;
        }
        ets[tid] = __expf(Av * s);
    }
    __syncthreads();

    int t = tid >> 2, pg = tid & 3;
    float cv[16];
    float et = ets[t];
#pragma unroll
    for (int n = 0; n < 16; n++) cv[n] = bf2f(Cs3[t][n]) * et;
    size_t row = rowof(t);
    u16* yrow = yp + row * 3072 + h * 64 + pg * 16;
    u16x8 ya = *(u16x8*)yrow;
    u16x8 yb = *(u16x8*)(yrow + 8);
#pragma unroll
    for (int jj = 0; jj < 16; jj++) {
        int p = pg * 16 + jj;
        float acc = 0.f;
#pragma unroll
        for (int q = 0; q < 4; q++) {
            f32x4 hv = *(const f32x4*)&hs[p][q * 4];
            acc += cv[q*4]*hv[0] + cv[q*4+1]*hv[1] + cv[q*4+2]*hv[2] + cv[q*4+3]*hv[3];
        }
        if (jj < 8) ya[jj] = f2bf(bf2f(ya[jj]) + acc);
        else        yb[jj - 8] = f2bf(bf2f(yb[jj - 8]) + acc);
    }
    *(u16x8*)yrow = ya;
    *(u16x8*)(yrow + 8) = yb;
}

// ---------- gating + RMSnorm ----------
__global__ __launch_bounds__(256)
void gatek(const u16* __restrict__ zxAll, u16* __restrict__ yAll,
           const float* __restrict__ nw)
{
    int row = blockIdx.x, dir = blockIdx.y;
    const u16* zx = zxAll + (size_t)row * 6256 + dir * 3128;
    u16* y = yAll + (size_t)row * 3072 + dir * 1536;
    const float* nwp = nw + dir * 1536;
    int tid = threadIdx.x;
    float g[6]; float s = 0.f;
#pragma unroll
    for (int j = 0; j < 6; j++) {
        int c = j * 256 + tid;
        float z  = bf2f(zx[c]);
        float yv = bf2f(y[c]);
        float gv = yv * z / (1.f + __expf(-z));
        g[j] = gv; s += gv * gv;
    }
    __shared__ float red[4];
    for (int o = 32; o; o >>= 1) s += __shfl_down(s, o, 64);
    if ((tid & 63) == 0) red[tid >> 6] = s;
    __syncthreads();
    s = red[0] + red[1] + red[2] + red[3];
    float sc = rsqrtf(s * (1.f / 1536.f) + 1e-5f);
#pragma unroll
    for (int j = 0; j < 6; j++) {
        int c = j * 256 + tid;
        y[c] = f2bf(g[j] * sc * nwp[c]);
    }
}

// ---------- final RMS norm ----------
__global__ __launch_bounds__(256)
void finalk(const float* __restrict__ x, const float* __restrict__ fw, float* __restrict__ out)
{
    int row = blockIdx.x; int tid = threadIdx.x;
    const float* xr = x + (size_t)row * 768;
    float v[3]; float s = 0.f;
#pragma unroll
    for (int j = 0; j < 3; j++) {
        int c = j * 256 + tid;
        v[j] = xr[c]; s += v[j] * v[j];
    }
    __shared__ float red[4];
    for (int o = 32; o; o >>= 1) s += __shfl_down(s, o, 64);
    if ((tid & 63) == 0) red[tid >> 6] = s;
    __syncthreads();
    s = red[0] + red[1] + red[2] + red[3];
    float sc = rsqrtf(s * (1.f / 768.f) + 1e-6f);
#pragma unroll
    for (int j = 0; j < 3; j++) {
        int c = j * 256 + tid;
        out[(size_t)row * 768 + c] = v[j] * sc * (1.f + fw[c]);
    }
}

// ---------- host ----------
extern "C" void kernel_launch(void* const* d_in, const int* in_sizes, int n_in,
                              void* d_out, int out_size, void* d_ws, size_t ws_size,
                              hipStream_t stream)
{
    const float* pe      = (const float*)d_in[0];
    const float* Wp      = (const float*)d_in[1];
    const float* bp      = (const float*)d_in[2];
    const float* in_w    = (const float*)d_in[3];
    const float* conv_w  = (const float*)d_in[4];
    const float* conv_b  = (const float*)d_in[5];
    const float* dt_bias = (const float*)d_in[6];
    const float* A_log   = (const float*)d_in[7];
    const float* Dh      = (const float*)d_in[8];
    const float* norm_w  = (const float*)d_in[9];
    const float* out_w   = (const float*)d_in[10];
    const float* bi_w    = (const float*)d_in[11];
    const float* ls      = (const float*)d_in[12];
    const float* fin_w   = (const float*)d_in[13];

    char* wp = (char*)d_ws;
    auto alloc = [&](size_t bytes) {
        char* r = wp; wp += (bytes + 255) & ~(size_t)255; return r;
    };
    u16*   WpT    = (u16*)  alloc((size_t)768 * 256 * 2);
    u16*   inWT   = (u16*)  alloc(((size_t)2 * 6400 * 768 + 4096) * 2);  // padded N=6400 + tail slack
    u16*   outWB  = (u16*)  alloc((size_t)4 * 1536 * 768 * 2);
    u16*   biWT   = (u16*)  alloc((size_t)4 * 768 * 768 * 2);
    u16*   WcombT = (u16*)  alloc((size_t)2 * 768 * 3072 * 2);
    u16*   peB    = (u16*)  alloc((size_t)4096 * 256 * 2);
    float* x      = (float*)alloc((size_t)4096 * 768 * 4);
    u16*   xb     = (u16*)  alloc((size_t)4096 * 768 * 2);
    u16*   zxAll  = (u16*)  alloc((size_t)4096 * 6256 * 2);
    float* dtAll  = (float*)alloc((size_t)2 * 4096 * 24 * 4);
    u16*   bcAll  = (u16*)  alloc((size_t)2 * 4096 * 32 * 2);
    u16*   yAll   = (u16*)  alloc((size_t)4096 * 3072 * 2);
    float* states = (float*)alloc((size_t)96 * 32 * 1024 * 4);
    float* decays = (float*)alloc((size_t)96 * 32 * 4);

    // ---- weight prep (batched over z) ----
    wtransT<<<dim3(24, 8, 1), 256, 0, stream>>>(Wp, WpT, 256, 768, 256, 0, 0, 0);
    wtransT<<<dim3(98, 24, 4), 256, 0, stream>>>(in_w, inWT, 768, 3128, 768,
                                                 2402304, 4915200, 2402304);
    wtransT<<<dim3(24, 24, 4), 256, 0, stream>>>(bi_w, biWT, 768, 768, 768,
                                                 589824, 1179648, 589824);
    cvt2k<<<(4 * 1536 * 768 + 4096 * 256 + 255) / 256, 256, 0, stream>>>(
        out_w, outWB, 4 * 1536 * 768, pe, peB, 4096 * 256);

    // ---- Wcomb (batched, pipelined) ----
    gemm10<<<dim3(24, 6, 4), 256, 0, stream>>>(
        biWT, outWB, 768, WcombT, 3072,
        (size_t)589824, (size_t)1179648, (size_t)768 * 3072, 1536);

    // ---- patch embedding GEMM (pipelined) ----
    gemm11<<<dim3(12, 32), 256, 0, stream>>>(peB, WpT, 256, x, xb, bp);

    hipFuncSetAttribute((const void*)gemmY,
                        hipFuncAttributeMaxDynamicSharedMemorySize, 131072);

    for (int i = 0; i < 2; i++) {
        // merged in_proj (both dirs), 256x256 4-phase pipelined GEMM
        gemmY<<<dim3(25, 16), 512, 131072, stream>>>(
            xb, inWT + (size_t)i * 6400 * 768, 6256, 768, zxAll, 6256);
        preK<<<(2 * 4096 * 56 + 255) / 256, 256, 0, stream>>>(
            zxAll, dtAll, bcAll, dt_bias + i * 48,
            conv_w + (size_t)i * 2 * 1568 * 4, conv_b + (size_t)i * 2 * 1568);
        scan1k<<<dim3(32, 48, 2), 256, 0, stream>>>(zxAll, dtAll, bcAll,
                                                    conv_w + (size_t)i * 2 * 1568 * 4,
                                                    conv_b + (size_t)i * 2 * 1568,
                                                    A_log + i * 48, Dh + i * 48,
                                                    yAll, states, decays);
        scan2k<<<96, 256, 0, stream>>>(states, decays);
        scan3k<<<dim3(31, 48, 2), 256, 0, stream>>>(states, bcAll, dtAll,
                                                    A_log + i * 48, yAll);
        gatek<<<dim3(4096, 2), 256, 0, stream>>>(zxAll, yAll, norm_w + (size_t)i * 2 * 1536);
        // fused out_proj + concat + bi_w + residual (3-buffer 1-barrier pipelined)
        gemm9<<<dim3(12, 32, 1), 256, 0, stream>>>(
            yAll, WcombT + (size_t)i * 768 * 3072, 3072, x, xb, ls + i * 768);
    }

    finalk<<<4096, 256, 0, stream>>>(x, fin_w, (float*)d_out);
}